// Round 2
// baseline (1418.070 us; speedup 1.0000x reference)
//
#include <hip/hip_runtime.h>
#include <math.h>

// ---------------------------------------------------------------------------
// GATClassifier on MI355X.
// Pipeline per call:
//   1. Build CSR over dst (deg histogram -> 1-block scan -> atomic scatter)
//   2. Per GAT layer: SGEMM (h = X @ W), att dots (a_s, a_d), per-node
//      wave-parallel softmax + weighted gather aggregation (+bias, +ELU)
//   3. Mean-pool per graph (atomics), final 32->1 linear
// All fp32. CSR avoids fp32 scatter atomics in the heavy aggregation.
// NOTE: edge_index / batch are int32 (harness: "integer -> const int*").
// ---------------------------------------------------------------------------

__global__ __launch_bounds__(256) void k_init_deg(int* deg, int N) {
  int n = blockIdx.x * 256 + threadIdx.x;
  if (n < N) deg[n] = 1;  // self-loop
}

__global__ __launch_bounds__(256) void k_count_deg(const int* __restrict__ ei,
                                                   int E, int* deg) {
  int e = blockIdx.x * 256 + threadIdx.x;
  if (e < E) {
    int d = ei[E + e];  // row 1 = dst
    atomicAdd(&deg[d], 1);
  }
}

// Exclusive scan of deg[0..N) -> rowptr[0..N], plus a cursor copy for scatter.
__global__ __launch_bounds__(1024) void k_scan(const int* __restrict__ deg,
                                               int* __restrict__ rowptr,
                                               int* __restrict__ cursor, int N) {
  __shared__ int part[1024];
  int t = threadIdx.x;
  int chunk = (N + 1023) >> 10;
  int b = t * chunk;
  int e = min(b + chunk, N);
  int s = 0;
  for (int i = b; i < e; i++) s += deg[i];
  part[t] = s;
  __syncthreads();
  for (int off = 1; off < 1024; off <<= 1) {
    int v = (t >= off) ? part[t - off] : 0;
    __syncthreads();
    part[t] += v;
    __syncthreads();
  }
  int run = (t > 0) ? part[t - 1] : 0;
  for (int i = b; i < e; i++) {
    rowptr[i] = run;
    cursor[i] = run;
    run += deg[i];
  }
  if (t == 1023) rowptr[N] = part[1023];
}

__global__ __launch_bounds__(256) void k_scatter(const int* __restrict__ ei,
                                                 int E, int N, int* cursor,
                                                 int* __restrict__ colsrc) {
  int i = blockIdx.x * 256 + threadIdx.x;
  if (i < E) {
    int s = ei[i];
    int d = ei[E + i];
    int pos = atomicAdd(&cursor[d], 1);
    colsrc[pos] = s;
  } else if (i < E + N) {
    int nn = i - E;
    int pos = atomicAdd(&cursor[nn], 1);
    colsrc[pos] = nn;  // self loop
  }
}

// C[M,Nc] = A[M,K] @ B[K,Nc], row-major. 64x64 tile, 256 thr, 4x4 micro-tile.
__global__ __launch_bounds__(256) void k_sgemm(const float* __restrict__ A,
                                               const float* __restrict__ B,
                                               float* __restrict__ C,
                                               int M, int Nc, int K) {
  __shared__ float As[16][65];
  __shared__ float Bs[16][65];
  int tid = threadIdx.x;
  int row0 = blockIdx.y * 64;
  int col0 = blockIdx.x * 64;
  int ty = tid >> 4, tx = tid & 15;
  int la_r = tid >> 2;           // 0..63 tile row for A load
  int la_k = (tid & 3) << 2;     // float4 k-offset
  int lb_k = tid >> 4;           // 0..15 tile k-row for B load
  int lb_c = (tid & 15) << 2;    // float4 col-offset
  float acc[4][4] = {};
  for (int k0 = 0; k0 < K; k0 += 16) {
    int ar = row0 + la_r;
    float4 av = make_float4(0.f, 0.f, 0.f, 0.f);
    if (ar < M) av = *(const float4*)(A + (size_t)ar * K + k0 + la_k);
    As[la_k + 0][la_r] = av.x;
    As[la_k + 1][la_r] = av.y;
    As[la_k + 2][la_r] = av.z;
    As[la_k + 3][la_r] = av.w;
    int br = k0 + lb_k;
    int bc = col0 + lb_c;
    float4 bv;
    if (bc + 3 < Nc) {
      bv = *(const float4*)(B + (size_t)br * Nc + bc);
    } else {
      bv.x = (bc + 0 < Nc) ? B[(size_t)br * Nc + bc + 0] : 0.f;
      bv.y = (bc + 1 < Nc) ? B[(size_t)br * Nc + bc + 1] : 0.f;
      bv.z = (bc + 2 < Nc) ? B[(size_t)br * Nc + bc + 2] : 0.f;
      bv.w = (bc + 3 < Nc) ? B[(size_t)br * Nc + bc + 3] : 0.f;
    }
    Bs[lb_k][lb_c + 0] = bv.x;
    Bs[lb_k][lb_c + 1] = bv.y;
    Bs[lb_k][lb_c + 2] = bv.z;
    Bs[lb_k][lb_c + 3] = bv.w;
    __syncthreads();
#pragma unroll
    for (int kk = 0; kk < 16; kk++) {
      float a0 = As[kk][ty * 4 + 0], a1 = As[kk][ty * 4 + 1];
      float a2 = As[kk][ty * 4 + 2], a3 = As[kk][ty * 4 + 3];
      float b0 = Bs[kk][tx * 4 + 0], b1 = Bs[kk][tx * 4 + 1];
      float b2 = Bs[kk][tx * 4 + 2], b3 = Bs[kk][tx * 4 + 3];
      acc[0][0] += a0 * b0; acc[0][1] += a0 * b1; acc[0][2] += a0 * b2; acc[0][3] += a0 * b3;
      acc[1][0] += a1 * b0; acc[1][1] += a1 * b1; acc[1][2] += a1 * b2; acc[1][3] += a1 * b3;
      acc[2][0] += a2 * b0; acc[2][1] += a2 * b1; acc[2][2] += a2 * b2; acc[2][3] += a2 * b3;
      acc[3][0] += a3 * b0; acc[3][1] += a3 * b1; acc[3][2] += a3 * b2; acc[3][3] += a3 * b3;
    }
    __syncthreads();
  }
#pragma unroll
  for (int i = 0; i < 4; i++) {
    int r = row0 + ty * 4 + i;
    if (r >= M) continue;
#pragma unroll
    for (int j = 0; j < 4; j++) {
      int c = col0 + tx * 4 + j;
      if (c < Nc) C[(size_t)r * Nc + c] = acc[i][j];
    }
  }
}

// a_s[n,h] = <h[n,h,:], att_src[h,:]>, a_d likewise. One thread per (n,h).
__global__ __launch_bounds__(256) void k_att(const float* __restrict__ hW,
                                             const float* __restrict__ attS,
                                             const float* __restrict__ attD,
                                             float* __restrict__ aS,
                                             float* __restrict__ aD, int NH, int H) {
  int idx = blockIdx.x * 256 + threadIdx.x;
  if (idx >= NH) return;
  int h = idx % H;
  const float4* hv = (const float4*)(hW + (size_t)idx * 32);
  const float4* sv = (const float4*)(attS + h * 32);
  const float4* dv = (const float4*)(attD + h * 32);
  float ss = 0.f, dd = 0.f;
#pragma unroll
  for (int k = 0; k < 8; k++) {
    float4 a = hv[k], b = sv[k], c = dv[k];
    ss += a.x * b.x + a.y * b.y + a.z * b.z + a.w * b.w;
    dd += a.x * c.x + a.y * c.y + a.z * c.z + a.w * c.w;
  }
  aS[idx] = ss;
  aD[idx] = dd;
}

// One wave per dst node: 2-pass softmax (max, sum) over in-edges with shuffle
// reductions, then serial-edge weighted gather; lane = (head-pair, channel).
template <int H, bool DO_ELU>
__global__ __launch_bounds__(256) void k_gat_agg(
    const float* __restrict__ hW, const float* __restrict__ aS,
    const float* __restrict__ aD, const int* __restrict__ rowptr,
    const int* __restrict__ colsrc, const float* __restrict__ bias,
    float* __restrict__ out, int N) {
  constexpr int C = 32;
  constexpr int HC = H * C;
  int wid = (blockIdx.x * blockDim.x + threadIdx.x) >> 6;
  int lane = threadIdx.x & 63;
  if (wid >= N) return;
  int n = wid;
  int row0 = rowptr[n];
  int deg = rowptr[n + 1] - row0;

  float adn[H], m[H], s[H];
#pragma unroll
  for (int h = 0; h < H; h++) {
    adn[h] = aD[(size_t)n * H + h];
    m[h] = -1e30f;
    s[h] = 0.f;
  }
  // pass 1: segment max
  for (int i = lane; i < deg; i += 64) {
    int src = colsrc[row0 + i];
#pragma unroll
    for (int h = 0; h < H; h++) {
      float e = aS[(size_t)src * H + h] + adn[h];
      e = (e > 0.f) ? e : 0.2f * e;
      m[h] = fmaxf(m[h], e);
    }
  }
#pragma unroll
  for (int h = 0; h < H; h++) {
#pragma unroll
    for (int off = 32; off > 0; off >>= 1) m[h] = fmaxf(m[h], __shfl_xor(m[h], off, 64));
  }
  // pass 2: segment sum of exp
  for (int i = lane; i < deg; i += 64) {
    int src = colsrc[row0 + i];
#pragma unroll
    for (int h = 0; h < H; h++) {
      float e = aS[(size_t)src * H + h] + adn[h];
      e = (e > 0.f) ? e : 0.2f * e;
      s[h] += __expf(e - m[h]);
    }
  }
#pragma unroll
  for (int h = 0; h < H; h++) {
#pragma unroll
    for (int off = 32; off > 0; off >>= 1) s[h] += __shfl_xor(s[h], off, 64);
  }
  float rs[H];
#pragma unroll
  for (int h = 0; h < H; h++) rs[h] = 1.f / s[h];

  if constexpr (H == 8) {
    // lane -> (h = 2*hp + (lane>>5), c = lane&31); offset in row = hp*64+lane
    int hbase = lane >> 5;
    float mh[4], rsh[4], adh[4], acc[4];
#pragma unroll
    for (int hp = 0; hp < 4; hp++) {
      mh[hp] = hbase ? m[2 * hp + 1] : m[2 * hp];
      rsh[hp] = hbase ? rs[2 * hp + 1] : rs[2 * hp];
      adh[hp] = hbase ? adn[2 * hp + 1] : adn[2 * hp];
      acc[hp] = 0.f;
    }
    for (int i = 0; i < deg; i++) {
      int src = colsrc[row0 + i];
      const float* hrow = hW + (size_t)src * HC;
#pragma unroll
      for (int hp = 0; hp < 4; hp++) {
        float e = aS[(size_t)src * 8 + 2 * hp + hbase] + adh[hp];
        e = (e > 0.f) ? e : 0.2f * e;
        float alpha = __expf(e - mh[hp]) * rsh[hp];
        acc[hp] += alpha * hrow[hp * 64 + lane];
      }
    }
#pragma unroll
    for (int hp = 0; hp < 4; hp++) {
      float v = acc[hp] + bias[hp * 64 + lane];
      if (DO_ELU) v = (v > 0.f) ? v : (__expf(v) - 1.f);
      out[(size_t)n * HC + hp * 64 + lane] = v;
    }
  } else {
    // H == 1: two edges in flight (lane>>5), 32 channels
    int c = lane & 31;
    int eo = lane >> 5;
    float acc = 0.f;
    for (int i = eo; i < deg; i += 2) {
      int src = colsrc[row0 + i];
      float e = aS[src] + adn[0];
      e = (e > 0.f) ? e : 0.2f * e;
      float alpha = __expf(e - m[0]) * rs[0];
      acc += alpha * hW[(size_t)src * C + c];
    }
    acc += __shfl_xor(acc, 32, 64);
    if (lane < 32) {
      float v = acc + bias[c];
      if (DO_ELU) v = (v > 0.f) ? v : (__expf(v) - 1.f);
      out[(size_t)n * C + c] = v;
    }
  }
}

__global__ __launch_bounds__(256) void k_zero_pool(float* sums, float* cnt) {
  int i = blockIdx.x * 256 + threadIdx.x;
  if (i < 64 * 32) sums[i] = 0.f;
  if (i < 64) cnt[i] = 0.f;
}

__global__ __launch_bounds__(256) void k_pool(const float* __restrict__ h,
                                              const int* __restrict__ batch,
                                              float* sums, float* cnt, int N) {
  int idx = blockIdx.x * 256 + threadIdx.x;
  if (idx >= N * 32) return;
  int n = idx >> 5, c = idx & 31;
  int g = batch[n];
  atomicAdd(&sums[g * 32 + c], h[idx]);
  if (c == 0) atomicAdd(&cnt[g], 1.f);
}

__global__ void k_final(const float* __restrict__ sums, const float* __restrict__ cnt,
                        const float* __restrict__ linW, const float* __restrict__ linb,
                        float* __restrict__ out) {
  int g = threadIdx.x;
  if (g >= 64) return;
  float r = 1.f / fmaxf(cnt[g], 1.f);
  float acc = 0.f;
  for (int k = 0; k < 32; k++) acc += sums[g * 32 + k] * linW[k];
  out[g] = acc * r + linb[0];
}

extern "C" void kernel_launch(void* const* d_in, const int* in_sizes, int n_in,
                              void* d_out, int out_size, void* d_ws, size_t ws_size,
                              hipStream_t stream) {
  const float* x = (const float*)d_in[0];
  const int* ei = (const int*)d_in[1];      // int32! (JAX x64 disabled)
  const int* batch = (const int*)d_in[2];   // int32!
  const float* W1 = (const float*)d_in[3];
  const float* as1 = (const float*)d_in[4];
  const float* ad1 = (const float*)d_in[5];
  const float* b1 = (const float*)d_in[6];
  const float* W2 = (const float*)d_in[7];
  const float* as2 = (const float*)d_in[8];
  const float* ad2 = (const float*)d_in[9];
  const float* b2 = (const float*)d_in[10];
  const float* W3 = (const float*)d_in[11];
  const float* as3 = (const float*)d_in[12];
  const float* ad3 = (const float*)d_in[13];
  const float* b3 = (const float*)d_in[14];
  const float* linW = (const float*)d_in[15];
  const float* linb = (const float*)d_in[16];

  const int N = in_sizes[0] / 256;
  const int E = in_sizes[1] / 2;
  float* out = (float*)d_out;

  // --- workspace carve ---
  char* ws = (char*)d_ws;
  size_t off = 0;
  auto alloc = [&](size_t bytes) -> void* {
    void* p = ws + off;
    off += (bytes + 255) & ~(size_t)255;
    return p;
  };
  float* B1 = (float*)alloc((size_t)N * 256 * 4);
  float* B2 = (float*)alloc((size_t)N * 256 * 4);
  float* aS = (float*)alloc((size_t)N * 8 * 4);
  float* aD = (float*)alloc((size_t)N * 8 * 4);
  int* deg = (int*)alloc((size_t)N * 4);
  int* rowptr = (int*)alloc((size_t)(N + 1) * 4);
  int* cursor = (int*)alloc((size_t)(N + 1) * 4);
  int* colsrc = (int*)alloc((size_t)(E + N) * 4);
  float* sums = (float*)alloc(64 * 32 * 4);
  float* cnt = (float*)alloc(64 * 4);
  // layer-3 buffers reuse B1's space (B1 holds h3 [N,32]; h3agg right after)
  float* h3 = B1;
  float* h3agg = B1 + (size_t)N * 32;

  // --- CSR build ---
  k_init_deg<<<(N + 255) / 256, 256, 0, stream>>>(deg, N);
  k_count_deg<<<(E + 255) / 256, 256, 0, stream>>>(ei, E, deg);
  k_scan<<<1, 1024, 0, stream>>>(deg, rowptr, cursor, N);
  k_scatter<<<(E + N + 255) / 256, 256, 0, stream>>>(ei, E, N, cursor, colsrc);

  const int aggBlocks = (N + 3) / 4;  // 4 waves/block, 1 node/wave

  // --- layer 1 ---
  {
    dim3 g((256 + 63) / 64, (N + 63) / 64);
    k_sgemm<<<g, 256, 0, stream>>>(x, W1, B1, N, 256, 256);
    k_att<<<(N * 8 + 255) / 256, 256, 0, stream>>>(B1, as1, ad1, aS, aD, N * 8, 8);
    k_gat_agg<8, true><<<aggBlocks, 256, 0, stream>>>(B1, aS, aD, rowptr, colsrc, b1, B2, N);
  }
  // --- layer 2 ---
  {
    dim3 g((256 + 63) / 64, (N + 63) / 64);
    k_sgemm<<<g, 256, 0, stream>>>(B2, W2, B1, N, 256, 256);
    k_att<<<(N * 8 + 255) / 256, 256, 0, stream>>>(B1, as2, ad2, aS, aD, N * 8, 8);
    k_gat_agg<8, true><<<aggBlocks, 256, 0, stream>>>(B1, aS, aD, rowptr, colsrc, b2, B2, N);
  }
  // --- layer 3 (H=1, no concat-mean needed, no ELU) ---
  {
    dim3 g((32 + 63) / 64, (N + 63) / 64);
    k_sgemm<<<g, 256, 0, stream>>>(B2, W3, h3, N, 32, 256);
    k_att<<<(N + 255) / 256, 256, 0, stream>>>(h3, as3, ad3, aS, aD, N, 1);
    k_gat_agg<1, false><<<aggBlocks, 256, 0, stream>>>(h3, aS, aD, rowptr, colsrc, b3, h3agg, N);
  }
  // --- pool + final linear ---
  k_zero_pool<<<8, 256, 0, stream>>>(sums, cnt);
  k_pool<<<((size_t)N * 32 + 255) / 256, 256, 0, stream>>>(h3agg, batch, sums, cnt, N);
  k_final<<<1, 64, 0, stream>>>(sums, cnt, linW, linb, out);
}

// Round 3
// 1062.660 us; speedup vs baseline: 1.3345x; 1.3345x over previous
//
#include <hip/hip_runtime.h>
#include <math.h>

// ---------------------------------------------------------------------------
// GATClassifier on MI355X.
// Pipeline per call:
//   1. Build CSR over dst (deg histogram -> 1-block scan -> atomic scatter)
//   2. Per GAT layer: SGEMM (h = X @ W), att dots (a_s, a_d), per-node
//      wave-parallel softmax + weighted gather aggregation (+bias, +ELU)
//   3. Fused mean-pool + 32->1 linear: batch is SORTED, so one block per
//      graph + binary search = zero atomics (R2: atomic k_pool was 383 us,
//      27% of total, from 1.6M atomicAdds onto 2048 addresses).
// All fp32. CSR avoids fp32 scatter atomics in the heavy aggregation.
// NOTE: edge_index / batch are int32 (harness: "integer -> const int*").
// ---------------------------------------------------------------------------

__global__ __launch_bounds__(256) void k_init_deg(int* deg, int N) {
  int n = blockIdx.x * 256 + threadIdx.x;
  if (n < N) deg[n] = 1;  // self-loop
}

__global__ __launch_bounds__(256) void k_count_deg(const int* __restrict__ ei,
                                                   int E, int* deg) {
  int e = blockIdx.x * 256 + threadIdx.x;
  if (e < E) {
    int d = ei[E + e];  // row 1 = dst
    atomicAdd(&deg[d], 1);
  }
}

// Exclusive scan of deg[0..N) -> rowptr[0..N], plus a cursor copy for scatter.
__global__ __launch_bounds__(1024) void k_scan(const int* __restrict__ deg,
                                               int* __restrict__ rowptr,
                                               int* __restrict__ cursor, int N) {
  __shared__ int part[1024];
  int t = threadIdx.x;
  int chunk = (N + 1023) >> 10;
  int b = t * chunk;
  int e = min(b + chunk, N);
  int s = 0;
  for (int i = b; i < e; i++) s += deg[i];
  part[t] = s;
  __syncthreads();
  for (int off = 1; off < 1024; off <<= 1) {
    int v = (t >= off) ? part[t - off] : 0;
    __syncthreads();
    part[t] += v;
    __syncthreads();
  }
  int run = (t > 0) ? part[t - 1] : 0;
  for (int i = b; i < e; i++) {
    rowptr[i] = run;
    cursor[i] = run;
    run += deg[i];
  }
  if (t == 1023) rowptr[N] = part[1023];
}

__global__ __launch_bounds__(256) void k_scatter(const int* __restrict__ ei,
                                                 int E, int N, int* cursor,
                                                 int* __restrict__ colsrc) {
  int i = blockIdx.x * 256 + threadIdx.x;
  if (i < E) {
    int s = ei[i];
    int d = ei[E + i];
    int pos = atomicAdd(&cursor[d], 1);
    colsrc[pos] = s;
  } else if (i < E + N) {
    int nn = i - E;
    int pos = atomicAdd(&cursor[nn], 1);
    colsrc[pos] = nn;  // self loop
  }
}

// C[M,Nc] = A[M,K] @ B[K,Nc], row-major. 64x64 tile, 256 thr, 4x4 micro-tile.
__global__ __launch_bounds__(256) void k_sgemm(const float* __restrict__ A,
                                               const float* __restrict__ B,
                                               float* __restrict__ C,
                                               int M, int Nc, int K) {
  __shared__ float As[16][65];
  __shared__ float Bs[16][65];
  int tid = threadIdx.x;
  int row0 = blockIdx.y * 64;
  int col0 = blockIdx.x * 64;
  int ty = tid >> 4, tx = tid & 15;
  int la_r = tid >> 2;           // 0..63 tile row for A load
  int la_k = (tid & 3) << 2;     // float4 k-offset
  int lb_k = tid >> 4;           // 0..15 tile k-row for B load
  int lb_c = (tid & 15) << 2;    // float4 col-offset
  float acc[4][4] = {};
  for (int k0 = 0; k0 < K; k0 += 16) {
    int ar = row0 + la_r;
    float4 av = make_float4(0.f, 0.f, 0.f, 0.f);
    if (ar < M) av = *(const float4*)(A + (size_t)ar * K + k0 + la_k);
    As[la_k + 0][la_r] = av.x;
    As[la_k + 1][la_r] = av.y;
    As[la_k + 2][la_r] = av.z;
    As[la_k + 3][la_r] = av.w;
    int br = k0 + lb_k;
    int bc = col0 + lb_c;
    float4 bv;
    if (bc + 3 < Nc) {
      bv = *(const float4*)(B + (size_t)br * Nc + bc);
    } else {
      bv.x = (bc + 0 < Nc) ? B[(size_t)br * Nc + bc + 0] : 0.f;
      bv.y = (bc + 1 < Nc) ? B[(size_t)br * Nc + bc + 1] : 0.f;
      bv.z = (bc + 2 < Nc) ? B[(size_t)br * Nc + bc + 2] : 0.f;
      bv.w = (bc + 3 < Nc) ? B[(size_t)br * Nc + bc + 3] : 0.f;
    }
    Bs[lb_k][lb_c + 0] = bv.x;
    Bs[lb_k][lb_c + 1] = bv.y;
    Bs[lb_k][lb_c + 2] = bv.z;
    Bs[lb_k][lb_c + 3] = bv.w;
    __syncthreads();
#pragma unroll
    for (int kk = 0; kk < 16; kk++) {
      float a0 = As[kk][ty * 4 + 0], a1 = As[kk][ty * 4 + 1];
      float a2 = As[kk][ty * 4 + 2], a3 = As[kk][ty * 4 + 3];
      float b0 = Bs[kk][tx * 4 + 0], b1 = Bs[kk][tx * 4 + 1];
      float b2 = Bs[kk][tx * 4 + 2], b3 = Bs[kk][tx * 4 + 3];
      acc[0][0] += a0 * b0; acc[0][1] += a0 * b1; acc[0][2] += a0 * b2; acc[0][3] += a0 * b3;
      acc[1][0] += a1 * b0; acc[1][1] += a1 * b1; acc[1][2] += a1 * b2; acc[1][3] += a1 * b3;
      acc[2][0] += a2 * b0; acc[2][1] += a2 * b1; acc[2][2] += a2 * b2; acc[2][3] += a2 * b3;
      acc[3][0] += a3 * b0; acc[3][1] += a3 * b1; acc[3][2] += a3 * b2; acc[3][3] += a3 * b3;
    }
    __syncthreads();
  }
#pragma unroll
  for (int i = 0; i < 4; i++) {
    int r = row0 + ty * 4 + i;
    if (r >= M) continue;
#pragma unroll
    for (int j = 0; j < 4; j++) {
      int c = col0 + tx * 4 + j;
      if (c < Nc) C[(size_t)r * Nc + c] = acc[i][j];
    }
  }
}

// a_s[n,h] = <h[n,h,:], att_src[h,:]>, a_d likewise. One thread per (n,h).
__global__ __launch_bounds__(256) void k_att(const float* __restrict__ hW,
                                             const float* __restrict__ attS,
                                             const float* __restrict__ attD,
                                             float* __restrict__ aS,
                                             float* __restrict__ aD, int NH, int H) {
  int idx = blockIdx.x * 256 + threadIdx.x;
  if (idx >= NH) return;
  int h = idx % H;
  const float4* hv = (const float4*)(hW + (size_t)idx * 32);
  const float4* sv = (const float4*)(attS + h * 32);
  const float4* dv = (const float4*)(attD + h * 32);
  float ss = 0.f, dd = 0.f;
#pragma unroll
  for (int k = 0; k < 8; k++) {
    float4 a = hv[k], b = sv[k], c = dv[k];
    ss += a.x * b.x + a.y * b.y + a.z * b.z + a.w * b.w;
    dd += a.x * c.x + a.y * c.y + a.z * c.z + a.w * c.w;
  }
  aS[idx] = ss;
  aD[idx] = dd;
}

// One wave per dst node: 2-pass softmax (max, sum) over in-edges with shuffle
// reductions, then serial-edge weighted gather; lane = (head-pair, channel).
template <int H, bool DO_ELU>
__global__ __launch_bounds__(256) void k_gat_agg(
    const float* __restrict__ hW, const float* __restrict__ aS,
    const float* __restrict__ aD, const int* __restrict__ rowptr,
    const int* __restrict__ colsrc, const float* __restrict__ bias,
    float* __restrict__ out, int N) {
  constexpr int C = 32;
  constexpr int HC = H * C;
  int wid = (blockIdx.x * blockDim.x + threadIdx.x) >> 6;
  int lane = threadIdx.x & 63;
  if (wid >= N) return;
  int n = wid;
  int row0 = rowptr[n];
  int deg = rowptr[n + 1] - row0;

  float adn[H], m[H], s[H];
#pragma unroll
  for (int h = 0; h < H; h++) {
    adn[h] = aD[(size_t)n * H + h];
    m[h] = -1e30f;
    s[h] = 0.f;
  }
  // pass 1: segment max
  for (int i = lane; i < deg; i += 64) {
    int src = colsrc[row0 + i];
#pragma unroll
    for (int h = 0; h < H; h++) {
      float e = aS[(size_t)src * H + h] + adn[h];
      e = (e > 0.f) ? e : 0.2f * e;
      m[h] = fmaxf(m[h], e);
    }
  }
#pragma unroll
  for (int h = 0; h < H; h++) {
#pragma unroll
    for (int off = 32; off > 0; off >>= 1) m[h] = fmaxf(m[h], __shfl_xor(m[h], off, 64));
  }
  // pass 2: segment sum of exp
  for (int i = lane; i < deg; i += 64) {
    int src = colsrc[row0 + i];
#pragma unroll
    for (int h = 0; h < H; h++) {
      float e = aS[(size_t)src * H + h] + adn[h];
      e = (e > 0.f) ? e : 0.2f * e;
      s[h] += __expf(e - m[h]);
    }
  }
#pragma unroll
  for (int h = 0; h < H; h++) {
#pragma unroll
    for (int off = 32; off > 0; off >>= 1) s[h] += __shfl_xor(s[h], off, 64);
  }
  float rs[H];
#pragma unroll
  for (int h = 0; h < H; h++) rs[h] = 1.f / s[h];

  if constexpr (H == 8) {
    // lane -> (h = 2*hp + (lane>>5), c = lane&31); offset in row = hp*64+lane
    int hbase = lane >> 5;
    float mh[4], rsh[4], adh[4], acc[4];
#pragma unroll
    for (int hp = 0; hp < 4; hp++) {
      mh[hp] = hbase ? m[2 * hp + 1] : m[2 * hp];
      rsh[hp] = hbase ? rs[2 * hp + 1] : rs[2 * hp];
      adh[hp] = hbase ? adn[2 * hp + 1] : adn[2 * hp];
      acc[hp] = 0.f;
    }
    for (int i = 0; i < deg; i++) {
      int src = colsrc[row0 + i];
      const float* hrow = hW + (size_t)src * HC;
#pragma unroll
      for (int hp = 0; hp < 4; hp++) {
        float e = aS[(size_t)src * 8 + 2 * hp + hbase] + adh[hp];
        e = (e > 0.f) ? e : 0.2f * e;
        float alpha = __expf(e - mh[hp]) * rsh[hp];
        acc[hp] += alpha * hrow[hp * 64 + lane];
      }
    }
#pragma unroll
    for (int hp = 0; hp < 4; hp++) {
      float v = acc[hp] + bias[hp * 64 + lane];
      if (DO_ELU) v = (v > 0.f) ? v : (__expf(v) - 1.f);
      out[(size_t)n * HC + hp * 64 + lane] = v;
    }
  } else {
    // H == 1: two edges in flight (lane>>5), 32 channels
    int c = lane & 31;
    int eo = lane >> 5;
    float acc = 0.f;
    for (int i = eo; i < deg; i += 2) {
      int src = colsrc[row0 + i];
      float e = aS[src] + adn[0];
      e = (e > 0.f) ? e : 0.2f * e;
      float alpha = __expf(e - m[0]) * rs[0];
      acc += alpha * hW[(size_t)src * C + c];
    }
    acc += __shfl_xor(acc, 32, 64);
    if (lane < 32) {
      float v = acc + bias[c];
      if (DO_ELU) v = (v > 0.f) ? v : (__expf(v) - 1.f);
      out[(size_t)n * C + c] = v;
    }
  }
}

// Fused mean-pool + linear. batch is sorted ascending, so graph g's nodes are
// the contiguous range [lower_bound(g), lower_bound(g+1)). One 256-thread
// block per graph: thread = (node-group 0..7) x (channel 0..31). No atomics.
__global__ __launch_bounds__(256) void k_pool_final(
    const float* __restrict__ h, const int* __restrict__ batch,
    const float* __restrict__ linW, const float* __restrict__ linb,
    float* __restrict__ out, int N) {
  __shared__ float sh[256];
  int g = blockIdx.x;
  int tid = threadIdx.x;
  int grp = tid >> 5, c = tid & 31;
  // lower_bound(batch, g) and lower_bound(batch, g+1)
  int lo = 0, hi = N;
  while (lo < hi) { int mid = (lo + hi) >> 1; if (batch[mid] < g) lo = mid + 1; else hi = mid; }
  int start = lo;
  hi = N;
  while (lo < hi) { int mid = (lo + hi) >> 1; if (batch[mid] < g + 1) lo = mid + 1; else hi = mid; }
  int end = lo;
  float acc = 0.f;
  for (int n = start + grp; n < end; n += 8) acc += h[(size_t)n * 32 + c];
  sh[tid] = acc;
  __syncthreads();
  if (tid < 32) {
    float s = 0.f;
#pragma unroll
    for (int j = 0; j < 8; j++) s += sh[j * 32 + tid];
    float v = s * linW[tid];
#pragma unroll
    for (int off = 16; off > 0; off >>= 1) v += __shfl_xor(v, off, 64);
    if (tid == 0) {
      float cnt = (float)(end - start);
      out[g] = v / fmaxf(cnt, 1.f) + linb[0];
    }
  }
}

extern "C" void kernel_launch(void* const* d_in, const int* in_sizes, int n_in,
                              void* d_out, int out_size, void* d_ws, size_t ws_size,
                              hipStream_t stream) {
  const float* x = (const float*)d_in[0];
  const int* ei = (const int*)d_in[1];      // int32! (JAX x64 disabled)
  const int* batch = (const int*)d_in[2];   // int32!
  const float* W1 = (const float*)d_in[3];
  const float* as1 = (const float*)d_in[4];
  const float* ad1 = (const float*)d_in[5];
  const float* b1 = (const float*)d_in[6];
  const float* W2 = (const float*)d_in[7];
  const float* as2 = (const float*)d_in[8];
  const float* ad2 = (const float*)d_in[9];
  const float* b2 = (const float*)d_in[10];
  const float* W3 = (const float*)d_in[11];
  const float* as3 = (const float*)d_in[12];
  const float* ad3 = (const float*)d_in[13];
  const float* b3 = (const float*)d_in[14];
  const float* linW = (const float*)d_in[15];
  const float* linb = (const float*)d_in[16];

  const int N = in_sizes[0] / 256;
  const int E = in_sizes[1] / 2;
  const int NUM_GRAPHS = 64;
  float* out = (float*)d_out;

  // --- workspace carve ---
  char* ws = (char*)d_ws;
  size_t off = 0;
  auto alloc = [&](size_t bytes) -> void* {
    void* p = ws + off;
    off += (bytes + 255) & ~(size_t)255;
    return p;
  };
  float* B1 = (float*)alloc((size_t)N * 256 * 4);
  float* B2 = (float*)alloc((size_t)N * 256 * 4);
  float* aS = (float*)alloc((size_t)N * 8 * 4);
  float* aD = (float*)alloc((size_t)N * 8 * 4);
  int* deg = (int*)alloc((size_t)N * 4);
  int* rowptr = (int*)alloc((size_t)(N + 1) * 4);
  int* cursor = (int*)alloc((size_t)(N + 1) * 4);
  int* colsrc = (int*)alloc((size_t)(E + N) * 4);
  // layer-3 buffers reuse B1's space (B1 holds h3 [N,32]; h3agg right after)
  float* h3 = B1;
  float* h3agg = B1 + (size_t)N * 32;

  // --- CSR build ---
  k_init_deg<<<(N + 255) / 256, 256, 0, stream>>>(deg, N);
  k_count_deg<<<(E + 255) / 256, 256, 0, stream>>>(ei, E, deg);
  k_scan<<<1, 1024, 0, stream>>>(deg, rowptr, cursor, N);
  k_scatter<<<(E + N + 255) / 256, 256, 0, stream>>>(ei, E, N, cursor, colsrc);

  const int aggBlocks = (N + 3) / 4;  // 4 waves/block, 1 node/wave

  // --- layer 1 ---
  {
    dim3 g((256 + 63) / 64, (N + 63) / 64);
    k_sgemm<<<g, 256, 0, stream>>>(x, W1, B1, N, 256, 256);
    k_att<<<(N * 8 + 255) / 256, 256, 0, stream>>>(B1, as1, ad1, aS, aD, N * 8, 8);
    k_gat_agg<8, true><<<aggBlocks, 256, 0, stream>>>(B1, aS, aD, rowptr, colsrc, b1, B2, N);
  }
  // --- layer 2 ---
  {
    dim3 g((256 + 63) / 64, (N + 63) / 64);
    k_sgemm<<<g, 256, 0, stream>>>(B2, W2, B1, N, 256, 256);
    k_att<<<(N * 8 + 255) / 256, 256, 0, stream>>>(B1, as2, ad2, aS, aD, N * 8, 8);
    k_gat_agg<8, true><<<aggBlocks, 256, 0, stream>>>(B1, aS, aD, rowptr, colsrc, b2, B2, N);
  }
  // --- layer 3 (H=1, no concat-mean needed, no ELU) ---
  {
    dim3 g((32 + 63) / 64, (N + 63) / 64);
    k_sgemm<<<g, 256, 0, stream>>>(B2, W3, h3, N, 32, 256);
    k_att<<<(N + 255) / 256, 256, 0, stream>>>(h3, as3, ad3, aS, aD, N, 1);
    k_gat_agg<1, false><<<aggBlocks, 256, 0, stream>>>(h3, aS, aD, rowptr, colsrc, b3, h3agg, N);
  }
  // --- fused mean-pool + final linear (sorted batch -> no atomics) ---
  k_pool_final<<<NUM_GRAPHS, 256, 0, stream>>>(h3agg, batch, linW, linb, out, N);
}

// Round 4
// 1031.236 us; speedup vs baseline: 1.3751x; 1.0305x over previous
//
#include <hip/hip_runtime.h>
#include <math.h>

// ---------------------------------------------------------------------------
// GATClassifier on MI355X.
//   1. CSR build over dst (histogram -> scan -> scatter)
//   2. Per layer: split-bf16 MFMA GEMM (h = X@W via Ah*Bh + Ah*Bl + Al*Bh,
//      fp32 acc; no fp32 MFMA on CDNA4), att dots, per-node wave softmax +
//      weighted gather agg. Agg epilogue for layers 1/2 emits split-bf16
//      directly (same bytes as fp32, feeds next GEMM).
//   3. Fused mean-pool + 32->1 linear (batch sorted -> binary search, 0 atomics)
// R2: atomic pool was 383us -> fixed R3. R3: fp32 SGEMM 158us x2 (VALU-bound,
// MfmaUtil 0) -> this round moves GEMMs to the matrix pipe.
// NOTE: edge_index / batch are int32.
// ---------------------------------------------------------------------------

typedef __attribute__((ext_vector_type(8))) __bf16 bf16x8;
typedef __attribute__((ext_vector_type(4))) float f32x4;

__device__ inline unsigned short f2bf(float f) {
  unsigned u = __float_as_uint(f);
  u += 0x7fff + ((u >> 16) & 1);  // RNE
  return (unsigned short)(u >> 16);
}
__device__ inline float bf2f(unsigned short h) {
  return __uint_as_float((unsigned)h << 16);
}

// ---------------- CSR build ----------------
__global__ __launch_bounds__(256) void k_init_deg(int* deg, int N) {
  int n = blockIdx.x * 256 + threadIdx.x;
  if (n < N) deg[n] = 1;  // self-loop
}

__global__ __launch_bounds__(256) void k_count_deg(const int* __restrict__ ei,
                                                   int E, int* deg) {
  int e = blockIdx.x * 256 + threadIdx.x;
  if (e < E) atomicAdd(&deg[ei[E + e]], 1);
}

__global__ __launch_bounds__(1024) void k_scan(const int* __restrict__ deg,
                                               int* __restrict__ rowptr,
                                               int* __restrict__ cursor, int N) {
  __shared__ int part[1024];
  int t = threadIdx.x;
  int chunk = (N + 1023) >> 10;
  int b = t * chunk;
  int e = min(b + chunk, N);
  int s = 0;
  for (int i = b; i < e; i++) s += deg[i];
  part[t] = s;
  __syncthreads();
  for (int off = 1; off < 1024; off <<= 1) {
    int v = (t >= off) ? part[t - off] : 0;
    __syncthreads();
    part[t] += v;
    __syncthreads();
  }
  int run = (t > 0) ? part[t - 1] : 0;
  for (int i = b; i < e; i++) {
    rowptr[i] = run;
    cursor[i] = run;
    run += deg[i];
  }
  if (t == 1023) rowptr[N] = part[1023];
}

__global__ __launch_bounds__(256) void k_scatter(const int* __restrict__ ei,
                                                 int E, int N, int* cursor,
                                                 int* __restrict__ colsrc) {
  int i = blockIdx.x * 256 + threadIdx.x;
  if (i < E) {
    int s = ei[i];
    int d = ei[E + i];
    int pos = atomicAdd(&cursor[d], 1);
    colsrc[pos] = s;
  } else if (i < E + N) {
    int nn = i - E;
    int pos = atomicAdd(&cursor[nn], 1);
    colsrc[pos] = nn;  // self loop
  }
}

// ---------------- split-cast preps ----------------
// fp32 -> (bf16 hi, bf16 lo residual), elementwise x4.
__global__ __launch_bounds__(256) void k_split(const float* __restrict__ in,
                                               unsigned short* __restrict__ oh,
                                               unsigned short* __restrict__ ol,
                                               int n4) {
  int i = blockIdx.x * 256 + threadIdx.x;
  if (i >= n4) return;
  float4 v = ((const float4*)in)[i];
  ushort4 h, l;
  h.x = f2bf(v.x); l.x = f2bf(v.x - bf2f(h.x));
  h.y = f2bf(v.y); l.y = f2bf(v.y - bf2f(h.y));
  h.z = f2bf(v.z); l.z = f2bf(v.z - bf2f(h.z));
  h.w = f2bf(v.w); l.w = f2bf(v.w - bf2f(h.w));
  ((ushort4*)oh)[i] = h;
  ((ushort4*)ol)[i] = l;
}

// W [K][Nc] fp32 -> WT hi/lo [Nc][K] bf16 (transposed so B-frags load b128).
__global__ __launch_bounds__(256) void k_wprep(const float* __restrict__ W,
                                               unsigned short* __restrict__ WTh,
                                               unsigned short* __restrict__ WTl,
                                               int K, int Nc) {
  int i = blockIdx.x * 256 + threadIdx.x;  // i = n*K + k
  if (i >= K * Nc) return;
  int n = i / K, k = i - n * K;
  float w = W[k * Nc + n];
  unsigned short h = f2bf(w);
  WTh[i] = h;
  WTl[i] = f2bf(w - bf2f(h));
}

// ---------------- split-bf16 MFMA GEMM ----------------
// C[M][Nc=NT*16] = (Ah+Al)[M][K] @ (Bh+Bl)[K][Nc], fp32 out.
// Block = 4 waves x 16 rows = 64 rows; each wave covers full Nc width
// (A read exactly once; WT is L2-resident broadcast). No LDS.
// mfma_f32_16x16x32_bf16 layouts (m89-verified):
//   A-frag: m=lane&15, k=quad*8+j  -> b128 from row-major A
//   B-frag: n=lane&15, k=quad*8+j  -> b128 from WT[n][k]
//   C/D   : row=quad*4+reg, col=lane&15
template <int NT>
__global__ __launch_bounds__(256) void k_gemm_split(
    const unsigned short* __restrict__ Ah, const unsigned short* __restrict__ Al,
    const unsigned short* __restrict__ BTh, const unsigned short* __restrict__ BTl,
    float* __restrict__ C, int M, int K) {
  constexpr int Nc = NT * 16;
  int lane = threadIdx.x & 63;
  int wave = threadIdx.x >> 6;
  int quad = lane >> 4;
  int l16 = lane & 15;
  int m0 = blockIdx.x * 64 + wave * 16;
  int am = min(m0 + l16, M - 1);  // clamp: rows >= M never stored
  const unsigned short* arh = Ah + (size_t)am * K + quad * 8;
  const unsigned short* arl = Al + (size_t)am * K + quad * 8;
  f32x4 acc[NT];
#pragma unroll
  for (int t = 0; t < NT; t++) acc[t] = (f32x4){0.f, 0.f, 0.f, 0.f};
  for (int k0 = 0; k0 < K; k0 += 32) {
    bf16x8 a_h = *(const bf16x8*)(arh + k0);
    bf16x8 a_l = *(const bf16x8*)(arl + k0);
#pragma unroll
    for (int t = 0; t < NT; t++) {
      size_t boff = (size_t)(t * 16 + l16) * K + k0 + quad * 8;
      bf16x8 b_h = *(const bf16x8*)(BTh + boff);
      bf16x8 b_l = *(const bf16x8*)(BTl + boff);
      acc[t] = __builtin_amdgcn_mfma_f32_16x16x32_bf16(a_h, b_h, acc[t], 0, 0, 0);
      acc[t] = __builtin_amdgcn_mfma_f32_16x16x32_bf16(a_h, b_l, acc[t], 0, 0, 0);
      acc[t] = __builtin_amdgcn_mfma_f32_16x16x32_bf16(a_l, b_h, acc[t], 0, 0, 0);
    }
  }
#pragma unroll
  for (int t = 0; t < NT; t++) {
#pragma unroll
    for (int r = 0; r < 4; r++) {
      int m = m0 + quad * 4 + r;
      if (m < M) C[(size_t)m * Nc + t * 16 + l16] = acc[t][r];
    }
  }
}

// ---------------- attention dots ----------------
__global__ __launch_bounds__(256) void k_att(const float* __restrict__ hW,
                                             const float* __restrict__ attS,
                                             const float* __restrict__ attD,
                                             float* __restrict__ aS,
                                             float* __restrict__ aD, int NH, int H) {
  int idx = blockIdx.x * 256 + threadIdx.x;
  if (idx >= NH) return;
  int h = idx % H;
  const float4* hv = (const float4*)(hW + (size_t)idx * 32);
  const float4* sv = (const float4*)(attS + h * 32);
  const float4* dv = (const float4*)(attD + h * 32);
  float ss = 0.f, dd = 0.f;
#pragma unroll
  for (int k = 0; k < 8; k++) {
    float4 a = hv[k], b = sv[k], c = dv[k];
    ss += a.x * b.x + a.y * b.y + a.z * b.z + a.w * b.w;
    dd += a.x * c.x + a.y * c.y + a.z * c.z + a.w * c.w;
  }
  aS[idx] = ss;
  aD[idx] = dd;
}

// ---------------- GAT aggregation ----------------
// One wave per dst node: 2-pass softmax over in-edges (shuffle reductions),
// then serial-edge weighted gather. SPLIT: emit bf16 hi/lo (feeds next GEMM).
template <int H, bool DO_ELU, bool SPLIT>
__global__ __launch_bounds__(256) void k_gat_agg(
    const float* __restrict__ hW, const float* __restrict__ aS,
    const float* __restrict__ aD, const int* __restrict__ rowptr,
    const int* __restrict__ colsrc, const float* __restrict__ bias,
    float* __restrict__ out, unsigned short* __restrict__ outh,
    unsigned short* __restrict__ outl, int N) {
  constexpr int C = 32;
  constexpr int HC = H * C;
  int wid = (blockIdx.x * blockDim.x + threadIdx.x) >> 6;
  int lane = threadIdx.x & 63;
  if (wid >= N) return;
  int n = wid;
  int row0 = rowptr[n];
  int deg = rowptr[n + 1] - row0;

  float adn[H], m[H], s[H];
#pragma unroll
  for (int h = 0; h < H; h++) {
    adn[h] = aD[(size_t)n * H + h];
    m[h] = -1e30f;
    s[h] = 0.f;
  }
  for (int i = lane; i < deg; i += 64) {
    int src = colsrc[row0 + i];
#pragma unroll
    for (int h = 0; h < H; h++) {
      float e = aS[(size_t)src * H + h] + adn[h];
      e = (e > 0.f) ? e : 0.2f * e;
      m[h] = fmaxf(m[h], e);
    }
  }
#pragma unroll
  for (int h = 0; h < H; h++) {
#pragma unroll
    for (int off = 32; off > 0; off >>= 1) m[h] = fmaxf(m[h], __shfl_xor(m[h], off, 64));
  }
  for (int i = lane; i < deg; i += 64) {
    int src = colsrc[row0 + i];
#pragma unroll
    for (int h = 0; h < H; h++) {
      float e = aS[(size_t)src * H + h] + adn[h];
      e = (e > 0.f) ? e : 0.2f * e;
      s[h] += __expf(e - m[h]);
    }
  }
#pragma unroll
  for (int h = 0; h < H; h++) {
#pragma unroll
    for (int off = 32; off > 0; off >>= 1) s[h] += __shfl_xor(s[h], off, 64);
  }
  float rs[H];
#pragma unroll
  for (int h = 0; h < H; h++) rs[h] = 1.f / s[h];

  if constexpr (H == 8) {
    int hbase = lane >> 5;
    float mh[4], rsh[4], adh[4], acc[4];
#pragma unroll
    for (int hp = 0; hp < 4; hp++) {
      mh[hp] = hbase ? m[2 * hp + 1] : m[2 * hp];
      rsh[hp] = hbase ? rs[2 * hp + 1] : rs[2 * hp];
      adh[hp] = hbase ? adn[2 * hp + 1] : adn[2 * hp];
      acc[hp] = 0.f;
    }
    for (int i = 0; i < deg; i++) {
      int src = colsrc[row0 + i];
      const float* hrow = hW + (size_t)src * HC;
#pragma unroll
      for (int hp = 0; hp < 4; hp++) {
        float e = aS[(size_t)src * 8 + 2 * hp + hbase] + adh[hp];
        e = (e > 0.f) ? e : 0.2f * e;
        float alpha = __expf(e - mh[hp]) * rsh[hp];
        acc[hp] += alpha * hrow[hp * 64 + lane];
      }
    }
#pragma unroll
    for (int hp = 0; hp < 4; hp++) {
      float v = acc[hp] + bias[hp * 64 + lane];
      if (DO_ELU) v = (v > 0.f) ? v : (__expf(v) - 1.f);
      if constexpr (SPLIT) {
        unsigned short hb = f2bf(v);
        outh[(size_t)n * HC + hp * 64 + lane] = hb;
        outl[(size_t)n * HC + hp * 64 + lane] = f2bf(v - bf2f(hb));
      } else {
        out[(size_t)n * HC + hp * 64 + lane] = v;
      }
    }
  } else {
    int c = lane & 31;
    int eo = lane >> 5;
    float acc = 0.f;
    for (int i = eo; i < deg; i += 2) {
      int src = colsrc[row0 + i];
      float e = aS[src] + adn[0];
      e = (e > 0.f) ? e : 0.2f * e;
      float alpha = __expf(e - m[0]) * rs[0];
      acc += alpha * hW[(size_t)src * C + c];
    }
    acc += __shfl_xor(acc, 32, 64);
    if (lane < 32) {
      float v = acc + bias[c];
      if (DO_ELU) v = (v > 0.f) ? v : (__expf(v) - 1.f);
      out[(size_t)n * C + c] = v;
    }
  }
}

// ---------------- fused mean-pool + linear ----------------
__global__ __launch_bounds__(256) void k_pool_final(
    const float* __restrict__ h, const int* __restrict__ batch,
    const float* __restrict__ linW, const float* __restrict__ linb,
    float* __restrict__ out, int N) {
  __shared__ float sh[256];
  int g = blockIdx.x;
  int tid = threadIdx.x;
  int grp = tid >> 5, c = tid & 31;
  int lo = 0, hi = N;
  while (lo < hi) { int mid = (lo + hi) >> 1; if (batch[mid] < g) lo = mid + 1; else hi = mid; }
  int start = lo;
  hi = N;
  while (lo < hi) { int mid = (lo + hi) >> 1; if (batch[mid] < g + 1) lo = mid + 1; else hi = mid; }
  int end = lo;
  float acc = 0.f;
  for (int n = start + grp; n < end; n += 8) acc += h[(size_t)n * 32 + c];
  sh[tid] = acc;
  __syncthreads();
  if (tid < 32) {
    float s = 0.f;
#pragma unroll
    for (int j = 0; j < 8; j++) s += sh[j * 32 + tid];
    float v = s * linW[tid];
#pragma unroll
    for (int off = 16; off > 0; off >>= 1) v += __shfl_xor(v, off, 64);
    if (tid == 0) {
      float cnt = (float)(end - start);
      out[g] = v / fmaxf(cnt, 1.f) + linb[0];
    }
  }
}

extern "C" void kernel_launch(void* const* d_in, const int* in_sizes, int n_in,
                              void* d_out, int out_size, void* d_ws, size_t ws_size,
                              hipStream_t stream) {
  const float* x = (const float*)d_in[0];
  const int* ei = (const int*)d_in[1];
  const int* batch = (const int*)d_in[2];
  const float* W1 = (const float*)d_in[3];
  const float* as1 = (const float*)d_in[4];
  const float* ad1 = (const float*)d_in[5];
  const float* b1 = (const float*)d_in[6];
  const float* W2 = (const float*)d_in[7];
  const float* as2 = (const float*)d_in[8];
  const float* ad2 = (const float*)d_in[9];
  const float* b2 = (const float*)d_in[10];
  const float* W3 = (const float*)d_in[11];
  const float* as3 = (const float*)d_in[12];
  const float* ad3 = (const float*)d_in[13];
  const float* b3 = (const float*)d_in[14];
  const float* linW = (const float*)d_in[15];
  const float* linb = (const float*)d_in[16];

  const int N = in_sizes[0] / 256;
  const int E = in_sizes[1] / 2;
  const int NUM_GRAPHS = 64;
  float* out = (float*)d_out;

  char* ws = (char*)d_ws;
  size_t off = 0;
  auto alloc = [&](size_t bytes) -> void* {
    void* p = ws + off;
    off += (bytes + 255) & ~(size_t)255;
    return p;
  };
  float* B1 = (float*)alloc((size_t)N * 256 * 4);          // fp32 GEMM outputs
  unsigned short* Ah = (unsigned short*)alloc((size_t)N * 256 * 2);  // split inputs
  unsigned short* Al = (unsigned short*)alloc((size_t)N * 256 * 2);
  float* aS = (float*)alloc((size_t)N * 8 * 4);
  float* aD = (float*)alloc((size_t)N * 8 * 4);
  int* deg = (int*)alloc((size_t)N * 4);
  int* rowptr = (int*)alloc((size_t)(N + 1) * 4);
  int* cursor = (int*)alloc((size_t)(N + 1) * 4);
  int* colsrc = (int*)alloc((size_t)(E + N) * 4);
  unsigned short* WT1h = (unsigned short*)alloc(256 * 256 * 2);
  unsigned short* WT1l = (unsigned short*)alloc(256 * 256 * 2);
  unsigned short* WT2h = (unsigned short*)alloc(256 * 256 * 2);
  unsigned short* WT2l = (unsigned short*)alloc(256 * 256 * 2);
  unsigned short* WT3h = (unsigned short*)alloc(32 * 256 * 2);
  unsigned short* WT3l = (unsigned short*)alloc(32 * 256 * 2);
  // h3agg reuses Ah (free after GEMM3 consumed it); [N,32] fp32 fits in 25.6MB
  float* h3agg = (float*)Ah;

  // --- preps: x split + W transposes/splits + CSR build ---
  k_split<<<(N * 64 + 255) / 256, 256, 0, stream>>>(x, Ah, Al, N * 64);
  k_wprep<<<(256 * 256 + 255) / 256, 256, 0, stream>>>(W1, WT1h, WT1l, 256, 256);
  k_wprep<<<(256 * 256 + 255) / 256, 256, 0, stream>>>(W2, WT2h, WT2l, 256, 256);
  k_wprep<<<(256 * 32 + 255) / 256, 256, 0, stream>>>(W3, WT3h, WT3l, 256, 32);
  k_init_deg<<<(N + 255) / 256, 256, 0, stream>>>(deg, N);
  k_count_deg<<<(E + 255) / 256, 256, 0, stream>>>(ei, E, deg);
  k_scan<<<1, 1024, 0, stream>>>(deg, rowptr, cursor, N);
  k_scatter<<<(E + N + 255) / 256, 256, 0, stream>>>(ei, E, N, cursor, colsrc);

  const int aggBlocks = (N + 3) / 4;
  const int gemmBlocks = (N + 63) / 64;

  // --- layer 1 ---
  k_gemm_split<16><<<gemmBlocks, 256, 0, stream>>>(Ah, Al, WT1h, WT1l, B1, N, 256);
  k_att<<<(N * 8 + 255) / 256, 256, 0, stream>>>(B1, as1, ad1, aS, aD, N * 8, 8);
  k_gat_agg<8, true, true><<<aggBlocks, 256, 0, stream>>>(
      B1, aS, aD, rowptr, colsrc, b1, nullptr, Ah, Al, N);
  // --- layer 2 ---
  k_gemm_split<16><<<gemmBlocks, 256, 0, stream>>>(Ah, Al, WT2h, WT2l, B1, N, 256);
  k_att<<<(N * 8 + 255) / 256, 256, 0, stream>>>(B1, as2, ad2, aS, aD, N * 8, 8);
  k_gat_agg<8, true, true><<<aggBlocks, 256, 0, stream>>>(
      B1, aS, aD, rowptr, colsrc, b2, nullptr, Ah, Al, N);
  // --- layer 3 (H=1, fp32 out) ---
  k_gemm_split<2><<<gemmBlocks, 256, 0, stream>>>(Ah, Al, WT3h, WT3l, B1, N, 256);
  k_att<<<(N + 255) / 256, 256, 0, stream>>>(B1, as3, ad3, aS, aD, N, 1);
  k_gat_agg<1, false, false><<<aggBlocks, 256, 0, stream>>>(
      B1, aS, aD, rowptr, colsrc, b3, h3agg, nullptr, nullptr, N);
  // --- pool + final ---
  k_pool_final<<<NUM_GRAPHS, 256, 0, stream>>>(h3agg, batch, linW, linb, out, N);
}

// Round 5
// 988.808 us; speedup vs baseline: 1.4341x; 1.0429x over previous
//
#include <hip/hip_runtime.h>
#include <math.h>

// ---------------------------------------------------------------------------
// GATClassifier on MI355X.
//   1. CSR build over dst (histogram -> scan -> scatter)
//   2. Per layer: split-bf16 MFMA GEMM (Ah*Bh + Ah*Bl + Al*Bh, fp32 acc)
//      writing h as bf16 hi+lo; att dots read hi+lo (exact); per-node wave
//      softmax (no-max: exp(e)/sum, identical math, |e|<~2) + weighted
//      gather reading h-HI ONLY (halves gather traffic; R4: agg FETCH 446MB,
//      155us x2 was the top). Agg epilogue emits split-bf16 for next GEMM.
//   3. Fused mean-pool + 32->1 linear (batch sorted -> binary search, 0 atomics)
// R2: atomic pool 383us -> R3 fixed. R3: fp32 SGEMM 158us x2 -> R4 MFMA.
// NOTE: edge_index / batch are int32.
// ---------------------------------------------------------------------------

typedef __attribute__((ext_vector_type(8))) __bf16 bf16x8;
typedef __attribute__((ext_vector_type(4))) __bf16 bf16x4;
typedef __attribute__((ext_vector_type(4))) float f32x4;

// ---------------- CSR build ----------------
__global__ __launch_bounds__(256) void k_init_deg(int* deg, int N) {
  int n = blockIdx.x * 256 + threadIdx.x;
  if (n < N) deg[n] = 1;  // self-loop
}

__global__ __launch_bounds__(256) void k_count_deg(const int* __restrict__ ei,
                                                   int E, int* deg) {
  int e = blockIdx.x * 256 + threadIdx.x;
  if (e < E) atomicAdd(&deg[ei[E + e]], 1);
}

__global__ __launch_bounds__(1024) void k_scan(const int* __restrict__ deg,
                                               int* __restrict__ rowptr,
                                               int* __restrict__ cursor, int N) {
  __shared__ int part[1024];
  int t = threadIdx.x;
  int chunk = (N + 1023) >> 10;
  int b = t * chunk;
  int e = min(b + chunk, N);
  int s = 0;
  for (int i = b; i < e; i++) s += deg[i];
  part[t] = s;
  __syncthreads();
  for (int off = 1; off < 1024; off <<= 1) {
    int v = (t >= off) ? part[t - off] : 0;
    __syncthreads();
    part[t] += v;
    __syncthreads();
  }
  int run = (t > 0) ? part[t - 1] : 0;
  for (int i = b; i < e; i++) {
    rowptr[i] = run;
    cursor[i] = run;
    run += deg[i];
  }
  if (t == 1023) rowptr[N] = part[1023];
}

__global__ __launch_bounds__(256) void k_scatter(const int* __restrict__ ei,
                                                 int E, int N, int* cursor,
                                                 int* __restrict__ colsrc) {
  int i = blockIdx.x * 256 + threadIdx.x;
  if (i < E) {
    int s = ei[i];
    int d = ei[E + i];
    int pos = atomicAdd(&cursor[d], 1);
    colsrc[pos] = s;
  } else if (i < E + N) {
    int nn = i - E;
    int pos = atomicAdd(&cursor[nn], 1);
    colsrc[pos] = nn;  // self loop
  }
}

// ---------------- split-cast preps ----------------
__global__ __launch_bounds__(256) void k_split(const float* __restrict__ in,
                                               __bf16* __restrict__ oh,
                                               __bf16* __restrict__ ol, int n4) {
  int i = blockIdx.x * 256 + threadIdx.x;
  if (i >= n4) return;
  float4 v = ((const float4*)in)[i];
  bf16x4 h, l;
  h[0] = (__bf16)v.x; l[0] = (__bf16)(v.x - (float)h[0]);
  h[1] = (__bf16)v.y; l[1] = (__bf16)(v.y - (float)h[1]);
  h[2] = (__bf16)v.z; l[2] = (__bf16)(v.z - (float)h[2]);
  h[3] = (__bf16)v.w; l[3] = (__bf16)(v.w - (float)h[3]);
  ((bf16x4*)oh)[i] = h;
  ((bf16x4*)ol)[i] = l;
}

// W [K][Nc] fp32 -> WT hi/lo [Nc][K] bf16 (transposed so B-frags load b128).
__global__ __launch_bounds__(256) void k_wprep(const float* __restrict__ W,
                                               __bf16* __restrict__ WTh,
                                               __bf16* __restrict__ WTl,
                                               int K, int Nc) {
  int i = blockIdx.x * 256 + threadIdx.x;  // i = n*K + k
  if (i >= K * Nc) return;
  int n = i / K, k = i - n * K;
  float w = W[k * Nc + n];
  __bf16 h = (__bf16)w;
  WTh[i] = h;
  WTl[i] = (__bf16)(w - (float)h);
}

// ---------------- split-bf16 MFMA GEMM ----------------
// (Ch+Cl)[M][Nc=NT*16] = (Ah+Al)[M][K] @ (Bh+Bl)[K][Nc]; output split bf16.
// Block = 4 waves x 16 rows; each wave spans full Nc (A read once). No LDS.
// mfma_f32_16x16x32_bf16 (m89-verified): A: m=lane&15,k=quad*8+j;
// B: n=lane&15,k=quad*8+j (from WT); C/D: row=quad*4+reg, col=lane&15.
template <int NT>
__global__ __launch_bounds__(256) void k_gemm_split(
    const __bf16* __restrict__ Ah, const __bf16* __restrict__ Al,
    const __bf16* __restrict__ BTh, const __bf16* __restrict__ BTl,
    __bf16* __restrict__ Ch, __bf16* __restrict__ Cl, int M, int K) {
  constexpr int Nc = NT * 16;
  int lane = threadIdx.x & 63;
  int wave = threadIdx.x >> 6;
  int quad = lane >> 4;
  int l16 = lane & 15;
  int m0 = blockIdx.x * 64 + wave * 16;
  int am = min(m0 + l16, M - 1);  // clamp: rows >= M never stored
  const __bf16* arh = Ah + (size_t)am * K + quad * 8;
  const __bf16* arl = Al + (size_t)am * K + quad * 8;
  f32x4 acc[NT];
#pragma unroll
  for (int t = 0; t < NT; t++) acc[t] = (f32x4){0.f, 0.f, 0.f, 0.f};
  for (int k0 = 0; k0 < K; k0 += 32) {
    bf16x8 a_h = *(const bf16x8*)(arh + k0);
    bf16x8 a_l = *(const bf16x8*)(arl + k0);
#pragma unroll
    for (int t = 0; t < NT; t++) {
      size_t boff = (size_t)(t * 16 + l16) * K + k0 + quad * 8;
      bf16x8 b_h = *(const bf16x8*)(BTh + boff);
      bf16x8 b_l = *(const bf16x8*)(BTl + boff);
      acc[t] = __builtin_amdgcn_mfma_f32_16x16x32_bf16(a_h, b_h, acc[t], 0, 0, 0);
      acc[t] = __builtin_amdgcn_mfma_f32_16x16x32_bf16(a_h, b_l, acc[t], 0, 0, 0);
      acc[t] = __builtin_amdgcn_mfma_f32_16x16x32_bf16(a_l, b_h, acc[t], 0, 0, 0);
    }
  }
#pragma unroll
  for (int t = 0; t < NT; t++) {
#pragma unroll
    for (int r = 0; r < 4; r++) {
      int m = m0 + quad * 4 + r;
      if (m < M) {
        float v = acc[t][r];
        __bf16 hb = (__bf16)v;
        size_t o = (size_t)m * Nc + t * 16 + l16;
        Ch[o] = hb;
        Cl[o] = (__bf16)(v - (float)hb);
      }
    }
  }
}

// ---------------- attention dots (hi+lo, exact) ----------------
__global__ __launch_bounds__(256) void k_att(const __bf16* __restrict__ Hh,
                                             const __bf16* __restrict__ Hl,
                                             const float* __restrict__ attS,
                                             const float* __restrict__ attD,
                                             float* __restrict__ aS,
                                             float* __restrict__ aD, int NH, int H) {
  int idx = blockIdx.x * 256 + threadIdx.x;
  if (idx >= NH) return;
  int h = idx % H;
  const bf16x8* hv = (const bf16x8*)(Hh + (size_t)idx * 32);
  const bf16x8* lv = (const bf16x8*)(Hl + (size_t)idx * 32);
  const float* sv = attS + h * 32;
  const float* dv = attD + h * 32;
  float ss = 0.f, dd = 0.f;
#pragma unroll
  for (int k = 0; k < 4; k++) {
    bf16x8 a = hv[k], b = lv[k];
#pragma unroll
    for (int j = 0; j < 8; j++) {
      float v = (float)a[j] + (float)b[j];
      ss += v * sv[k * 8 + j];
      dd += v * dv[k * 8 + j];
    }
  }
  aS[idx] = ss;
  aD[idx] = dd;
}

// ---------------- GAT aggregation ----------------
// One wave per dst node. No-max softmax (exp(e)/sum — identical math, |e|<~2):
// pass 1 sums exp over in-edges (shuffle reduce), pass 2 serial-edge weighted
// gather of bf16-HI rows. SPLIT: emit bf16 hi/lo for the next GEMM.
template <int H, bool DO_ELU, bool SPLIT>
__global__ __launch_bounds__(256) void k_gat_agg(
    const __bf16* __restrict__ Hh, const float* __restrict__ aS,
    const float* __restrict__ aD, const int* __restrict__ rowptr,
    const int* __restrict__ colsrc, const float* __restrict__ bias,
    float* __restrict__ out, __bf16* __restrict__ outh,
    __bf16* __restrict__ outl, int N) {
  constexpr int C = 32;
  constexpr int HC = H * C;
  int wid = (blockIdx.x * blockDim.x + threadIdx.x) >> 6;
  int lane = threadIdx.x & 63;
  if (wid >= N) return;
  int n = wid;
  int row0 = rowptr[n];
  int deg = rowptr[n + 1] - row0;

  float adn[H], s[H];
#pragma unroll
  for (int h = 0; h < H; h++) {
    adn[h] = aD[(size_t)n * H + h];
    s[h] = 0.f;
  }
  // pass 1: sum of exp(leaky(e))
  for (int i = lane; i < deg; i += 64) {
    int src = colsrc[row0 + i];
#pragma unroll
    for (int h = 0; h < H; h++) {
      float e = aS[(size_t)src * H + h] + adn[h];
      e = (e > 0.f) ? e : 0.2f * e;
      s[h] += __expf(e);
    }
  }
#pragma unroll
  for (int h = 0; h < H; h++) {
#pragma unroll
    for (int off = 32; off > 0; off >>= 1) s[h] += __shfl_xor(s[h], off, 64);
  }
  float rs[H];
#pragma unroll
  for (int h = 0; h < H; h++) rs[h] = 1.f / s[h];

  if constexpr (H == 8) {
    // lane -> (h = 2*hp + (lane>>5), c = lane&31); offset in row = hp*64+lane
    int hbase = lane >> 5;
    float rsh[4], adh[4], acc[4];
#pragma unroll
    for (int hp = 0; hp < 4; hp++) {
      rsh[hp] = hbase ? rs[2 * hp + 1] : rs[2 * hp];
      adh[hp] = hbase ? adn[2 * hp + 1] : adn[2 * hp];
      acc[hp] = 0.f;
    }
    for (int i = 0; i < deg; i++) {
      int src = colsrc[row0 + i];
      const __bf16* hrow = Hh + (size_t)src * HC;
#pragma unroll
      for (int hp = 0; hp < 4; hp++) {
        float e = aS[(size_t)src * 8 + 2 * hp + hbase] + adh[hp];
        e = (e > 0.f) ? e : 0.2f * e;
        float alpha = __expf(e) * rsh[hp];
        acc[hp] += alpha * (float)hrow[hp * 64 + lane];
      }
    }
#pragma unroll
    for (int hp = 0; hp < 4; hp++) {
      float v = acc[hp] + bias[hp * 64 + lane];
      if (DO_ELU) v = (v > 0.f) ? v : (__expf(v) - 1.f);
      if constexpr (SPLIT) {
        __bf16 hb = (__bf16)v;
        outh[(size_t)n * HC + hp * 64 + lane] = hb;
        outl[(size_t)n * HC + hp * 64 + lane] = (__bf16)(v - (float)hb);
      } else {
        out[(size_t)n * HC + hp * 64 + lane] = v;
      }
    }
  } else {
    // H == 1: two edges in flight (lane>>5), 32 channels
    int c = lane & 31;
    int eo = lane >> 5;
    float acc = 0.f;
    for (int i = eo; i < deg; i += 2) {
      int src = colsrc[row0 + i];
      float e = aS[src] + adn[0];
      e = (e > 0.f) ? e : 0.2f * e;
      float alpha = __expf(e) * rs[0];
      acc += alpha * (float)Hh[(size_t)src * C + c];
    }
    acc += __shfl_xor(acc, 32, 64);
    if (lane < 32) {
      float v = acc + bias[c];
      if (DO_ELU) v = (v > 0.f) ? v : (__expf(v) - 1.f);
      out[(size_t)n * C + c] = v;
    }
  }
}

// ---------------- fused mean-pool + linear ----------------
__global__ __launch_bounds__(256) void k_pool_final(
    const float* __restrict__ h, const int* __restrict__ batch,
    const float* __restrict__ linW, const float* __restrict__ linb,
    float* __restrict__ out, int N) {
  __shared__ float sh[256];
  int g = blockIdx.x;
  int tid = threadIdx.x;
  int grp = tid >> 5, c = tid & 31;
  int lo = 0, hi = N;
  while (lo < hi) { int mid = (lo + hi) >> 1; if (batch[mid] < g) lo = mid + 1; else hi = mid; }
  int start = lo;
  hi = N;
  while (lo < hi) { int mid = (lo + hi) >> 1; if (batch[mid] < g + 1) lo = mid + 1; else hi = mid; }
  int end = lo;
  float acc = 0.f;
  for (int n = start + grp; n < end; n += 8) acc += h[(size_t)n * 32 + c];
  sh[tid] = acc;
  __syncthreads();
  if (tid < 32) {
    float s = 0.f;
#pragma unroll
    for (int j = 0; j < 8; j++) s += sh[j * 32 + tid];
    float v = s * linW[tid];
#pragma unroll
    for (int off = 16; off > 0; off >>= 1) v += __shfl_xor(v, off, 64);
    if (tid == 0) {
      float cnt = (float)(end - start);
      out[g] = v / fmaxf(cnt, 1.f) + linb[0];
    }
  }
}

extern "C" void kernel_launch(void* const* d_in, const int* in_sizes, int n_in,
                              void* d_out, int out_size, void* d_ws, size_t ws_size,
                              hipStream_t stream) {
  const float* x = (const float*)d_in[0];
  const int* ei = (const int*)d_in[1];
  const int* batch = (const int*)d_in[2];
  const float* W1 = (const float*)d_in[3];
  const float* as1 = (const float*)d_in[4];
  const float* ad1 = (const float*)d_in[5];
  const float* b1 = (const float*)d_in[6];
  const float* W2 = (const float*)d_in[7];
  const float* as2 = (const float*)d_in[8];
  const float* ad2 = (const float*)d_in[9];
  const float* b2 = (const float*)d_in[10];
  const float* W3 = (const float*)d_in[11];
  const float* as3 = (const float*)d_in[12];
  const float* ad3 = (const float*)d_in[13];
  const float* b3 = (const float*)d_in[14];
  const float* linW = (const float*)d_in[15];
  const float* linb = (const float*)d_in[16];

  const int N = in_sizes[0] / 256;
  const int E = in_sizes[1] / 2;
  const int NUM_GRAPHS = 64;
  float* out = (float*)d_out;

  char* ws = (char*)d_ws;
  size_t off = 0;
  auto alloc = [&](size_t bytes) -> void* {
    void* p = ws + off;
    off += (bytes + 255) & ~(size_t)255;
    return p;
  };
  __bf16* Hh = (__bf16*)alloc((size_t)N * 256 * 2);  // GEMM h out (hi)
  __bf16* Hl = (__bf16*)alloc((size_t)N * 256 * 2);  //            (lo)
  __bf16* Ah = (__bf16*)alloc((size_t)N * 256 * 2);  // GEMM A in (hi)
  __bf16* Al = (__bf16*)alloc((size_t)N * 256 * 2);  //           (lo)
  float* aS = (float*)alloc((size_t)N * 8 * 4);
  float* aD = (float*)alloc((size_t)N * 8 * 4);
  int* deg = (int*)alloc((size_t)N * 4);
  int* rowptr = (int*)alloc((size_t)(N + 1) * 4);
  int* cursor = (int*)alloc((size_t)(N + 1) * 4);
  int* colsrc = (int*)alloc((size_t)(E + N) * 4);
  __bf16* WT1h = (__bf16*)alloc(256 * 256 * 2);
  __bf16* WT1l = (__bf16*)alloc(256 * 256 * 2);
  __bf16* WT2h = (__bf16*)alloc(256 * 256 * 2);
  __bf16* WT2l = (__bf16*)alloc(256 * 256 * 2);
  __bf16* WT3h = (__bf16*)alloc(32 * 256 * 2);
  __bf16* WT3l = (__bf16*)alloc(32 * 256 * 2);
  // h3agg reuses Ah (GEMM3 already consumed it when agg3 writes)
  float* h3agg = (float*)Ah;

  // --- preps: x split + W transposes/splits + CSR build ---
  k_split<<<(N * 64 + 255) / 256, 256, 0, stream>>>(x, Ah, Al, N * 64);
  k_wprep<<<(256 * 256 + 255) / 256, 256, 0, stream>>>(W1, WT1h, WT1l, 256, 256);
  k_wprep<<<(256 * 256 + 255) / 256, 256, 0, stream>>>(W2, WT2h, WT2l, 256, 256);
  k_wprep<<<(256 * 32 + 255) / 256, 256, 0, stream>>>(W3, WT3h, WT3l, 256, 32);
  k_init_deg<<<(N + 255) / 256, 256, 0, stream>>>(deg, N);
  k_count_deg<<<(E + 255) / 256, 256, 0, stream>>>(ei, E, deg);
  k_scan<<<1, 1024, 0, stream>>>(deg, rowptr, cursor, N);
  k_scatter<<<(E + N + 255) / 256, 256, 0, stream>>>(ei, E, N, cursor, colsrc);

  const int aggBlocks = (N + 3) / 4;
  const int gemmBlocks = (N + 63) / 64;

  // --- layer 1 ---
  k_gemm_split<16><<<gemmBlocks, 256, 0, stream>>>(Ah, Al, WT1h, WT1l, Hh, Hl, N, 256);
  k_att<<<(N * 8 + 255) / 256, 256, 0, stream>>>(Hh, Hl, as1, ad1, aS, aD, N * 8, 8);
  k_gat_agg<8, true, true><<<aggBlocks, 256, 0, stream>>>(
      Hh, aS, aD, rowptr, colsrc, b1, nullptr, Ah, Al, N);
  // --- layer 2 ---
  k_gemm_split<16><<<gemmBlocks, 256, 0, stream>>>(Ah, Al, WT2h, WT2l, Hh, Hl, N, 256);
  k_att<<<(N * 8 + 255) / 256, 256, 0, stream>>>(Hh, Hl, as2, ad2, aS, aD, N * 8, 8);
  k_gat_agg<8, true, true><<<aggBlocks, 256, 0, stream>>>(
      Hh, aS, aD, rowptr, colsrc, b2, nullptr, Ah, Al, N);
  // --- layer 3 (H=1, fp32 out) ---
  k_gemm_split<2><<<gemmBlocks, 256, 0, stream>>>(Ah, Al, WT3h, WT3l, Hh, Hl, N, 256);
  k_att<<<(N + 255) / 256, 256, 0, stream>>>(Hh, Hl, as3, ad3, aS, aD, N, 1);
  k_gat_agg<1, false, false><<<aggBlocks, 256, 0, stream>>>(
      Hh, aS, aD, rowptr, colsrc, b3, h3agg, nullptr, nullptr, N);
  // --- pool + final ---
  k_pool_final<<<NUM_GRAPHS, 256, 0, stream>>>(h3agg, batch, linW, linb, out, N);
}

// Round 6
// 893.419 us; speedup vs baseline: 1.5872x; 1.1068x over previous
//
#include <hip/hip_runtime.h>
#include <math.h>

// ---------------------------------------------------------------------------
// GATClassifier on MI355X.
//   1. CSR build over dst (histogram -> scan -> scatter)
//   2. Per layer: split-bf16 MFMA GEMM (Ah*Bh + Ah*Bl + Al*Bh, fp32 acc)
//      writing h as bf16 hi+lo; att dots read hi+lo (exact); per-node wave
//      no-max softmax + weighted gather of bf16-hi rows; agg epilogue emits
//      split-bf16 for next GEMM.
//   3. Fused mean-pool + 32->1 linear (batch sorted -> binary search, 0 atomics)
// R2: atomic pool 383us. R3: fp32 SGEMM 158us x2. R4: agg 155us x2 (fp32
// gather + 3-pass softmax). R5: gemm latency-bound (MfmaUtil 5%, Occ 25%,
// grid 782 blocks, serialized L2 B-loads) -> R6 re-tile: col-split (64 cols)
// x 2 m-tiles/wave (32 rows), batched loads, 1564 blocks.
// NOTE: edge_index / batch are int32.
// ---------------------------------------------------------------------------

typedef __attribute__((ext_vector_type(8))) __bf16 bf16x8;
typedef __attribute__((ext_vector_type(4))) __bf16 bf16x4;
typedef __attribute__((ext_vector_type(4))) float f32x4;

// ---------------- CSR build ----------------
__global__ __launch_bounds__(256) void k_init_deg(int* deg, int N) {
  int n = blockIdx.x * 256 + threadIdx.x;
  if (n < N) deg[n] = 1;  // self-loop
}

__global__ __launch_bounds__(256) void k_count_deg(const int* __restrict__ ei,
                                                   int E, int* deg) {
  int e = blockIdx.x * 256 + threadIdx.x;
  if (e < E) atomicAdd(&deg[ei[E + e]], 1);
}

__global__ __launch_bounds__(1024) void k_scan(const int* __restrict__ deg,
                                               int* __restrict__ rowptr,
                                               int* __restrict__ cursor, int N) {
  __shared__ int part[1024];
  int t = threadIdx.x;
  int chunk = (N + 1023) >> 10;
  int b = t * chunk;
  int e = min(b + chunk, N);
  int s = 0;
  for (int i = b; i < e; i++) s += deg[i];
  part[t] = s;
  __syncthreads();
  for (int off = 1; off < 1024; off <<= 1) {
    int v = (t >= off) ? part[t - off] : 0;
    __syncthreads();
    part[t] += v;
    __syncthreads();
  }
  int run = (t > 0) ? part[t - 1] : 0;
  for (int i = b; i < e; i++) {
    rowptr[i] = run;
    cursor[i] = run;
    run += deg[i];
  }
  if (t == 1023) rowptr[N] = part[1023];
}

__global__ __launch_bounds__(256) void k_scatter(const int* __restrict__ ei,
                                                 int E, int N, int* cursor,
                                                 int* __restrict__ colsrc) {
  int i = blockIdx.x * 256 + threadIdx.x;
  if (i < E) {
    int s = ei[i];
    int d = ei[E + i];
    int pos = atomicAdd(&cursor[d], 1);
    colsrc[pos] = s;
  } else if (i < E + N) {
    int nn = i - E;
    int pos = atomicAdd(&cursor[nn], 1);
    colsrc[pos] = nn;  // self loop
  }
}

// ---------------- split-cast preps ----------------
__global__ __launch_bounds__(256) void k_split(const float* __restrict__ in,
                                               __bf16* __restrict__ oh,
                                               __bf16* __restrict__ ol, int n4) {
  int i = blockIdx.x * 256 + threadIdx.x;
  if (i >= n4) return;
  float4 v = ((const float4*)in)[i];
  bf16x4 h, l;
  h[0] = (__bf16)v.x; l[0] = (__bf16)(v.x - (float)h[0]);
  h[1] = (__bf16)v.y; l[1] = (__bf16)(v.y - (float)h[1]);
  h[2] = (__bf16)v.z; l[2] = (__bf16)(v.z - (float)h[2]);
  h[3] = (__bf16)v.w; l[3] = (__bf16)(v.w - (float)h[3]);
  ((bf16x4*)oh)[i] = h;
  ((bf16x4*)ol)[i] = l;
}

// W [K][Nc] fp32 -> WT hi/lo [Nc][K] bf16 (transposed so B-frags load b128).
__global__ __launch_bounds__(256) void k_wprep(const float* __restrict__ W,
                                               __bf16* __restrict__ WTh,
                                               __bf16* __restrict__ WTl,
                                               int K, int Nc) {
  int i = blockIdx.x * 256 + threadIdx.x;  // i = n*K + k
  if (i >= K * Nc) return;
  int n = i / K, k = i - n * K;
  float w = W[k * Nc + n];
  __bf16 h = (__bf16)w;
  WTh[i] = h;
  WTl[i] = (__bf16)(w - (float)h);
}

// ---------------- split-bf16 MFMA GEMM ----------------
// (Ch+Cl)[M][NcFull] = (Ah+Al)[M][K] @ (Bh+Bl)[K][NcFull]; output split bf16.
// Block = 4 waves; wave = MT m-tiles (MT*16 rows) x NT col-tiles (NT*16 cols).
// Grid = (NcFull/(NT*16) col-groups, ceil(M/(64*MT))). Loads batched per
// k-step (MT*2 A + NT*2 B b128s) then MT*NT*3 MFMAs -> latency hidden by
// occupancy (R6 fix; R5 was 25% occ / 5% MfmaUtil with NT=16 single m-tile).
// mfma_f32_16x16x32_bf16 (m89-verified): A: m=lane&15,k=quad*8+j;
// B: n=lane&15,k=quad*8+j (from WT); C/D: row=quad*4+reg, col=lane&15.
template <int NT, int MT>
__global__ __launch_bounds__(256) void k_gemm_split(
    const __bf16* __restrict__ Ah, const __bf16* __restrict__ Al,
    const __bf16* __restrict__ BTh, const __bf16* __restrict__ BTl,
    __bf16* __restrict__ Ch, __bf16* __restrict__ Cl, int M, int K, int NcFull) {
  int lane = threadIdx.x & 63;
  int wave = threadIdx.x >> 6;
  int quad = lane >> 4;
  int l16 = lane & 15;
  int m0 = blockIdx.y * (64 * MT) + wave * (16 * MT);
  int col0 = blockIdx.x * (NT * 16);
  const __bf16* arh[MT];
  const __bf16* arl[MT];
#pragma unroll
  for (int mt = 0; mt < MT; mt++) {
    int am = min(m0 + mt * 16 + l16, M - 1);  // clamp: rows >= M never stored
    arh[mt] = Ah + (size_t)am * K + quad * 8;
    arl[mt] = Al + (size_t)am * K + quad * 8;
  }
  const __bf16* brh = BTh + (size_t)(col0 + l16) * K + quad * 8;
  const __bf16* brl = BTl + (size_t)(col0 + l16) * K + quad * 8;
  f32x4 acc[MT][NT];
#pragma unroll
  for (int mt = 0; mt < MT; mt++)
#pragma unroll
    for (int t = 0; t < NT; t++) acc[mt][t] = (f32x4){0.f, 0.f, 0.f, 0.f};
  for (int k0 = 0; k0 < K; k0 += 32) {
    bf16x8 a_h[MT], a_l[MT], b_h[NT], b_l[NT];
#pragma unroll
    for (int mt = 0; mt < MT; mt++) {
      a_h[mt] = *(const bf16x8*)(arh[mt] + k0);
      a_l[mt] = *(const bf16x8*)(arl[mt] + k0);
    }
#pragma unroll
    for (int t = 0; t < NT; t++) {
      b_h[t] = *(const bf16x8*)(brh + (size_t)t * 16 * K + k0);
      b_l[t] = *(const bf16x8*)(brl + (size_t)t * 16 * K + k0);
    }
#pragma unroll
    for (int t = 0; t < NT; t++) {
#pragma unroll
      for (int mt = 0; mt < MT; mt++) {
        acc[mt][t] = __builtin_amdgcn_mfma_f32_16x16x32_bf16(a_h[mt], b_h[t], acc[mt][t], 0, 0, 0);
        acc[mt][t] = __builtin_amdgcn_mfma_f32_16x16x32_bf16(a_h[mt], b_l[t], acc[mt][t], 0, 0, 0);
        acc[mt][t] = __builtin_amdgcn_mfma_f32_16x16x32_bf16(a_l[mt], b_h[t], acc[mt][t], 0, 0, 0);
      }
    }
  }
#pragma unroll
  for (int mt = 0; mt < MT; mt++) {
#pragma unroll
    for (int t = 0; t < NT; t++) {
#pragma unroll
      for (int r = 0; r < 4; r++) {
        int m = m0 + mt * 16 + quad * 4 + r;
        if (m < M) {
          float v = acc[mt][t][r];
          __bf16 hb = (__bf16)v;
          size_t o = (size_t)m * NcFull + col0 + t * 16 + l16;
          Ch[o] = hb;
          Cl[o] = (__bf16)(v - (float)hb);
        }
      }
    }
  }
}

// ---------------- attention dots (hi+lo, exact) ----------------
__global__ __launch_bounds__(256) void k_att(const __bf16* __restrict__ Hh,
                                             const __bf16* __restrict__ Hl,
                                             const float* __restrict__ attS,
                                             const float* __restrict__ attD,
                                             float* __restrict__ aS,
                                             float* __restrict__ aD, int NH, int H) {
  int idx = blockIdx.x * 256 + threadIdx.x;
  if (idx >= NH) return;
  int h = idx % H;
  const bf16x8* hv = (const bf16x8*)(Hh + (size_t)idx * 32);
  const bf16x8* lv = (const bf16x8*)(Hl + (size_t)idx * 32);
  const float* sv = attS + h * 32;
  const float* dv = attD + h * 32;
  float ss = 0.f, dd = 0.f;
#pragma unroll
  for (int k = 0; k < 4; k++) {
    bf16x8 a = hv[k], b = lv[k];
#pragma unroll
    for (int j = 0; j < 8; j++) {
      float v = (float)a[j] + (float)b[j];
      ss += v * sv[k * 8 + j];
      dd += v * dv[k * 8 + j];
    }
  }
  aS[idx] = ss;
  aD[idx] = dd;
}

// ---------------- GAT aggregation ----------------
// One wave per dst node. No-max softmax (exp(e)/sum — identical math, |e|<~2):
// pass 1 sums exp over in-edges (shuffle reduce), pass 2 serial-edge weighted
// gather of bf16-HI rows. SPLIT: emit bf16 hi/lo for the next GEMM.
template <int H, bool DO_ELU, bool SPLIT>
__global__ __launch_bounds__(256) void k_gat_agg(
    const __bf16* __restrict__ Hh, const float* __restrict__ aS,
    const float* __restrict__ aD, const int* __restrict__ rowptr,
    const int* __restrict__ colsrc, const float* __restrict__ bias,
    float* __restrict__ out, __bf16* __restrict__ outh,
    __bf16* __restrict__ outl, int N) {
  constexpr int C = 32;
  constexpr int HC = H * C;
  int wid = (blockIdx.x * blockDim.x + threadIdx.x) >> 6;
  int lane = threadIdx.x & 63;
  if (wid >= N) return;
  int n = wid;
  int row0 = rowptr[n];
  int deg = rowptr[n + 1] - row0;

  float adn[H], s[H];
#pragma unroll
  for (int h = 0; h < H; h++) {
    adn[h] = aD[(size_t)n * H + h];
    s[h] = 0.f;
  }
  // pass 1: sum of exp(leaky(e))
  for (int i = lane; i < deg; i += 64) {
    int src = colsrc[row0 + i];
#pragma unroll
    for (int h = 0; h < H; h++) {
      float e = aS[(size_t)src * H + h] + adn[h];
      e = (e > 0.f) ? e : 0.2f * e;
      s[h] += __expf(e);
    }
  }
#pragma unroll
  for (int h = 0; h < H; h++) {
#pragma unroll
    for (int off = 32; off > 0; off >>= 1) s[h] += __shfl_xor(s[h], off, 64);
  }
  float rs[H];
#pragma unroll
  for (int h = 0; h < H; h++) rs[h] = 1.f / s[h];

  if constexpr (H == 8) {
    // lane -> (h = 2*hp + (lane>>5), c = lane&31); offset in row = hp*64+lane
    int hbase = lane >> 5;
    float rsh[4], adh[4], acc[4];
#pragma unroll
    for (int hp = 0; hp < 4; hp++) {
      rsh[hp] = hbase ? rs[2 * hp + 1] : rs[2 * hp];
      adh[hp] = hbase ? adn[2 * hp + 1] : adn[2 * hp];
      acc[hp] = 0.f;
    }
    for (int i = 0; i < deg; i++) {
      int src = colsrc[row0 + i];
      const __bf16* hrow = Hh + (size_t)src * HC;
#pragma unroll
      for (int hp = 0; hp < 4; hp++) {
        float e = aS[(size_t)src * 8 + 2 * hp + hbase] + adh[hp];
        e = (e > 0.f) ? e : 0.2f * e;
        float alpha = __expf(e) * rsh[hp];
        acc[hp] += alpha * (float)hrow[hp * 64 + lane];
      }
    }
#pragma unroll
    for (int hp = 0; hp < 4; hp++) {
      float v = acc[hp] + bias[hp * 64 + lane];
      if (DO_ELU) v = (v > 0.f) ? v : (__expf(v) - 1.f);
      if constexpr (SPLIT) {
        __bf16 hb = (__bf16)v;
        outh[(size_t)n * HC + hp * 64 + lane] = hb;
        outl[(size_t)n * HC + hp * 64 + lane] = (__bf16)(v - (float)hb);
      } else {
        out[(size_t)n * HC + hp * 64 + lane] = v;
      }
    }
  } else {
    // H == 1: two edges in flight (lane>>5), 32 channels
    int c = lane & 31;
    int eo = lane >> 5;
    float acc = 0.f;
    for (int i = eo; i < deg; i += 2) {
      int src = colsrc[row0 + i];
      float e = aS[src] + adn[0];
      e = (e > 0.f) ? e : 0.2f * e;
      float alpha = __expf(e) * rs[0];
      acc += alpha * (float)Hh[(size_t)src * C + c];
    }
    acc += __shfl_xor(acc, 32, 64);
    if (lane < 32) {
      float v = acc + bias[c];
      if (DO_ELU) v = (v > 0.f) ? v : (__expf(v) - 1.f);
      out[(size_t)n * C + c] = v;
    }
  }
}

// ---------------- fused mean-pool + linear ----------------
__global__ __launch_bounds__(256) void k_pool_final(
    const float* __restrict__ h, const int* __restrict__ batch,
    const float* __restrict__ linW, const float* __restrict__ linb,
    float* __restrict__ out, int N) {
  __shared__ float sh[256];
  int g = blockIdx.x;
  int tid = threadIdx.x;
  int grp = tid >> 5, c = tid & 31;
  int lo = 0, hi = N;
  while (lo < hi) { int mid = (lo + hi) >> 1; if (batch[mid] < g) lo = mid + 1; else hi = mid; }
  int start = lo;
  hi = N;
  while (lo < hi) { int mid = (lo + hi) >> 1; if (batch[mid] < g + 1) lo = mid + 1; else hi = mid; }
  int end = lo;
  float acc = 0.f;
  for (int n = start + grp; n < end; n += 8) acc += h[(size_t)n * 32 + c];
  sh[tid] = acc;
  __syncthreads();
  if (tid < 32) {
    float s = 0.f;
#pragma unroll
    for (int j = 0; j < 8; j++) s += sh[j * 32 + tid];
    float v = s * linW[tid];
#pragma unroll
    for (int off = 16; off > 0; off >>= 1) v += __shfl_xor(v, off, 64);
    if (tid == 0) {
      float cnt = (float)(end - start);
      out[g] = v / fmaxf(cnt, 1.f) + linb[0];
    }
  }
}

extern "C" void kernel_launch(void* const* d_in, const int* in_sizes, int n_in,
                              void* d_out, int out_size, void* d_ws, size_t ws_size,
                              hipStream_t stream) {
  const float* x = (const float*)d_in[0];
  const int* ei = (const int*)d_in[1];
  const int* batch = (const int*)d_in[2];
  const float* W1 = (const float*)d_in[3];
  const float* as1 = (const float*)d_in[4];
  const float* ad1 = (const float*)d_in[5];
  const float* b1 = (const float*)d_in[6];
  const float* W2 = (const float*)d_in[7];
  const float* as2 = (const float*)d_in[8];
  const float* ad2 = (const float*)d_in[9];
  const float* b2 = (const float*)d_in[10];
  const float* W3 = (const float*)d_in[11];
  const float* as3 = (const float*)d_in[12];
  const float* ad3 = (const float*)d_in[13];
  const float* b3 = (const float*)d_in[14];
  const float* linW = (const float*)d_in[15];
  const float* linb = (const float*)d_in[16];

  const int N = in_sizes[0] / 256;
  const int E = in_sizes[1] / 2;
  const int NUM_GRAPHS = 64;
  float* out = (float*)d_out;

  char* ws = (char*)d_ws;
  size_t off = 0;
  auto alloc = [&](size_t bytes) -> void* {
    void* p = ws + off;
    off += (bytes + 255) & ~(size_t)255;
    return p;
  };
  __bf16* Hh = (__bf16*)alloc((size_t)N * 256 * 2);  // GEMM h out (hi)
  __bf16* Hl = (__bf16*)alloc((size_t)N * 256 * 2);  //            (lo)
  __bf16* Ah = (__bf16*)alloc((size_t)N * 256 * 2);  // GEMM A in (hi)
  __bf16* Al = (__bf16*)alloc((size_t)N * 256 * 2);  //           (lo)
  float* aS = (float*)alloc((size_t)N * 8 * 4);
  float* aD = (float*)alloc((size_t)N * 8 * 4);
  int* deg = (int*)alloc((size_t)N * 4);
  int* rowptr = (int*)alloc((size_t)(N + 1) * 4);
  int* cursor = (int*)alloc((size_t)(N + 1) * 4);
  int* colsrc = (int*)alloc((size_t)(E + N) * 4);
  __bf16* WT1h = (__bf16*)alloc(256 * 256 * 2);
  __bf16* WT1l = (__bf16*)alloc(256 * 256 * 2);
  __bf16* WT2h = (__bf16*)alloc(256 * 256 * 2);
  __bf16* WT2l = (__bf16*)alloc(256 * 256 * 2);
  __bf16* WT3h = (__bf16*)alloc(32 * 256 * 2);
  __bf16* WT3l = (__bf16*)alloc(32 * 256 * 2);
  // h3agg reuses Ah (GEMM3 already consumed it when agg3 writes)
  float* h3agg = (float*)Ah;

  // --- preps: x split + W transposes/splits + CSR build ---
  k_split<<<(N * 64 + 255) / 256, 256, 0, stream>>>(x, Ah, Al, N * 64);
  k_wprep<<<(256 * 256 + 255) / 256, 256, 0, stream>>>(W1, WT1h, WT1l, 256, 256);
  k_wprep<<<(256 * 256 + 255) / 256, 256, 0, stream>>>(W2, WT2h, WT2l, 256, 256);
  k_wprep<<<(256 * 32 + 255) / 256, 256, 0, stream>>>(W3, WT3h, WT3l, 256, 32);
  k_init_deg<<<(N + 255) / 256, 256, 0, stream>>>(deg, N);
  k_count_deg<<<(E + 255) / 256, 256, 0, stream>>>(ei, E, deg);
  k_scan<<<1, 1024, 0, stream>>>(deg, rowptr, cursor, N);
  k_scatter<<<(E + N + 255) / 256, 256, 0, stream>>>(ei, E, N, cursor, colsrc);

  const int aggBlocks = (N + 3) / 4;
  // GEMM grids: layers 1/2: 4 col-groups of 64 cols, 128 rows/block;
  // layer 3: 1 col-group of 32 cols, 64 rows/block (MT=1 keeps waves up).
  dim3 g12(4, (N + 127) / 128);
  dim3 g3(1, (N + 63) / 64);

  // --- layer 1 ---
  k_gemm_split<4, 2><<<g12, 256, 0, stream>>>(Ah, Al, WT1h, WT1l, Hh, Hl, N, 256, 256);
  k_att<<<(N * 8 + 255) / 256, 256, 0, stream>>>(Hh, Hl, as1, ad1, aS, aD, N * 8, 8);
  k_gat_agg<8, true, true><<<aggBlocks, 256, 0, stream>>>(
      Hh, aS, aD, rowptr, colsrc, b1, nullptr, Ah, Al, N);
  // --- layer 2 ---
  k_gemm_split<4, 2><<<g12, 256, 0, stream>>>(Ah, Al, WT2h, WT2l, Hh, Hl, N, 256, 256);
  k_att<<<(N * 8 + 255) / 256, 256, 0, stream>>>(Hh, Hl, as2, ad2, aS, aD, N * 8, 8);
  k_gat_agg<8, true, true><<<aggBlocks, 256, 0, stream>>>(
      Hh, aS, aD, rowptr, colsrc, b2, nullptr, Ah, Al, N);
  // --- layer 3 (H=1, fp32 out) ---
  k_gemm_split<2, 1><<<g3, 256, 0, stream>>>(Ah, Al, WT3h, WT3l, Hh, Hl, N, 256, 32);
  k_att<<<(N + 255) / 256, 256, 0, stream>>>(Hh, Hl, as3, ad3, aS, aD, N, 1);
  k_gat_agg<1, false, false><<<aggBlocks, 256, 0, stream>>>(
      Hh, aS, aD, rowptr, colsrc, b3, h3agg, nullptr, nullptr, N);
  // --- pool + final ---
  k_pool_final<<<NUM_GRAPHS, 256, 0, stream>>>(h3agg, batch, linW, linb, out, N);
}

// Round 7
// 768.446 us; speedup vs baseline: 1.8454x; 1.1626x over previous
//
#include <hip/hip_runtime.h>
#include <math.h>

// ---------------------------------------------------------------------------
// GATClassifier on MI355X.
//   1. CSR build over dst (histogram -> scan -> scatter)
//   2. Per layer: split-bf16 MFMA GEMM (Ah*Bh + Ah*Bl + Al*Bh, fp32 acc),
//      h stored bf16-hi only; att dots from bf16-hi; agg: pass1 computes
//      exp(leaky(e)) ONCE per (edge,head), stores bf16 ealpha (L2-hot
//      same-wave readback) + shuffle-reduced sum; pass2 gathers bf16x4 row
//      chunks (lane = 4 consecutive channels) weighted by ealpha, normalizes
//      in the epilogue. Agg epilogue emits split-bf16 for the next GEMM.
//   3. Fused mean-pool + 32->1 linear (batch sorted -> binary search)
// History: R2 atomic pool 383us. R3 fp32 SGEMM 158us x2. R4 agg fp32-gather
// 155us x2. R5 gemm latency-bound 140us x2 -> R6 re-tile. R6: agg 131us x2
// (4x ushort gather + redundant exp recompute, VALUBusy 65%) -> R7 this.
// NOTE: edge_index / batch are int32.
// ---------------------------------------------------------------------------

typedef __attribute__((ext_vector_type(8))) __bf16 bf16x8;
typedef __attribute__((ext_vector_type(4))) __bf16 bf16x4;
typedef __attribute__((ext_vector_type(4))) float f32x4;

// ---------------- CSR build ----------------
__global__ __launch_bounds__(256) void k_init_deg(int* deg, int N) {
  int n = blockIdx.x * 256 + threadIdx.x;
  if (n < N) deg[n] = 1;  // self-loop
}

__global__ __launch_bounds__(256) void k_count_deg(const int* __restrict__ ei,
                                                   int E, int* deg) {
  int e = blockIdx.x * 256 + threadIdx.x;
  if (e < E) atomicAdd(&deg[ei[E + e]], 1);
}

__global__ __launch_bounds__(1024) void k_scan(const int* __restrict__ deg,
                                               int* __restrict__ rowptr,
                                               int* __restrict__ cursor, int N) {
  __shared__ int part[1024];
  int t = threadIdx.x;
  int chunk = (N + 1023) >> 10;
  int b = t * chunk;
  int e = min(b + chunk, N);
  int s = 0;
  for (int i = b; i < e; i++) s += deg[i];
  part[t] = s;
  __syncthreads();
  for (int off = 1; off < 1024; off <<= 1) {
    int v = (t >= off) ? part[t - off] : 0;
    __syncthreads();
    part[t] += v;
    __syncthreads();
  }
  int run = (t > 0) ? part[t - 1] : 0;
  for (int i = b; i < e; i++) {
    rowptr[i] = run;
    cursor[i] = run;
    run += deg[i];
  }
  if (t == 1023) rowptr[N] = part[1023];
}

__global__ __launch_bounds__(256) void k_scatter(const int* __restrict__ ei,
                                                 int E, int N, int* cursor,
                                                 int* __restrict__ colsrc) {
  int i = blockIdx.x * 256 + threadIdx.x;
  if (i < E) {
    int s = ei[i];
    int d = ei[E + i];
    int pos = atomicAdd(&cursor[d], 1);
    colsrc[pos] = s;
  } else if (i < E + N) {
    int nn = i - E;
    int pos = atomicAdd(&cursor[nn], 1);
    colsrc[pos] = nn;  // self loop
  }
}

// ---------------- split-cast preps ----------------
__global__ __launch_bounds__(256) void k_split(const float* __restrict__ in,
                                               __bf16* __restrict__ oh,
                                               __bf16* __restrict__ ol, int n4) {
  int i = blockIdx.x * 256 + threadIdx.x;
  if (i >= n4) return;
  float4 v = ((const float4*)in)[i];
  bf16x4 h, l;
  h[0] = (__bf16)v.x; l[0] = (__bf16)(v.x - (float)h[0]);
  h[1] = (__bf16)v.y; l[1] = (__bf16)(v.y - (float)h[1]);
  h[2] = (__bf16)v.z; l[2] = (__bf16)(v.z - (float)h[2]);
  h[3] = (__bf16)v.w; l[3] = (__bf16)(v.w - (float)h[3]);
  ((bf16x4*)oh)[i] = h;
  ((bf16x4*)ol)[i] = l;
}

// W [K][Nc] fp32 -> WT hi/lo [Nc][K] bf16 (transposed so B-frags load b128).
__global__ __launch_bounds__(256) void k_wprep(const float* __restrict__ W,
                                               __bf16* __restrict__ WTh,
                                               __bf16* __restrict__ WTl,
                                               int K, int Nc) {
  int i = blockIdx.x * 256 + threadIdx.x;  // i = n*K + k
  if (i >= K * Nc) return;
  int n = i / K, k = i - n * K;
  float w = W[k * Nc + n];
  __bf16 h = (__bf16)w;
  WTh[i] = h;
  WTl[i] = (__bf16)(w - (float)h);
}

// ---------------- split-bf16 MFMA GEMM (bf16-hi output) ----------------
// Ch[M][NcFull] = (Ah+Al)[M][K] @ (Bh+Bl)[K][NcFull], fp32 acc -> bf16.
// Block = 4 waves; wave = MT m-tiles x NT col-tiles; batched b128 loads then
// MT*NT*3 MFMAs (R6 fix for the R5 latency stall).
// mfma_f32_16x16x32_bf16 (m89-verified): A: m=lane&15,k=quad*8+j;
// B: n=lane&15,k=quad*8+j (from WT); C/D: row=quad*4+reg, col=lane&15.
template <int NT, int MT>
__global__ __launch_bounds__(256) void k_gemm_split(
    const __bf16* __restrict__ Ah, const __bf16* __restrict__ Al,
    const __bf16* __restrict__ BTh, const __bf16* __restrict__ BTl,
    __bf16* __restrict__ Ch, int M, int K, int NcFull) {
  int lane = threadIdx.x & 63;
  int wave = threadIdx.x >> 6;
  int quad = lane >> 4;
  int l16 = lane & 15;
  int m0 = blockIdx.y * (64 * MT) + wave * (16 * MT);
  int col0 = blockIdx.x * (NT * 16);
  const __bf16* arh[MT];
  const __bf16* arl[MT];
#pragma unroll
  for (int mt = 0; mt < MT; mt++) {
    int am = min(m0 + mt * 16 + l16, M - 1);  // clamp: rows >= M never stored
    arh[mt] = Ah + (size_t)am * K + quad * 8;
    arl[mt] = Al + (size_t)am * K + quad * 8;
  }
  const __bf16* brh = BTh + (size_t)(col0 + l16) * K + quad * 8;
  const __bf16* brl = BTl + (size_t)(col0 + l16) * K + quad * 8;
  f32x4 acc[MT][NT];
#pragma unroll
  for (int mt = 0; mt < MT; mt++)
#pragma unroll
    for (int t = 0; t < NT; t++) acc[mt][t] = (f32x4){0.f, 0.f, 0.f, 0.f};
  for (int k0 = 0; k0 < K; k0 += 32) {
    bf16x8 a_h[MT], a_l[MT], b_h[NT], b_l[NT];
#pragma unroll
    for (int mt = 0; mt < MT; mt++) {
      a_h[mt] = *(const bf16x8*)(arh[mt] + k0);
      a_l[mt] = *(const bf16x8*)(arl[mt] + k0);
    }
#pragma unroll
    for (int t = 0; t < NT; t++) {
      b_h[t] = *(const bf16x8*)(brh + (size_t)t * 16 * K + k0);
      b_l[t] = *(const bf16x8*)(brl + (size_t)t * 16 * K + k0);
    }
#pragma unroll
    for (int t = 0; t < NT; t++) {
#pragma unroll
      for (int mt = 0; mt < MT; mt++) {
        acc[mt][t] = __builtin_amdgcn_mfma_f32_16x16x32_bf16(a_h[mt], b_h[t], acc[mt][t], 0, 0, 0);
        acc[mt][t] = __builtin_amdgcn_mfma_f32_16x16x32_bf16(a_h[mt], b_l[t], acc[mt][t], 0, 0, 0);
        acc[mt][t] = __builtin_amdgcn_mfma_f32_16x16x32_bf16(a_l[mt], b_h[t], acc[mt][t], 0, 0, 0);
      }
    }
  }
#pragma unroll
  for (int mt = 0; mt < MT; mt++) {
#pragma unroll
    for (int t = 0; t < NT; t++) {
#pragma unroll
      for (int r = 0; r < 4; r++) {
        int m = m0 + mt * 16 + quad * 4 + r;
        if (m < M)
          Ch[(size_t)m * NcFull + col0 + t * 16 + l16] = (__bf16)acc[mt][t][r];
      }
    }
  }
}

// ---------------- attention dots (bf16-hi) ----------------
__global__ __launch_bounds__(256) void k_att(const __bf16* __restrict__ Hh,
                                             const float* __restrict__ attS,
                                             const float* __restrict__ attD,
                                             float* __restrict__ aS,
                                             float* __restrict__ aD, int NH, int H) {
  int idx = blockIdx.x * 256 + threadIdx.x;
  if (idx >= NH) return;
  int h = idx % H;
  const bf16x8* hv = (const bf16x8*)(Hh + (size_t)idx * 32);
  const float* sv = attS + h * 32;
  const float* dv = attD + h * 32;
  float ss = 0.f, dd = 0.f;
#pragma unroll
  for (int k = 0; k < 4; k++) {
    bf16x8 a = hv[k];
#pragma unroll
    for (int j = 0; j < 8; j++) {
      float v = (float)a[j];
      ss += v * sv[k * 8 + j];
      dd += v * dv[k * 8 + j];
    }
  }
  aS[idx] = ss;
  aD[idx] = dd;
}

// ---------------- GAT aggregation, H=8 ----------------
// One wave per dst node. Pass 1 (lane-parallel over edges): computes
// exp(leaky(e)) once per (edge,head), stores bf16 ealpha[slot*8+h], reduces
// sums. Pass 2 (serial edges, unroll-2): lane = 4 consecutive channels
// (head = lane>>3), one bf16x4 row load/edge, weight from ealpha; normalize
// by 1/s in the epilogue (algebraically identical). ELU + split-bf16 out.
__global__ __launch_bounds__(256) void k_gat_agg8(
    const __bf16* __restrict__ Hh, const float* __restrict__ aS,
    const float* __restrict__ aD, const int* __restrict__ rowptr,
    const int* __restrict__ colsrc, const float* __restrict__ bias,
    __bf16* __restrict__ ealpha, __bf16* __restrict__ outh,
    __bf16* __restrict__ outl, int N) {
  int wid = (blockIdx.x * blockDim.x + threadIdx.x) >> 6;
  int lane = threadIdx.x & 63;
  if (wid >= N) return;
  int n = wid;
  int row0 = rowptr[n];
  int deg = rowptr[n + 1] - row0;

  float adn[8], s[8];
#pragma unroll
  for (int h = 0; h < 8; h++) {
    adn[h] = aD[(size_t)n * 8 + h];
    s[h] = 0.f;
  }
  // pass 1: exp once per (edge,head); store; sum
  for (int i = lane; i < deg; i += 64) {
    int slot = row0 + i;
    int src = colsrc[slot];
    const float* ap = aS + (size_t)src * 8;
    bf16x8 ev;
#pragma unroll
    for (int h = 0; h < 8; h++) {
      float e = ap[h] + adn[h];
      e = (e > 0.f) ? e : 0.2f * e;
      float x = __expf(e);
      s[h] += x;
      ev[h] = (__bf16)x;
    }
    *(bf16x8*)(ealpha + (size_t)slot * 8) = ev;
  }
#pragma unroll
  for (int h = 0; h < 8; h++) {
#pragma unroll
    for (int off = 32; off > 0; off >>= 1) s[h] += __shfl_xor(s[h], off, 64);
  }
  // per-lane head and its 1/s (3-level select tree, once per node)
  int head = lane >> 3;
  float r0 = (head & 4) ? s[4] : s[0];
  float r1 = (head & 4) ? s[5] : s[1];
  float r2 = (head & 4) ? s[6] : s[2];
  float r3 = (head & 4) ? s[7] : s[3];
  float u0 = (head & 2) ? r2 : r0;
  float u1 = (head & 2) ? r3 : r1;
  float rsv = 1.f / ((head & 1) ? u1 : u0);

  // pass 2: weighted gather, unroll-2 (2 rows in flight)
  f32x4 acc = (f32x4){0.f, 0.f, 0.f, 0.f};
  const __bf16* ea = ealpha;
  int i = 0;
  for (; i + 1 < deg; i += 2) {
    int sl = row0 + i;
    int s0 = colsrc[sl];
    int s1 = colsrc[sl + 1];
    float w0 = (float)ea[(size_t)sl * 8 + head];
    float w1 = (float)ea[(size_t)(sl + 1) * 8 + head];
    bf16x4 h0 = *(const bf16x4*)(Hh + (size_t)s0 * 256 + lane * 4);
    bf16x4 h1 = *(const bf16x4*)(Hh + (size_t)s1 * 256 + lane * 4);
#pragma unroll
    for (int j = 0; j < 4; j++) acc[j] += w0 * (float)h0[j];
#pragma unroll
    for (int j = 0; j < 4; j++) acc[j] += w1 * (float)h1[j];
  }
  if (i < deg) {
    int sl = row0 + i;
    int s0 = colsrc[sl];
    float w0 = (float)ea[(size_t)sl * 8 + head];
    bf16x4 h0 = *(const bf16x4*)(Hh + (size_t)s0 * 256 + lane * 4);
#pragma unroll
    for (int j = 0; j < 4; j++) acc[j] += w0 * (float)h0[j];
  }
  // epilogue: normalize, bias, ELU, split-bf16 store
  float4 bv = *(const float4*)(bias + lane * 4);
  bf16x4 hb, lb;
#pragma unroll
  for (int j = 0; j < 4; j++) {
    float v = acc[j] * rsv + ((const float*)&bv)[j];
    v = (v > 0.f) ? v : (__expf(v) - 1.f);  // ELU
    hb[j] = (__bf16)v;
    lb[j] = (__bf16)(v - (float)hb[j]);
  }
  *(bf16x4*)(outh + (size_t)n * 256 + lane * 4) = hb;
  *(bf16x4*)(outl + (size_t)n * 256 + lane * 4) = lb;
}

// ---------------- GAT aggregation, H=1 (layer 3, fp32 out, no ELU) ------
// 8 edges in flight: lane = (edge-group eo = lane>>3, channel-group lane&7,
// 4 channels each). Cross-edge-group shuffle reduce at the end.
__global__ __launch_bounds__(256) void k_gat_agg1(
    const __bf16* __restrict__ Hh, const float* __restrict__ aS,
    const float* __restrict__ aD, const int* __restrict__ rowptr,
    const int* __restrict__ colsrc, const float* __restrict__ bias,
    __bf16* __restrict__ ealpha, float* __restrict__ out, int N) {
  int wid = (blockIdx.x * blockDim.x + threadIdx.x) >> 6;
  int lane = threadIdx.x & 63;
  if (wid >= N) return;
  int n = wid;
  int row0 = rowptr[n];
  int deg = rowptr[n + 1] - row0;
  float adn = aD[n];
  float s = 0.f;
  for (int i = lane; i < deg; i += 64) {
    int slot = row0 + i;
    float e = aS[colsrc[slot]] + adn;
    e = (e > 0.f) ? e : 0.2f * e;
    float x = __expf(e);
    s += x;
    ealpha[slot] = (__bf16)x;
  }
#pragma unroll
  for (int off = 32; off > 0; off >>= 1) s += __shfl_xor(s, off, 64);
  float rsv = 1.f / s;

  int eo = lane >> 3;
  int cl = lane & 7;
  f32x4 acc = (f32x4){0.f, 0.f, 0.f, 0.f};
  for (int i = eo; i < deg; i += 8) {
    int slot = row0 + i;
    int src = colsrc[slot];
    float w = (float)ealpha[slot];
    bf16x4 hv = *(const bf16x4*)(Hh + (size_t)src * 32 + cl * 4);
#pragma unroll
    for (int j = 0; j < 4; j++) acc[j] += w * (float)hv[j];
  }
#pragma unroll
  for (int j = 0; j < 4; j++) {
#pragma unroll
    for (int off = 8; off < 64; off <<= 1) acc[j] += __shfl_xor(acc[j], off, 64);
  }
  if (eo == 0) {
#pragma unroll
    for (int j = 0; j < 4; j++)
      out[(size_t)n * 32 + cl * 4 + j] = acc[j] * rsv + bias[cl * 4 + j];
  }
}

// ---------------- fused mean-pool + linear ----------------
__global__ __launch_bounds__(256) void k_pool_final(
    const float* __restrict__ h, const int* __restrict__ batch,
    const float* __restrict__ linW, const float* __restrict__ linb,
    float* __restrict__ out, int N) {
  __shared__ float sh[256];
  int g = blockIdx.x;
  int tid = threadIdx.x;
  int grp = tid >> 5, c = tid & 31;
  int lo = 0, hi = N;
  while (lo < hi) { int mid = (lo + hi) >> 1; if (batch[mid] < g) lo = mid + 1; else hi = mid; }
  int start = lo;
  hi = N;
  while (lo < hi) { int mid = (lo + hi) >> 1; if (batch[mid] < g + 1) lo = mid + 1; else hi = mid; }
  int end = lo;
  float acc = 0.f;
  for (int n = start + grp; n < end; n += 8) acc += h[(size_t)n * 32 + c];
  sh[tid] = acc;
  __syncthreads();
  if (tid < 32) {
    float s = 0.f;
#pragma unroll
    for (int j = 0; j < 8; j++) s += sh[j * 32 + tid];
    float v = s * linW[tid];
#pragma unroll
    for (int off = 16; off > 0; off >>= 1) v += __shfl_xor(v, off, 64);
    if (tid == 0) {
      float cnt = (float)(end - start);
      out[g] = v / fmaxf(cnt, 1.f) + linb[0];
    }
  }
}

extern "C" void kernel_launch(void* const* d_in, const int* in_sizes, int n_in,
                              void* d_out, int out_size, void* d_ws, size_t ws_size,
                              hipStream_t stream) {
  const float* x = (const float*)d_in[0];
  const int* ei = (const int*)d_in[1];
  const int* batch = (const int*)d_in[2];
  const float* W1 = (const float*)d_in[3];
  const float* as1 = (const float*)d_in[4];
  const float* ad1 = (const float*)d_in[5];
  const float* b1 = (const float*)d_in[6];
  const float* W2 = (const float*)d_in[7];
  const float* as2 = (const float*)d_in[8];
  const float* ad2 = (const float*)d_in[9];
  const float* b2 = (const float*)d_in[10];
  const float* W3 = (const float*)d_in[11];
  const float* as3 = (const float*)d_in[12];
  const float* ad3 = (const float*)d_in[13];
  const float* b3 = (const float*)d_in[14];
  const float* linW = (const float*)d_in[15];
  const float* linb = (const float*)d_in[16];

  const int N = in_sizes[0] / 256;
  const int E = in_sizes[1] / 2;
  const int NUM_GRAPHS = 64;
  float* out = (float*)d_out;

  char* ws = (char*)d_ws;
  size_t off = 0;
  auto alloc = [&](size_t bytes) -> void* {
    void* p = ws + off;
    off += (bytes + 255) & ~(size_t)255;
    return p;
  };
  __bf16* Hh = (__bf16*)alloc((size_t)N * 256 * 2);  // GEMM h out (bf16-hi)
  __bf16* Ah = (__bf16*)alloc((size_t)N * 256 * 2);  // GEMM A in (hi)
  __bf16* Al = (__bf16*)alloc((size_t)N * 256 * 2);  //           (lo)
  __bf16* ealpha = (__bf16*)alloc((size_t)(E + N) * 8 * 2);  // per-edge exps
  float* aS = (float*)alloc((size_t)N * 8 * 4);
  float* aD = (float*)alloc((size_t)N * 8 * 4);
  int* deg = (int*)alloc((size_t)N * 4);
  int* rowptr = (int*)alloc((size_t)(N + 1) * 4);
  int* cursor = (int*)alloc((size_t)(N + 1) * 4);
  int* colsrc = (int*)alloc((size_t)(E + N) * 4);
  __bf16* WT1h = (__bf16*)alloc(256 * 256 * 2);
  __bf16* WT1l = (__bf16*)alloc(256 * 256 * 2);
  __bf16* WT2h = (__bf16*)alloc(256 * 256 * 2);
  __bf16* WT2l = (__bf16*)alloc(256 * 256 * 2);
  __bf16* WT3h = (__bf16*)alloc(32 * 256 * 2);
  __bf16* WT3l = (__bf16*)alloc(32 * 256 * 2);
  // h3agg reuses Ah (GEMM3 already consumed Ah/Al when agg3 writes)
  float* h3agg = (float*)Ah;

  // --- preps: x split + W transposes/splits + CSR build ---
  k_split<<<(N * 64 + 255) / 256, 256, 0, stream>>>(x, Ah, Al, N * 64);
  k_wprep<<<(256 * 256 + 255) / 256, 256, 0, stream>>>(W1, WT1h, WT1l, 256, 256);
  k_wprep<<<(256 * 256 + 255) / 256, 256, 0, stream>>>(W2, WT2h, WT2l, 256, 256);
  k_wprep<<<(256 * 32 + 255) / 256, 256, 0, stream>>>(W3, WT3h, WT3l, 256, 32);
  k_init_deg<<<(N + 255) / 256, 256, 0, stream>>>(deg, N);
  k_count_deg<<<(E + 255) / 256, 256, 0, stream>>>(ei, E, deg);
  k_scan<<<1, 1024, 0, stream>>>(deg, rowptr, cursor, N);
  k_scatter<<<(E + N + 255) / 256, 256, 0, stream>>>(ei, E, N, cursor, colsrc);

  const int aggBlocks = (N + 3) / 4;
  dim3 g12(4, (N + 127) / 128);
  dim3 g3(1, (N + 63) / 64);

  // --- layer 1 ---
  k_gemm_split<4, 2><<<g12, 256, 0, stream>>>(Ah, Al, WT1h, WT1l, Hh, N, 256, 256);
  k_att<<<(N * 8 + 255) / 256, 256, 0, stream>>>(Hh, as1, ad1, aS, aD, N * 8, 8);
  k_gat_agg8<<<aggBlocks, 256, 0, stream>>>(Hh, aS, aD, rowptr, colsrc, b1,
                                            ealpha, Ah, Al, N);
  // --- layer 2 ---
  k_gemm_split<4, 2><<<g12, 256, 0, stream>>>(Ah, Al, WT2h, WT2l, Hh, N, 256, 256);
  k_att<<<(N * 8 + 255) / 256, 256, 0, stream>>>(Hh, as2, ad2, aS, aD, N * 8, 8);
  k_gat_agg8<<<aggBlocks, 256, 0, stream>>>(Hh, aS, aD, rowptr, colsrc, b2,
                                            ealpha, Ah, Al, N);
  // --- layer 3 (H=1) ---
  k_gemm_split<2, 1><<<g3, 256, 0, stream>>>(Ah, Al, WT3h, WT3l, Hh, N, 256, 32);
  k_att<<<(N + 255) / 256, 256, 0, stream>>>(Hh, as3, ad3, aS, aD, N, 1);
  k_gat_agg1<<<aggBlocks, 256, 0, stream>>>(Hh, aS, aD, rowptr, colsrc, b3,
                                            ealpha, h3agg, N);
  // --- pool + final ---
  k_pool_final<<<NUM_GRAPHS, 256, 0, stream>>>(h3agg, batch, linW, linb, out, N);
}

// Round 8
// 670.671 us; speedup vs baseline: 2.1144x; 1.1458x over previous
//
#include <hip/hip_runtime.h>
#include <math.h>

// ---------------------------------------------------------------------------
// GATClassifier on MI355X.
//   1. CSR build over dst (histogram -> 3-phase device-wide scan -> scatter)
//   2. Per layer: split-bf16 MFMA GEMM (Ah*Bh + Ah*Bl + Al*Bh, fp32 acc),
//      h stored bf16-hi; att dots from bf16-hi; agg: pass1 computes
//      exp(leaky(e)) once per (edge,head) -> bf16 ealpha + reduced sums;
//      pass2 gathers bf16x4 row chunks weighted by ealpha; normalize in
//      epilogue; split-bf16 out for next GEMM.
//   3. Fused mean-pool + 32->1 linear (batch sorted -> binary search)
// History: R2 atomic pool 383us. R3 fp32 SGEMM 158x2. R4 agg fp32-gather
// 155x2. R5 gemm latency 140x2 -> R6 re-tile. R6 agg 131x2 -> R7 ealpha+
// vec gather. R7: single-block k_scan 111us (Occ 0.14%!) -> R8 3-phase scan.
// NOTE: edge_index / batch are int32.
// ---------------------------------------------------------------------------

typedef __attribute__((ext_vector_type(8))) __bf16 bf16x8;
typedef __attribute__((ext_vector_type(4))) __bf16 bf16x4;
typedef __attribute__((ext_vector_type(4))) float f32x4;

#define SCAN_CH 4  // elements per thread in the device-wide scan

// ---------------- CSR build ----------------
__global__ __launch_bounds__(256) void k_init_deg(int* deg, int N) {
  int n = blockIdx.x * 256 + threadIdx.x;
  if (n < N) deg[n] = 1;  // self-loop
}

__global__ __launch_bounds__(256) void k_count_deg(const int* __restrict__ ei,
                                                   int E, int* deg) {
  int e = blockIdx.x * 256 + threadIdx.x;
  if (e < E) atomicAdd(&deg[ei[E + e]], 1);
}

// --- 3-phase exclusive scan of deg[0..N) -> rowptr/cursor (R8: the old
// single-block scan ran on ONE CU for 111us) ---
__global__ __launch_bounds__(256) void k_scan_partial(const int* __restrict__ deg,
                                                      int* __restrict__ blockSums,
                                                      int N) {
  __shared__ int sh[256];
  int t = threadIdx.x, b = blockIdx.x;
  int base = (b * 256 + t) * SCAN_CH;
  int s = 0;
#pragma unroll
  for (int j = 0; j < SCAN_CH; j++) {
    int idx = base + j;
    if (idx < N) s += deg[idx];
  }
  sh[t] = s;
  __syncthreads();
  for (int off = 128; off > 0; off >>= 1) {
    if (t < off) sh[t] += sh[t + off];
    __syncthreads();
  }
  if (t == 0) blockSums[b] = sh[0];
}

__global__ __launch_bounds__(256) void k_scan_blocksums(
    const int* __restrict__ blockSums, int* __restrict__ blockOffs,
    int* __restrict__ rowptr, int nb, int N) {
  __shared__ int sh[256];
  int t = threadIdx.x;
  int v = (t < nb) ? blockSums[t] : 0;
  sh[t] = v;
  __syncthreads();
  for (int off = 1; off < 256; off <<= 1) {
    int u = (t >= off) ? sh[t - off] : 0;
    __syncthreads();
    sh[t] += u;
    __syncthreads();
  }
  if (t < nb) blockOffs[t] = sh[t] - v;  // exclusive
  if (t == nb - 1) rowptr[N] = sh[t];    // total
}

__global__ __launch_bounds__(256) void k_scan_final(const int* __restrict__ deg,
                                                    const int* __restrict__ blockOffs,
                                                    int* __restrict__ rowptr,
                                                    int* __restrict__ cursor, int N) {
  __shared__ int sh[256];
  int t = threadIdx.x, b = blockIdx.x;
  int base = (b * 256 + t) * SCAN_CH;
  int vals[SCAN_CH];
  int s = 0;
#pragma unroll
  for (int j = 0; j < SCAN_CH; j++) {
    int idx = base + j;
    vals[j] = (idx < N) ? deg[idx] : 0;
    s += vals[j];
  }
  sh[t] = s;
  __syncthreads();
  for (int off = 1; off < 256; off <<= 1) {
    int u = (t >= off) ? sh[t - off] : 0;
    __syncthreads();
    sh[t] += u;
    __syncthreads();
  }
  int run = blockOffs[b] + sh[t] - s;  // exclusive prefix for this thread
#pragma unroll
  for (int j = 0; j < SCAN_CH; j++) {
    int idx = base + j;
    if (idx < N) {
      rowptr[idx] = run;
      cursor[idx] = run;
      run += vals[j];
    }
  }
}

__global__ __launch_bounds__(256) void k_scatter(const int* __restrict__ ei,
                                                 int E, int N, int* cursor,
                                                 int* __restrict__ colsrc) {
  int i = blockIdx.x * 256 + threadIdx.x;
  if (i < E) {
    int s = ei[i];
    int d = ei[E + i];
    int pos = atomicAdd(&cursor[d], 1);
    colsrc[pos] = s;
  } else if (i < E + N) {
    int nn = i - E;
    int pos = atomicAdd(&cursor[nn], 1);
    colsrc[pos] = nn;  // self loop
  }
}

// ---------------- split-cast preps ----------------
__global__ __launch_bounds__(256) void k_split(const float* __restrict__ in,
                                               __bf16* __restrict__ oh,
                                               __bf16* __restrict__ ol, int n4) {
  int i = blockIdx.x * 256 + threadIdx.x;
  if (i >= n4) return;
  float4 v = ((const float4*)in)[i];
  bf16x4 h, l;
  h[0] = (__bf16)v.x; l[0] = (__bf16)(v.x - (float)h[0]);
  h[1] = (__bf16)v.y; l[1] = (__bf16)(v.y - (float)h[1]);
  h[2] = (__bf16)v.z; l[2] = (__bf16)(v.z - (float)h[2]);
  h[3] = (__bf16)v.w; l[3] = (__bf16)(v.w - (float)h[3]);
  ((bf16x4*)oh)[i] = h;
  ((bf16x4*)ol)[i] = l;
}

// W [K][Nc] fp32 -> WT hi/lo [Nc][K] bf16 (transposed so B-frags load b128).
__global__ __launch_bounds__(256) void k_wprep(const float* __restrict__ W,
                                               __bf16* __restrict__ WTh,
                                               __bf16* __restrict__ WTl,
                                               int K, int Nc) {
  int i = blockIdx.x * 256 + threadIdx.x;  // i = n*K + k
  if (i >= K * Nc) return;
  int n = i / K, k = i - n * K;
  float w = W[k * Nc + n];
  __bf16 h = (__bf16)w;
  WTh[i] = h;
  WTl[i] = (__bf16)(w - (float)h);
}

// ---------------- split-bf16 MFMA GEMM (bf16-hi output) ----------------
// Block = 4 waves; wave = MT m-tiles x NT col-tiles; batched b128 loads then
// MT*NT*3 MFMAs (R6 fix for the R5 latency stall).
// mfma_f32_16x16x32_bf16 (m89-verified): A: m=lane&15,k=quad*8+j;
// B: n=lane&15,k=quad*8+j (from WT); C/D: row=quad*4+reg, col=lane&15.
template <int NT, int MT>
__global__ __launch_bounds__(256) void k_gemm_split(
    const __bf16* __restrict__ Ah, const __bf16* __restrict__ Al,
    const __bf16* __restrict__ BTh, const __bf16* __restrict__ BTl,
    __bf16* __restrict__ Ch, int M, int K, int NcFull) {
  int lane = threadIdx.x & 63;
  int wave = threadIdx.x >> 6;
  int quad = lane >> 4;
  int l16 = lane & 15;
  int m0 = blockIdx.y * (64 * MT) + wave * (16 * MT);
  int col0 = blockIdx.x * (NT * 16);
  const __bf16* arh[MT];
  const __bf16* arl[MT];
#pragma unroll
  for (int mt = 0; mt < MT; mt++) {
    int am = min(m0 + mt * 16 + l16, M - 1);  // clamp: rows >= M never stored
    arh[mt] = Ah + (size_t)am * K + quad * 8;
    arl[mt] = Al + (size_t)am * K + quad * 8;
  }
  const __bf16* brh = BTh + (size_t)(col0 + l16) * K + quad * 8;
  const __bf16* brl = BTl + (size_t)(col0 + l16) * K + quad * 8;
  f32x4 acc[MT][NT];
#pragma unroll
  for (int mt = 0; mt < MT; mt++)
#pragma unroll
    for (int t = 0; t < NT; t++) acc[mt][t] = (f32x4){0.f, 0.f, 0.f, 0.f};
  for (int k0 = 0; k0 < K; k0 += 32) {
    bf16x8 a_h[MT], a_l[MT], b_h[NT], b_l[NT];
#pragma unroll
    for (int mt = 0; mt < MT; mt++) {
      a_h[mt] = *(const bf16x8*)(arh[mt] + k0);
      a_l[mt] = *(const bf16x8*)(arl[mt] + k0);
    }
#pragma unroll
    for (int t = 0; t < NT; t++) {
      b_h[t] = *(const bf16x8*)(brh + (size_t)t * 16 * K + k0);
      b_l[t] = *(const bf16x8*)(brl + (size_t)t * 16 * K + k0);
    }
#pragma unroll
    for (int t = 0; t < NT; t++) {
#pragma unroll
      for (int mt = 0; mt < MT; mt++) {
        acc[mt][t] = __builtin_amdgcn_mfma_f32_16x16x32_bf16(a_h[mt], b_h[t], acc[mt][t], 0, 0, 0);
        acc[mt][t] = __builtin_amdgcn_mfma_f32_16x16x32_bf16(a_h[mt], b_l[t], acc[mt][t], 0, 0, 0);
        acc[mt][t] = __builtin_amdgcn_mfma_f32_16x16x32_bf16(a_l[mt], b_h[t], acc[mt][t], 0, 0, 0);
      }
    }
  }
#pragma unroll
  for (int mt = 0; mt < MT; mt++) {
#pragma unroll
    for (int t = 0; t < NT; t++) {
#pragma unroll
      for (int r = 0; r < 4; r++) {
        int m = m0 + mt * 16 + quad * 4 + r;
        if (m < M)
          Ch[(size_t)m * NcFull + col0 + t * 16 + l16] = (__bf16)acc[mt][t][r];
      }
    }
  }
}

// ---------------- attention dots (bf16-hi) ----------------
__global__ __launch_bounds__(256) void k_att(const __bf16* __restrict__ Hh,
                                             const float* __restrict__ attS,
                                             const float* __restrict__ attD,
                                             float* __restrict__ aS,
                                             float* __restrict__ aD, int NH, int H) {
  int idx = blockIdx.x * 256 + threadIdx.x;
  if (idx >= NH) return;
  int h = idx % H;
  const bf16x8* hv = (const bf16x8*)(Hh + (size_t)idx * 32);
  const float* sv = attS + h * 32;
  const float* dv = attD + h * 32;
  float ss = 0.f, dd = 0.f;
#pragma unroll
  for (int k = 0; k < 4; k++) {
    bf16x8 a = hv[k];
#pragma unroll
    for (int j = 0; j < 8; j++) {
      float v = (float)a[j];
      ss += v * sv[k * 8 + j];
      dd += v * dv[k * 8 + j];
    }
  }
  aS[idx] = ss;
  aD[idx] = dd;
}

// ---------------- GAT aggregation, H=8 ----------------
// One wave per dst node. Pass 1: exp(leaky(e)) once per (edge,head) -> bf16
// ealpha + shuffle-reduced sums. Pass 2 (serial edges, unroll-2): lane = 4
// consecutive channels (head = lane>>3), one bf16x4 row load/edge; normalize
// in epilogue. ELU + split-bf16 out.
__global__ __launch_bounds__(256) void k_gat_agg8(
    const __bf16* __restrict__ Hh, const float* __restrict__ aS,
    const float* __restrict__ aD, const int* __restrict__ rowptr,
    const int* __restrict__ colsrc, const float* __restrict__ bias,
    __bf16* __restrict__ ealpha, __bf16* __restrict__ outh,
    __bf16* __restrict__ outl, int N) {
  int wid = (blockIdx.x * blockDim.x + threadIdx.x) >> 6;
  int lane = threadIdx.x & 63;
  if (wid >= N) return;
  int n = wid;
  int row0 = rowptr[n];
  int deg = rowptr[n + 1] - row0;

  float adn[8], s[8];
#pragma unroll
  for (int h = 0; h < 8; h++) {
    adn[h] = aD[(size_t)n * 8 + h];
    s[h] = 0.f;
  }
  for (int i = lane; i < deg; i += 64) {
    int slot = row0 + i;
    int src = colsrc[slot];
    const float* ap = aS + (size_t)src * 8;
    bf16x8 ev;
#pragma unroll
    for (int h = 0; h < 8; h++) {
      float e = ap[h] + adn[h];
      e = (e > 0.f) ? e : 0.2f * e;
      float x = __expf(e);
      s[h] += x;
      ev[h] = (__bf16)x;
    }
    *(bf16x8*)(ealpha + (size_t)slot * 8) = ev;
  }
#pragma unroll
  for (int h = 0; h < 8; h++) {
#pragma unroll
    for (int off = 32; off > 0; off >>= 1) s[h] += __shfl_xor(s[h], off, 64);
  }
  int head = lane >> 3;
  float r0 = (head & 4) ? s[4] : s[0];
  float r1 = (head & 4) ? s[5] : s[1];
  float r2 = (head & 4) ? s[6] : s[2];
  float r3 = (head & 4) ? s[7] : s[3];
  float u0 = (head & 2) ? r2 : r0;
  float u1 = (head & 2) ? r3 : r1;
  float rsv = 1.f / ((head & 1) ? u1 : u0);

  f32x4 acc = (f32x4){0.f, 0.f, 0.f, 0.f};
  const __bf16* ea = ealpha;
  int i = 0;
  for (; i + 1 < deg; i += 2) {
    int sl = row0 + i;
    int s0 = colsrc[sl];
    int s1 = colsrc[sl + 1];
    float w0 = (float)ea[(size_t)sl * 8 + head];
    float w1 = (float)ea[(size_t)(sl + 1) * 8 + head];
    bf16x4 h0 = *(const bf16x4*)(Hh + (size_t)s0 * 256 + lane * 4);
    bf16x4 h1 = *(const bf16x4*)(Hh + (size_t)s1 * 256 + lane * 4);
#pragma unroll
    for (int j = 0; j < 4; j++) acc[j] += w0 * (float)h0[j];
#pragma unroll
    for (int j = 0; j < 4; j++) acc[j] += w1 * (float)h1[j];
  }
  if (i < deg) {
    int sl = row0 + i;
    int s0 = colsrc[sl];
    float w0 = (float)ea[(size_t)sl * 8 + head];
    bf16x4 h0 = *(const bf16x4*)(Hh + (size_t)s0 * 256 + lane * 4);
#pragma unroll
    for (int j = 0; j < 4; j++) acc[j] += w0 * (float)h0[j];
  }
  float4 bv = *(const float4*)(bias + lane * 4);
  bf16x4 hb, lb;
#pragma unroll
  for (int j = 0; j < 4; j++) {
    float v = acc[j] * rsv + ((const float*)&bv)[j];
    v = (v > 0.f) ? v : (__expf(v) - 1.f);  // ELU
    hb[j] = (__bf16)v;
    lb[j] = (__bf16)(v - (float)hb[j]);
  }
  *(bf16x4*)(outh + (size_t)n * 256 + lane * 4) = hb;
  *(bf16x4*)(outl + (size_t)n * 256 + lane * 4) = lb;
}

// ---------------- GAT aggregation, H=1 (layer 3, fp32 out, no ELU) ------
__global__ __launch_bounds__(256) void k_gat_agg1(
    const __bf16* __restrict__ Hh, const float* __restrict__ aS,
    const float* __restrict__ aD, const int* __restrict__ rowptr,
    const int* __restrict__ colsrc, const float* __restrict__ bias,
    __bf16* __restrict__ ealpha, float* __restrict__ out, int N) {
  int wid = (blockIdx.x * blockDim.x + threadIdx.x) >> 6;
  int lane = threadIdx.x & 63;
  if (wid >= N) return;
  int n = wid;
  int row0 = rowptr[n];
  int deg = rowptr[n + 1] - row0;
  float adn = aD[n];
  float s = 0.f;
  for (int i = lane; i < deg; i += 64) {
    int slot = row0 + i;
    float e = aS[colsrc[slot]] + adn;
    e = (e > 0.f) ? e : 0.2f * e;
    float x = __expf(e);
    s += x;
    ealpha[slot] = (__bf16)x;
  }
#pragma unroll
  for (int off = 32; off > 0; off >>= 1) s += __shfl_xor(s, off, 64);
  float rsv = 1.f / s;

  int eo = lane >> 3;
  int cl = lane & 7;
  f32x4 acc = (f32x4){0.f, 0.f, 0.f, 0.f};
  for (int i = eo; i < deg; i += 8) {
    int slot = row0 + i;
    int src = colsrc[slot];
    float w = (float)ealpha[slot];
    bf16x4 hv = *(const bf16x4*)(Hh + (size_t)src * 32 + cl * 4);
#pragma unroll
    for (int j = 0; j < 4; j++) acc[j] += w * (float)hv[j];
  }
#pragma unroll
  for (int j = 0; j < 4; j++) {
#pragma unroll
    for (int off = 8; off < 64; off <<= 1) acc[j] += __shfl_xor(acc[j], off, 64);
  }
  if (eo == 0) {
#pragma unroll
    for (int j = 0; j < 4; j++)
      out[(size_t)n * 32 + cl * 4 + j] = acc[j] * rsv + bias[cl * 4 + j];
  }
}

// ---------------- fused mean-pool + linear ----------------
__global__ __launch_bounds__(256) void k_pool_final(
    const float* __restrict__ h, const int* __restrict__ batch,
    const float* __restrict__ linW, const float* __restrict__ linb,
    float* __restrict__ out, int N) {
  __shared__ float sh[256];
  int g = blockIdx.x;
  int tid = threadIdx.x;
  int grp = tid >> 5, c = tid & 31;
  int lo = 0, hi = N;
  while (lo < hi) { int mid = (lo + hi) >> 1; if (batch[mid] < g) lo = mid + 1; else hi = mid; }
  int start = lo;
  hi = N;
  while (lo < hi) { int mid = (lo + hi) >> 1; if (batch[mid] < g + 1) lo = mid + 1; else hi = mid; }
  int end = lo;
  float acc = 0.f;
  for (int n = start + grp; n < end; n += 8) acc += h[(size_t)n * 32 + c];
  sh[tid] = acc;
  __syncthreads();
  if (tid < 32) {
    float s = 0.f;
#pragma unroll
    for (int j = 0; j < 8; j++) s += sh[j * 32 + tid];
    float v = s * linW[tid];
#pragma unroll
    for (int off = 16; off > 0; off >>= 1) v += __shfl_xor(v, off, 64);
    if (tid == 0) {
      float cnt = (float)(end - start);
      out[g] = v / fmaxf(cnt, 1.f) + linb[0];
    }
  }
}

extern "C" void kernel_launch(void* const* d_in, const int* in_sizes, int n_in,
                              void* d_out, int out_size, void* d_ws, size_t ws_size,
                              hipStream_t stream) {
  const float* x = (const float*)d_in[0];
  const int* ei = (const int*)d_in[1];
  const int* batch = (const int*)d_in[2];
  const float* W1 = (const float*)d_in[3];
  const float* as1 = (const float*)d_in[4];
  const float* ad1 = (const float*)d_in[5];
  const float* b1 = (const float*)d_in[6];
  const float* W2 = (const float*)d_in[7];
  const float* as2 = (const float*)d_in[8];
  const float* ad2 = (const float*)d_in[9];
  const float* b2 = (const float*)d_in[10];
  const float* W3 = (const float*)d_in[11];
  const float* as3 = (const float*)d_in[12];
  const float* ad3 = (const float*)d_in[13];
  const float* b3 = (const float*)d_in[14];
  const float* linW = (const float*)d_in[15];
  const float* linb = (const float*)d_in[16];

  const int N = in_sizes[0] / 256;
  const int E = in_sizes[1] / 2;
  const int NUM_GRAPHS = 64;
  float* out = (float*)d_out;

  char* ws = (char*)d_ws;
  size_t off = 0;
  auto alloc = [&](size_t bytes) -> void* {
    void* p = ws + off;
    off += (bytes + 255) & ~(size_t)255;
    return p;
  };
  __bf16* Hh = (__bf16*)alloc((size_t)N * 256 * 2);  // GEMM h out (bf16-hi)
  __bf16* Ah = (__bf16*)alloc((size_t)N * 256 * 2);  // GEMM A in (hi)
  __bf16* Al = (__bf16*)alloc((size_t)N * 256 * 2);  //           (lo)
  __bf16* ealpha = (__bf16*)alloc((size_t)(E + N) * 8 * 2);  // per-edge exps
  float* aS = (float*)alloc((size_t)N * 8 * 4);
  float* aD = (float*)alloc((size_t)N * 8 * 4);
  int* deg = (int*)alloc((size_t)N * 4);
  int* rowptr = (int*)alloc((size_t)(N + 1) * 4);
  int* cursor = (int*)alloc((size_t)(N + 1) * 4);
  int* colsrc = (int*)alloc((size_t)(E + N) * 4);
  int* blockSums = (int*)alloc(256 * 4);
  int* blockOffs = (int*)alloc(256 * 4);
  __bf16* WT1h = (__bf16*)alloc(256 * 256 * 2);
  __bf16* WT1l = (__bf16*)alloc(256 * 256 * 2);
  __bf16* WT2h = (__bf16*)alloc(256 * 256 * 2);
  __bf16* WT2l = (__bf16*)alloc(256 * 256 * 2);
  __bf16* WT3h = (__bf16*)alloc(32 * 256 * 2);
  __bf16* WT3l = (__bf16*)alloc(32 * 256 * 2);
  // h3agg reuses Ah (GEMM3 already consumed Ah/Al when agg3 writes)
  float* h3agg = (float*)Ah;

  // --- preps: x split + W transposes/splits + CSR build ---
  k_split<<<(N * 64 + 255) / 256, 256, 0, stream>>>(x, Ah, Al, N * 64);
  k_wprep<<<(256 * 256 + 255) / 256, 256, 0, stream>>>(W1, WT1h, WT1l, 256, 256);
  k_wprep<<<(256 * 256 + 255) / 256, 256, 0, stream>>>(W2, WT2h, WT2l, 256, 256);
  k_wprep<<<(256 * 32 + 255) / 256, 256, 0, stream>>>(W3, WT3h, WT3l, 256, 32);
  k_init_deg<<<(N + 255) / 256, 256, 0, stream>>>(deg, N);
  k_count_deg<<<(E + 255) / 256, 256, 0, stream>>>(ei, E, deg);
  const int nb = (N + 256 * SCAN_CH - 1) / (256 * SCAN_CH);  // 49 <= 256
  k_scan_partial<<<nb, 256, 0, stream>>>(deg, blockSums, N);
  k_scan_blocksums<<<1, 256, 0, stream>>>(blockSums, blockOffs, rowptr, nb, N);
  k_scan_final<<<nb, 256, 0, stream>>>(deg, blockOffs, rowptr, cursor, N);
  k_scatter<<<(E + N + 255) / 256, 256, 0, stream>>>(ei, E, N, cursor, colsrc);

  const int aggBlocks = (N + 3) / 4;
  dim3 g12(4, (N + 127) / 128);
  dim3 g3(1, (N + 63) / 64);

  // --- layer 1 ---
  k_gemm_split<4, 2><<<g12, 256, 0, stream>>>(Ah, Al, WT1h, WT1l, Hh, N, 256, 256);
  k_att<<<(N * 8 + 255) / 256, 256, 0, stream>>>(Hh, as1, ad1, aS, aD, N * 8, 8);
  k_gat_agg8<<<aggBlocks, 256, 0, stream>>>(Hh, aS, aD, rowptr, colsrc, b1,
                                            ealpha, Ah, Al, N);
  // --- layer 2 ---
  k_gemm_split<4, 2><<<g12, 256, 0, stream>>>(Ah, Al, WT2h, WT2l, Hh, N, 256, 256);
  k_att<<<(N * 8 + 255) / 256, 256, 0, stream>>>(Hh, as2, ad2, aS, aD, N * 8, 8);
  k_gat_agg8<<<aggBlocks, 256, 0, stream>>>(Hh, aS, aD, rowptr, colsrc, b2,
                                            ealpha, Ah, Al, N);
  // --- layer 3 (H=1) ---
  k_gemm_split<2, 1><<<g3, 256, 0, stream>>>(Ah, Al, WT3h, WT3l, Hh, N, 256, 32);
  k_att<<<(N + 255) / 256, 256, 0, stream>>>(Hh, as3, ad3, aS, aD, N, 1);
  k_gat_agg1<<<aggBlocks, 256, 0, stream>>>(Hh, aS, aD, rowptr, colsrc, b3,
                                            ealpha, h3agg, N);
  // --- pool + final ---
  k_pool_final<<<NUM_GRAPHS, 256, 0, stream>>>(h3agg, batch, linW, linb, out, N);
}

// Round 9
// 659.676 us; speedup vs baseline: 2.1496x; 1.0167x over previous
//
#include <hip/hip_runtime.h>
#include <hip/hip_fp8.h>
#include <math.h>

// ---------------------------------------------------------------------------
// GATClassifier on MI355X.
//   1. CSR build over dst (histogram -> 3-phase device-wide scan -> scatter)
//   2. Per layer: split-bf16 MFMA GEMM (Ah*Bh + Ah*Bl + Al*Bh, fp32 acc),
//      h stored bf16-hi + fp8-e4m3 copy (layers 1/2); att dots from bf16;
//      agg pass1: exp(leaky(e)) once per (edge,head) -> bf16 ealpha + sums;
//      agg pass2: gathers FP8 row chunks (256B/row vs 512B bf16 — R8 showed
//      agg8 at 43% HBM / 50% VALU, so bytes/edge is the lever) weighted by
//      ealpha; normalize in epilogue; split-bf16 out for next GEMM.
//   3. Fused mean-pool + 32->1 linear (batch sorted -> binary search)
// History: R2 atomic pool 383us. R3 fp32 SGEMM 158x2. R4 agg fp32-gather
// 155x2. R5 gemm latency 140x2 -> R6 re-tile. R6 agg 131x2 -> R7 ealpha+
// vec gather. R7 1-block scan 111us -> R8 3-phase. R8 agg8 87x2 -> R9 fp8.
// NOTE: edge_index / batch are int32.
// ---------------------------------------------------------------------------

typedef __attribute__((ext_vector_type(8))) __bf16 bf16x8;
typedef __attribute__((ext_vector_type(4))) __bf16 bf16x4;
typedef __attribute__((ext_vector_type(4))) float f32x4;

#define SCAN_CH 4  // elements per thread in the device-wide scan

__device__ inline unsigned char f32_to_fp8(float f) {
  __hip_fp8_e4m3 v(f);
  return (unsigned char)v.__x;
}
__device__ inline float fp8_to_f32(unsigned char u) {
  __hip_fp8_e4m3 v;
  v.__x = (__hip_fp8_storage_t)u;
  return (float)v;
}

// ---------------- CSR build ----------------
__global__ __launch_bounds__(256) void k_init_deg(int* deg, int N) {
  int n = blockIdx.x * 256 + threadIdx.x;
  if (n < N) deg[n] = 1;  // self-loop
}

__global__ __launch_bounds__(256) void k_count_deg(const int* __restrict__ ei,
                                                   int E, int* deg) {
  int e = blockIdx.x * 256 + threadIdx.x;
  if (e < E) atomicAdd(&deg[ei[E + e]], 1);
}

// --- 3-phase exclusive scan (R8: old single-block scan was 111us on 1 CU) ---
__global__ __launch_bounds__(256) void k_scan_partial(const int* __restrict__ deg,
                                                      int* __restrict__ blockSums,
                                                      int N) {
  __shared__ int sh[256];
  int t = threadIdx.x, b = blockIdx.x;
  int base = (b * 256 + t) * SCAN_CH;
  int s = 0;
#pragma unroll
  for (int j = 0; j < SCAN_CH; j++) {
    int idx = base + j;
    if (idx < N) s += deg[idx];
  }
  sh[t] = s;
  __syncthreads();
  for (int off = 128; off > 0; off >>= 1) {
    if (t < off) sh[t] += sh[t + off];
    __syncthreads();
  }
  if (t == 0) blockSums[b] = sh[0];
}

__global__ __launch_bounds__(256) void k_scan_blocksums(
    const int* __restrict__ blockSums, int* __restrict__ blockOffs,
    int* __restrict__ rowptr, int nb, int N) {
  __shared__ int sh[256];
  int t = threadIdx.x;
  int v = (t < nb) ? blockSums[t] : 0;
  sh[t] = v;
  __syncthreads();
  for (int off = 1; off < 256; off <<= 1) {
    int u = (t >= off) ? sh[t - off] : 0;
    __syncthreads();
    sh[t] += u;
    __syncthreads();
  }
  if (t < nb) blockOffs[t] = sh[t] - v;  // exclusive
  if (t == nb - 1) rowptr[N] = sh[t];    // total
}

__global__ __launch_bounds__(256) void k_scan_final(const int* __restrict__ deg,
                                                    const int* __restrict__ blockOffs,
                                                    int* __restrict__ rowptr,
                                                    int* __restrict__ cursor, int N) {
  __shared__ int sh[256];
  int t = threadIdx.x, b = blockIdx.x;
  int base = (b * 256 + t) * SCAN_CH;
  int vals[SCAN_CH];
  int s = 0;
#pragma unroll
  for (int j = 0; j < SCAN_CH; j++) {
    int idx = base + j;
    vals[j] = (idx < N) ? deg[idx] : 0;
    s += vals[j];
  }
  sh[t] = s;
  __syncthreads();
  for (int off = 1; off < 256; off <<= 1) {
    int u = (t >= off) ? sh[t - off] : 0;
    __syncthreads();
    sh[t] += u;
    __syncthreads();
  }
  int run = blockOffs[b] + sh[t] - s;  // exclusive prefix for this thread
#pragma unroll
  for (int j = 0; j < SCAN_CH; j++) {
    int idx = base + j;
    if (idx < N) {
      rowptr[idx] = run;
      cursor[idx] = run;
      run += vals[j];
    }
  }
}

__global__ __launch_bounds__(256) void k_scatter(const int* __restrict__ ei,
                                                 int E, int N, int* cursor,
                                                 int* __restrict__ colsrc) {
  int i = blockIdx.x * 256 + threadIdx.x;
  if (i < E) {
    int s = ei[i];
    int d = ei[E + i];
    int pos = atomicAdd(&cursor[d], 1);
    colsrc[pos] = s;
  } else if (i < E + N) {
    int nn = i - E;
    int pos = atomicAdd(&cursor[nn], 1);
    colsrc[pos] = nn;  // self loop
  }
}

// ---------------- split-cast preps ----------------
__global__ __launch_bounds__(256) void k_split(const float* __restrict__ in,
                                               __bf16* __restrict__ oh,
                                               __bf16* __restrict__ ol, int n4) {
  int i = blockIdx.x * 256 + threadIdx.x;
  if (i >= n4) return;
  float4 v = ((const float4*)in)[i];
  bf16x4 h, l;
  h[0] = (__bf16)v.x; l[0] = (__bf16)(v.x - (float)h[0]);
  h[1] = (__bf16)v.y; l[1] = (__bf16)(v.y - (float)h[1]);
  h[2] = (__bf16)v.z; l[2] = (__bf16)(v.z - (float)h[2]);
  h[3] = (__bf16)v.w; l[3] = (__bf16)(v.w - (float)h[3]);
  ((bf16x4*)oh)[i] = h;
  ((bf16x4*)ol)[i] = l;
}

// W [K][Nc] fp32 -> WT hi/lo [Nc][K] bf16 (transposed so B-frags load b128).
__global__ __launch_bounds__(256) void k_wprep(const float* __restrict__ W,
                                               __bf16* __restrict__ WTh,
                                               __bf16* __restrict__ WTl,
                                               int K, int Nc) {
  int i = blockIdx.x * 256 + threadIdx.x;  // i = n*K + k
  if (i >= K * Nc) return;
  int n = i / K, k = i - n * K;
  float w = W[k * Nc + n];
  __bf16 h = (__bf16)w;
  WTh[i] = h;
  WTl[i] = (__bf16)(w - (float)h);
}

// ---------------- split-bf16 MFMA GEMM (bf16-hi [+fp8] output) ----------
// Block = 4 waves; wave = MT m-tiles x NT col-tiles; batched b128 loads then
// MT*NT*3 MFMAs (R6 fix for the R5 latency stall). F8: also emit an
// fp8-e4m3 copy of the output for the agg gather (R9).
// mfma_f32_16x16x32_bf16 (m89-verified): A: m=lane&15,k=quad*8+j;
// B: n=lane&15,k=quad*8+j (from WT); C/D: row=quad*4+reg, col=lane&15.
template <int NT, int MT, bool F8>
__global__ __launch_bounds__(256) void k_gemm_split(
    const __bf16* __restrict__ Ah, const __bf16* __restrict__ Al,
    const __bf16* __restrict__ BTh, const __bf16* __restrict__ BTl,
    __bf16* __restrict__ Ch, unsigned char* __restrict__ Cf8,
    int M, int K, int NcFull) {
  int lane = threadIdx.x & 63;
  int wave = threadIdx.x >> 6;
  int quad = lane >> 4;
  int l16 = lane & 15;
  int m0 = blockIdx.y * (64 * MT) + wave * (16 * MT);
  int col0 = blockIdx.x * (NT * 16);
  const __bf16* arh[MT];
  const __bf16* arl[MT];
#pragma unroll
  for (int mt = 0; mt < MT; mt++) {
    int am = min(m0 + mt * 16 + l16, M - 1);  // clamp: rows >= M never stored
    arh[mt] = Ah + (size_t)am * K + quad * 8;
    arl[mt] = Al + (size_t)am * K + quad * 8;
  }
  const __bf16* brh = BTh + (size_t)(col0 + l16) * K + quad * 8;
  const __bf16* brl = BTl + (size_t)(col0 + l16) * K + quad * 8;
  f32x4 acc[MT][NT];
#pragma unroll
  for (int mt = 0; mt < MT; mt++)
#pragma unroll
    for (int t = 0; t < NT; t++) acc[mt][t] = (f32x4){0.f, 0.f, 0.f, 0.f};
  for (int k0 = 0; k0 < K; k0 += 32) {
    bf16x8 a_h[MT], a_l[MT], b_h[NT], b_l[NT];
#pragma unroll
    for (int mt = 0; mt < MT; mt++) {
      a_h[mt] = *(const bf16x8*)(arh[mt] + k0);
      a_l[mt] = *(const bf16x8*)(arl[mt] + k0);
    }
#pragma unroll
    for (int t = 0; t < NT; t++) {
      b_h[t] = *(const bf16x8*)(brh + (size_t)t * 16 * K + k0);
      b_l[t] = *(const bf16x8*)(brl + (size_t)t * 16 * K + k0);
    }
#pragma unroll
    for (int t = 0; t < NT; t++) {
#pragma unroll
      for (int mt = 0; mt < MT; mt++) {
        acc[mt][t] = __builtin_amdgcn_mfma_f32_16x16x32_bf16(a_h[mt], b_h[t], acc[mt][t], 0, 0, 0);
        acc[mt][t] = __builtin_amdgcn_mfma_f32_16x16x32_bf16(a_h[mt], b_l[t], acc[mt][t], 0, 0, 0);
        acc[mt][t] = __builtin_amdgcn_mfma_f32_16x16x32_bf16(a_l[mt], b_h[t], acc[mt][t], 0, 0, 0);
      }
    }
  }
#pragma unroll
  for (int mt = 0; mt < MT; mt++) {
#pragma unroll
    for (int t = 0; t < NT; t++) {
#pragma unroll
      for (int r = 0; r < 4; r++) {
        int m = m0 + mt * 16 + quad * 4 + r;
        if (m < M) {
          size_t o = (size_t)m * NcFull + col0 + t * 16 + l16;
          Ch[o] = (__bf16)acc[mt][t][r];
          if constexpr (F8) Cf8[o] = f32_to_fp8(acc[mt][t][r]);
        }
      }
    }
  }
}

// ---------------- attention dots (bf16-hi) ----------------
__global__ __launch_bounds__(256) void k_att(const __bf16* __restrict__ Hh,
                                             const float* __restrict__ attS,
                                             const float* __restrict__ attD,
                                             float* __restrict__ aS,
                                             float* __restrict__ aD, int NH, int H) {
  int idx = blockIdx.x * 256 + threadIdx.x;
  if (idx >= NH) return;
  int h = idx % H;
  const bf16x8* hv = (const bf16x8*)(Hh + (size_t)idx * 32);
  const float* sv = attS + h * 32;
  const float* dv = attD + h * 32;
  float ss = 0.f, dd = 0.f;
#pragma unroll
  for (int k = 0; k < 4; k++) {
    bf16x8 a = hv[k];
#pragma unroll
    for (int j = 0; j < 8; j++) {
      float v = (float)a[j];
      ss += v * sv[k * 8 + j];
      dd += v * dv[k * 8 + j];
    }
  }
  aS[idx] = ss;
  aD[idx] = dd;
}

// ---------------- GAT aggregation, H=8 ----------------
// One wave per dst node. Pass 1: exp(leaky(e)) once per (edge,head) -> bf16
// ealpha + shuffle-reduced sums. Pass 2 (serial edges, unroll-2): lane = 4
// consecutive channels (head = lane>>3), one FP8x4 (4B) row load per edge
// (R9: halves R8's 233MB gather fetch); normalize in epilogue. ELU +
// split-bf16 out.
__global__ __launch_bounds__(256) void k_gat_agg8(
    const unsigned char* __restrict__ Hf8, const float* __restrict__ aS,
    const float* __restrict__ aD, const int* __restrict__ rowptr,
    const int* __restrict__ colsrc, const float* __restrict__ bias,
    __bf16* __restrict__ ealpha, __bf16* __restrict__ outh,
    __bf16* __restrict__ outl, int N) {
  int wid = (blockIdx.x * blockDim.x + threadIdx.x) >> 6;
  int lane = threadIdx.x & 63;
  if (wid >= N) return;
  int n = wid;
  int row0 = rowptr[n];
  int deg = rowptr[n + 1] - row0;

  float adn[8], s[8];
#pragma unroll
  for (int h = 0; h < 8; h++) {
    adn[h] = aD[(size_t)n * 8 + h];
    s[h] = 0.f;
  }
  for (int i = lane; i < deg; i += 64) {
    int slot = row0 + i;
    int src = colsrc[slot];
    const float* ap = aS + (size_t)src * 8;
    bf16x8 ev;
#pragma unroll
    for (int h = 0; h < 8; h++) {
      float e = ap[h] + adn[h];
      e = (e > 0.f) ? e : 0.2f * e;
      float x = __expf(e);
      s[h] += x;
      ev[h] = (__bf16)x;
    }
    *(bf16x8*)(ealpha + (size_t)slot * 8) = ev;
  }
#pragma unroll
  for (int h = 0; h < 8; h++) {
#pragma unroll
    for (int off = 32; off > 0; off >>= 1) s[h] += __shfl_xor(s[h], off, 64);
  }
  int head = lane >> 3;
  float r0 = (head & 4) ? s[4] : s[0];
  float r1 = (head & 4) ? s[5] : s[1];
  float r2 = (head & 4) ? s[6] : s[2];
  float r3 = (head & 4) ? s[7] : s[3];
  float u0 = (head & 2) ? r2 : r0;
  float u1 = (head & 2) ? r3 : r1;
  float rsv = 1.f / ((head & 1) ? u1 : u0);

  f32x4 acc = (f32x4){0.f, 0.f, 0.f, 0.f};
  const __bf16* ea = ealpha;
  int i = 0;
  for (; i + 1 < deg; i += 2) {
    int sl = row0 + i;
    int s0 = colsrc[sl];
    int s1 = colsrc[sl + 1];
    float w0 = (float)ea[(size_t)sl * 8 + head];
    float w1 = (float)ea[(size_t)(sl + 1) * 8 + head];
    uchar4 h0 = *(const uchar4*)(Hf8 + (size_t)s0 * 256 + lane * 4);
    uchar4 h1 = *(const uchar4*)(Hf8 + (size_t)s1 * 256 + lane * 4);
    acc[0] += w0 * fp8_to_f32(h0.x);
    acc[1] += w0 * fp8_to_f32(h0.y);
    acc[2] += w0 * fp8_to_f32(h0.z);
    acc[3] += w0 * fp8_to_f32(h0.w);
    acc[0] += w1 * fp8_to_f32(h1.x);
    acc[1] += w1 * fp8_to_f32(h1.y);
    acc[2] += w1 * fp8_to_f32(h1.z);
    acc[3] += w1 * fp8_to_f32(h1.w);
  }
  if (i < deg) {
    int sl = row0 + i;
    int s0 = colsrc[sl];
    float w0 = (float)ea[(size_t)sl * 8 + head];
    uchar4 h0 = *(const uchar4*)(Hf8 + (size_t)s0 * 256 + lane * 4);
    acc[0] += w0 * fp8_to_f32(h0.x);
    acc[1] += w0 * fp8_to_f32(h0.y);
    acc[2] += w0 * fp8_to_f32(h0.z);
    acc[3] += w0 * fp8_to_f32(h0.w);
  }
  float4 bv = *(const float4*)(bias + lane * 4);
  bf16x4 hb, lb;
#pragma unroll
  for (int j = 0; j < 4; j++) {
    float v = acc[j] * rsv + ((const float*)&bv)[j];
    v = (v > 0.f) ? v : (__expf(v) - 1.f);  // ELU
    hb[j] = (__bf16)v;
    lb[j] = (__bf16)(v - (float)hb[j]);
  }
  *(bf16x4*)(outh + (size_t)n * 256 + lane * 4) = hb;
  *(bf16x4*)(outl + (size_t)n * 256 + lane * 4) = lb;
}

// ---------------- GAT aggregation, H=1 (layer 3, fp32 out, no ELU) ------
// bf16 gather (layer-3 error path skips the pooling washout; rows only 64B).
__global__ __launch_bounds__(256) void k_gat_agg1(
    const __bf16* __restrict__ Hh, const float* __restrict__ aS,
    const float* __restrict__ aD, const int* __restrict__ rowptr,
    const int* __restrict__ colsrc, const float* __restrict__ bias,
    __bf16* __restrict__ ealpha, float* __restrict__ out, int N) {
  int wid = (blockIdx.x * blockDim.x + threadIdx.x) >> 6;
  int lane = threadIdx.x & 63;
  if (wid >= N) return;
  int n = wid;
  int row0 = rowptr[n];
  int deg = rowptr[n + 1] - row0;
  float adn = aD[n];
  float s = 0.f;
  for (int i = lane; i < deg; i += 64) {
    int slot = row0 + i;
    float e = aS[colsrc[slot]] + adn;
    e = (e > 0.f) ? e : 0.2f * e;
    float x = __expf(e);
    s += x;
    ealpha[slot] = (__bf16)x;
  }
#pragma unroll
  for (int off = 32; off > 0; off >>= 1) s += __shfl_xor(s, off, 64);
  float rsv = 1.f / s;

  int eo = lane >> 3;
  int cl = lane & 7;
  f32x4 acc = (f32x4){0.f, 0.f, 0.f, 0.f};
  for (int i = eo; i < deg; i += 8) {
    int slot = row0 + i;
    int src = colsrc[slot];
    float w = (float)ealpha[slot];
    bf16x4 hv = *(const bf16x4*)(Hh + (size_t)src * 32 + cl * 4);
#pragma unroll
    for (int j = 0; j < 4; j++) acc[j] += w * (float)hv[j];
  }
#pragma unroll
  for (int j = 0; j < 4; j++) {
#pragma unroll
    for (int off = 8; off < 64; off <<= 1) acc[j] += __shfl_xor(acc[j], off, 64);
  }
  if (eo == 0) {
#pragma unroll
    for (int j = 0; j < 4; j++)
      out[(size_t)n * 32 + cl * 4 + j] = acc[j] * rsv + bias[cl * 4 + j];
  }
}

// ---------------- fused mean-pool + linear ----------------
__global__ __launch_bounds__(256) void k_pool_final(
    const float* __restrict__ h, const int* __restrict__ batch,
    const float* __restrict__ linW, const float* __restrict__ linb,
    float* __restrict__ out, int N) {
  __shared__ float sh[256];
  int g = blockIdx.x;
  int tid = threadIdx.x;
  int grp = tid >> 5, c = tid & 31;
  int lo = 0, hi = N;
  while (lo < hi) { int mid = (lo + hi) >> 1; if (batch[mid] < g) lo = mid + 1; else hi = mid; }
  int start = lo;
  hi = N;
  while (lo < hi) { int mid = (lo + hi) >> 1; if (batch[mid] < g + 1) lo = mid + 1; else hi = mid; }
  int end = lo;
  float acc = 0.f;
  for (int n = start + grp; n < end; n += 8) acc += h[(size_t)n * 32 + c];
  sh[tid] = acc;
  __syncthreads();
  if (tid < 32) {
    float s = 0.f;
#pragma unroll
    for (int j = 0; j < 8; j++) s += sh[j * 32 + tid];
    float v = s * linW[tid];
#pragma unroll
    for (int off = 16; off > 0; off >>= 1) v += __shfl_xor(v, off, 64);
    if (tid == 0) {
      float cnt = (float)(end - start);
      out[g] = v / fmaxf(cnt, 1.f) + linb[0];
    }
  }
}

extern "C" void kernel_launch(void* const* d_in, const int* in_sizes, int n_in,
                              void* d_out, int out_size, void* d_ws, size_t ws_size,
                              hipStream_t stream) {
  const float* x = (const float*)d_in[0];
  const int* ei = (const int*)d_in[1];
  const int* batch = (const int*)d_in[2];
  const float* W1 = (const float*)d_in[3];
  const float* as1 = (const float*)d_in[4];
  const float* ad1 = (const float*)d_in[5];
  const float* b1 = (const float*)d_in[6];
  const float* W2 = (const float*)d_in[7];
  const float* as2 = (const float*)d_in[8];
  const float* ad2 = (const float*)d_in[9];
  const float* b2 = (const float*)d_in[10];
  const float* W3 = (const float*)d_in[11];
  const float* as3 = (const float*)d_in[12];
  const float* ad3 = (const float*)d_in[13];
  const float* b3 = (const float*)d_in[14];
  const float* linW = (const float*)d_in[15];
  const float* linb = (const float*)d_in[16];

  const int N = in_sizes[0] / 256;
  const int E = in_sizes[1] / 2;
  const int NUM_GRAPHS = 64;
  float* out = (float*)d_out;

  char* ws = (char*)d_ws;
  size_t off = 0;
  auto alloc = [&](size_t bytes) -> void* {
    void* p = ws + off;
    off += (bytes + 255) & ~(size_t)255;
    return p;
  };
  __bf16* Hh = (__bf16*)alloc((size_t)N * 256 * 2);  // GEMM h out (bf16-hi)
  unsigned char* Hf8 = (unsigned char*)alloc((size_t)N * 256);  // fp8 copy
  __bf16* Ah = (__bf16*)alloc((size_t)N * 256 * 2);  // GEMM A in (hi)
  __bf16* Al = (__bf16*)alloc((size_t)N * 256 * 2);  //           (lo)
  __bf16* ealpha = (__bf16*)alloc((size_t)(E + N) * 8 * 2);  // per-edge exps
  float* aS = (float*)alloc((size_t)N * 8 * 4);
  float* aD = (float*)alloc((size_t)N * 8 * 4);
  int* deg = (int*)alloc((size_t)N * 4);
  int* rowptr = (int*)alloc((size_t)(N + 1) * 4);
  int* cursor = (int*)alloc((size_t)(N + 1) * 4);
  int* colsrc = (int*)alloc((size_t)(E + N) * 4);
  int* blockSums = (int*)alloc(256 * 4);
  int* blockOffs = (int*)alloc(256 * 4);
  __bf16* WT1h = (__bf16*)alloc(256 * 256 * 2);
  __bf16* WT1l = (__bf16*)alloc(256 * 256 * 2);
  __bf16* WT2h = (__bf16*)alloc(256 * 256 * 2);
  __bf16* WT2l = (__bf16*)alloc(256 * 256 * 2);
  __bf16* WT3h = (__bf16*)alloc(32 * 256 * 2);
  __bf16* WT3l = (__bf16*)alloc(32 * 256 * 2);
  // h3agg reuses Ah (GEMM3 already consumed Ah/Al when agg3 writes)
  float* h3agg = (float*)Ah;

  // --- preps: x split + W transposes/splits + CSR build ---
  k_split<<<(N * 64 + 255) / 256, 256, 0, stream>>>(x, Ah, Al, N * 64);
  k_wprep<<<(256 * 256 + 255) / 256, 256, 0, stream>>>(W1, WT1h, WT1l, 256, 256);
  k_wprep<<<(256 * 256 + 255) / 256, 256, 0, stream>>>(W2, WT2h, WT2l, 256, 256);
  k_wprep<<<(256 * 32 + 255) / 256, 256, 0, stream>>>(W3, WT3h, WT3l, 256, 32);
  k_init_deg<<<(N + 255) / 256, 256, 0, stream>>>(deg, N);
  k_count_deg<<<(E + 255) / 256, 256, 0, stream>>>(ei, E, deg);
  const int nb = (N + 256 * SCAN_CH - 1) / (256 * SCAN_CH);  // 49 <= 256
  k_scan_partial<<<nb, 256, 0, stream>>>(deg, blockSums, N);
  k_scan_blocksums<<<1, 256, 0, stream>>>(blockSums, blockOffs, rowptr, nb, N);
  k_scan_final<<<nb, 256, 0, stream>>>(deg, blockOffs, rowptr, cursor, N);
  k_scatter<<<(E + N + 255) / 256, 256, 0, stream>>>(ei, E, N, cursor, colsrc);

  const int aggBlocks = (N + 3) / 4;
  dim3 g12(4, (N + 127) / 128);
  dim3 g3(1, (N + 63) / 64);

  // --- layer 1 ---
  k_gemm_split<4, 2, true><<<g12, 256, 0, stream>>>(Ah, Al, WT1h, WT1l, Hh, Hf8, N, 256, 256);
  k_att<<<(N * 8 + 255) / 256, 256, 0, stream>>>(Hh, as1, ad1, aS, aD, N * 8, 8);
  k_gat_agg8<<<aggBlocks, 256, 0, stream>>>(Hf8, aS, aD, rowptr, colsrc, b1,
                                            ealpha, Ah, Al, N);
  // --- layer 2 ---
  k_gemm_split<4, 2, true><<<g12, 256, 0, stream>>>(Ah, Al, WT2h, WT2l, Hh, Hf8, N, 256, 256);
  k_att<<<(N * 8 + 255) / 256, 256, 0, stream>>>(Hh, as2, ad2, aS, aD, N * 8, 8);
  k_gat_agg8<<<aggBlocks, 256, 0, stream>>>(Hf8, aS, aD, rowptr, colsrc, b2,
                                            ealpha, Ah, Al, N);
  // --- layer 3 (H=1, bf16 gather) ---
  k_gemm_split<2, 1, false><<<g3, 256, 0, stream>>>(Ah, Al, WT3h, WT3l, Hh, nullptr, N, 256, 32);
  k_att<<<(N + 255) / 256, 256, 0, stream>>>(Hh, as3, ad3, aS, aD, N, 1);
  k_gat_agg1<<<aggBlocks, 256, 0, stream>>>(Hh, aS, aD, rowptr, colsrc, b3,
                                            ealpha, h3agg, N);
  // --- pool + final ---
  k_pool_final<<<NUM_GRAPHS, 256, 0, stream>>>(h3agg, batch, linW, linb, out, N);
}

// Round 10
// 611.617 us; speedup vs baseline: 2.3186x; 1.0786x over previous
//
#include <hip/hip_runtime.h>
#include <hip/hip_fp8.h>
#include <math.h>

// ---------------------------------------------------------------------------
// GATClassifier on MI355X.
//   1. CSR build over dst (histogram -> 3-phase device-wide scan -> scatter)
//   2. Per layer: split-bf16 MFMA GEMM; layers 1/2 use an LDS-staged A-tile
//      shared by all 4 col-group waves (R10: R6's col-split grid re-streamed
//      A 4x from HBM -> FETCH 163MB, 89us, MfmaUtil 8.5%); h stored bf16-hi
//      + fp8-e4m3 copy; att dots from bf16; agg pass1: exp(leaky(e)) once
//      per (edge,head) -> bf16 ealpha + sums; pass2: fp8x4 row gather
//      weighted by ealpha; normalize in epilogue; split-bf16 out.
//   3. Fused mean-pool + 32->1 linear (batch sorted -> binary search)
// History: R2 atomic pool 383us. R3 fp32 SGEMM 158x2. R4 agg fp32-gather
// 155x2. R5 gemm latency 140x2. R6 agg 131x2 -> ealpha+vec gather. R7
// 1-block scan 111us -> 3-phase. R8 agg8 87x2 -> fp8 gather. R9 gemm
// A-over-fetch 89x2 -> R10 LDS-shared A.
// NOTE: edge_index / batch are int32.
// ---------------------------------------------------------------------------

typedef __attribute__((ext_vector_type(8))) __bf16 bf16x8;
typedef __attribute__((ext_vector_type(4))) __bf16 bf16x4;
typedef __attribute__((ext_vector_type(4))) float f32x4;

#define SCAN_CH 4  // elements per thread in the device-wide scan

__device__ inline unsigned char f32_to_fp8(float f) {
  __hip_fp8_e4m3 v(f);
  return (unsigned char)v.__x;
}
__device__ inline float fp8_to_f32(unsigned char u) {
  __hip_fp8_e4m3 v;
  v.__x = (__hip_fp8_storage_t)u;
  return (float)v;
}

// ---------------- CSR build ----------------
__global__ __launch_bounds__(256) void k_init_deg(int* deg, int N) {
  int n = blockIdx.x * 256 + threadIdx.x;
  if (n < N) deg[n] = 1;  // self-loop
}

__global__ __launch_bounds__(256) void k_count_deg(const int* __restrict__ ei,
                                                   int E, int* deg) {
  int e = blockIdx.x * 256 + threadIdx.x;
  if (e < E) atomicAdd(&deg[ei[E + e]], 1);
}

// --- 3-phase exclusive scan (R8: old single-block scan was 111us on 1 CU) ---
__global__ __launch_bounds__(256) void k_scan_partial(const int* __restrict__ deg,
                                                      int* __restrict__ blockSums,
                                                      int N) {
  __shared__ int sh[256];
  int t = threadIdx.x, b = blockIdx.x;
  int base = (b * 256 + t) * SCAN_CH;
  int s = 0;
#pragma unroll
  for (int j = 0; j < SCAN_CH; j++) {
    int idx = base + j;
    if (idx < N) s += deg[idx];
  }
  sh[t] = s;
  __syncthreads();
  for (int off = 128; off > 0; off >>= 1) {
    if (t < off) sh[t] += sh[t + off];
    __syncthreads();
  }
  if (t == 0) blockSums[b] = sh[0];
}

__global__ __launch_bounds__(256) void k_scan_blocksums(
    const int* __restrict__ blockSums, int* __restrict__ blockOffs,
    int* __restrict__ rowptr, int nb, int N) {
  __shared__ int sh[256];
  int t = threadIdx.x;
  int v = (t < nb) ? blockSums[t] : 0;
  sh[t] = v;
  __syncthreads();
  for (int off = 1; off < 256; off <<= 1) {
    int u = (t >= off) ? sh[t - off] : 0;
    __syncthreads();
    sh[t] += u;
    __syncthreads();
  }
  if (t < nb) blockOffs[t] = sh[t] - v;  // exclusive
  if (t == nb - 1) rowptr[N] = sh[t];    // total
}

__global__ __launch_bounds__(256) void k_scan_final(const int* __restrict__ deg,
                                                    const int* __restrict__ blockOffs,
                                                    int* __restrict__ rowptr,
                                                    int* __restrict__ cursor, int N) {
  __shared__ int sh[256];
  int t = threadIdx.x, b = blockIdx.x;
  int base = (b * 256 + t) * SCAN_CH;
  int vals[SCAN_CH];
  int s = 0;
#pragma unroll
  for (int j = 0; j < SCAN_CH; j++) {
    int idx = base + j;
    vals[j] = (idx < N) ? deg[idx] : 0;
    s += vals[j];
  }
  sh[t] = s;
  __syncthreads();
  for (int off = 1; off < 256; off <<= 1) {
    int u = (t >= off) ? sh[t - off] : 0;
    __syncthreads();
    sh[t] += u;
    __syncthreads();
  }
  int run = blockOffs[b] + sh[t] - s;  // exclusive prefix for this thread
#pragma unroll
  for (int j = 0; j < SCAN_CH; j++) {
    int idx = base + j;
    if (idx < N) {
      rowptr[idx] = run;
      cursor[idx] = run;
      run += vals[j];
    }
  }
}

__global__ __launch_bounds__(256) void k_scatter(const int* __restrict__ ei,
                                                 int E, int N, int* cursor,
                                                 int* __restrict__ colsrc) {
  int i = blockIdx.x * 256 + threadIdx.x;
  if (i < E) {
    int s = ei[i];
    int d = ei[E + i];
    int pos = atomicAdd(&cursor[d], 1);
    colsrc[pos] = s;
  } else if (i < E + N) {
    int nn = i - E;
    int pos = atomicAdd(&cursor[nn], 1);
    colsrc[pos] = nn;  // self loop
  }
}

// ---------------- split-cast preps ----------------
__global__ __launch_bounds__(256) void k_split(const float* __restrict__ in,
                                               __bf16* __restrict__ oh,
                                               __bf16* __restrict__ ol, int n4) {
  int i = blockIdx.x * 256 + threadIdx.x;
  if (i >= n4) return;
  float4 v = ((const float4*)in)[i];
  bf16x4 h, l;
  h[0] = (__bf16)v.x; l[0] = (__bf16)(v.x - (float)h[0]);
  h[1] = (__bf16)v.y; l[1] = (__bf16)(v.y - (float)h[1]);
  h[2] = (__bf16)v.z; l[2] = (__bf16)(v.z - (float)h[2]);
  h[3] = (__bf16)v.w; l[3] = (__bf16)(v.w - (float)h[3]);
  ((bf16x4*)oh)[i] = h;
  ((bf16x4*)ol)[i] = l;
}

// W [K][Nc] fp32 -> WT hi/lo [Nc][K] bf16 (transposed so B-frags load b128).
__global__ __launch_bounds__(256) void k_wprep(const float* __restrict__ W,
                                               __bf16* __restrict__ WTh,
                                               __bf16* __restrict__ WTl,
                                               int K, int Nc) {
  int i = blockIdx.x * 256 + threadIdx.x;  // i = n*K + k
  if (i >= K * Nc) return;
  int n = i / K, k = i - n * K;
  float w = W[k * Nc + n];
  __bf16 h = (__bf16)w;
  WTh[i] = h;
  WTl[i] = (__bf16)(w - (float)h);
}

// ---------------- LDS-shared split-bf16 MFMA GEMM (layers 1/2) ----------
// Block = 64 rows x 256 cols; per 32-k step the A-tile (64x32 hi+lo, 8KB)
// is cooperatively staged into LDS in MFMA-FRAGMENT ORDER (lane reads its
// b128 at consecutive 16B -> conflict-free), then each of the 4 waves
// computes its own 64-col group (MT=4 x NT=4 = 48 MFMAs per k-step).
// A is read from HBM exactly ONCE (R9: col-split grid re-streamed A 4x,
// FETCH 163MB). Numerics identical to k_gemm_split.
// mfma_f32_16x16x32_bf16 (m89-verified): A: m=lane&15,k=quad*8+j;
// B: n=lane&15,k=quad*8+j (from WT); C/D: row=quad*4+reg, col=lane&15.
__global__ __launch_bounds__(256) void k_gemm_lds(
    const __bf16* __restrict__ Ah, const __bf16* __restrict__ Al,
    const __bf16* __restrict__ BTh, const __bf16* __restrict__ BTl,
    __bf16* __restrict__ Ch, unsigned char* __restrict__ Cf8, int M, int K) {
  constexpr int NcFull = 256;
  __shared__ __bf16 sAh[2048];  // [mt*4+kq][l16][8k] fragment-order, 4KB
  __shared__ __bf16 sAl[2048];
  int tid = threadIdx.x;
  int lane = tid & 63, wave = tid >> 6;
  int quad = lane >> 4, l16 = lane & 15;
  int m0 = blockIdx.x * 64;
  int col0 = wave * 64;
  // staging map: thread t -> row sr = t>>2 (0..63), k-quad skq = t&3
  int sr = tid >> 2, skq = tid & 3;
  int sidx = (((sr >> 4) * 4 + skq) * 16 + (sr & 15)) * 8;
  int arow = min(m0 + sr, M - 1);  // clamp: rows >= M never stored
  const __bf16* agh = Ah + (size_t)arow * K + skq * 8;
  const __bf16* agl = Al + (size_t)arow * K + skq * 8;
  const __bf16* brh = BTh + (size_t)(col0 + l16) * K + quad * 8;
  const __bf16* brl = BTl + (size_t)(col0 + l16) * K + quad * 8;
  f32x4 acc[4][4];  // [mt][nt]
#pragma unroll
  for (int mt = 0; mt < 4; mt++)
#pragma unroll
    for (int t = 0; t < 4; t++) acc[mt][t] = (f32x4){0.f, 0.f, 0.f, 0.f};
  for (int k0 = 0; k0 < K; k0 += 32) {
    bf16x8 gh = *(const bf16x8*)(agh + k0);
    bf16x8 gl = *(const bf16x8*)(agl + k0);
    __syncthreads();  // previous iter's LDS reads done
    *(bf16x8*)(sAh + sidx) = gh;
    *(bf16x8*)(sAl + sidx) = gl;
    __syncthreads();  // staging visible
    bf16x8 b_h[4], b_l[4];
#pragma unroll
    for (int t = 0; t < 4; t++) {
      b_h[t] = *(const bf16x8*)(brh + (size_t)t * 16 * K + k0);
      b_l[t] = *(const bf16x8*)(brl + (size_t)t * 16 * K + k0);
    }
    bf16x8 a_h[4], a_l[4];
#pragma unroll
    for (int mt = 0; mt < 4; mt++) {
      int fi = ((mt * 4 + quad) * 16 + l16) * 8;
      a_h[mt] = *(const bf16x8*)(sAh + fi);
      a_l[mt] = *(const bf16x8*)(sAl + fi);
    }
#pragma unroll
    for (int t = 0; t < 4; t++) {
#pragma unroll
      for (int mt = 0; mt < 4; mt++) {
        acc[mt][t] = __builtin_amdgcn_mfma_f32_16x16x32_bf16(a_h[mt], b_h[t], acc[mt][t], 0, 0, 0);
        acc[mt][t] = __builtin_amdgcn_mfma_f32_16x16x32_bf16(a_h[mt], b_l[t], acc[mt][t], 0, 0, 0);
        acc[mt][t] = __builtin_amdgcn_mfma_f32_16x16x32_bf16(a_l[mt], b_h[t], acc[mt][t], 0, 0, 0);
      }
    }
  }
#pragma unroll
  for (int mt = 0; mt < 4; mt++) {
#pragma unroll
    for (int t = 0; t < 4; t++) {
#pragma unroll
      for (int r = 0; r < 4; r++) {
        int m = m0 + mt * 16 + quad * 4 + r;
        if (m < M) {
          size_t o = (size_t)m * NcFull + col0 + t * 16 + l16;
          Ch[o] = (__bf16)acc[mt][t][r];
          Cf8[o] = f32_to_fp8(acc[mt][t][r]);
        }
      }
    }
  }
}

// ---------------- split-bf16 MFMA GEMM, no-LDS (layer 3) ----------------
template <int NT, int MT>
__global__ __launch_bounds__(256) void k_gemm_split(
    const __bf16* __restrict__ Ah, const __bf16* __restrict__ Al,
    const __bf16* __restrict__ BTh, const __bf16* __restrict__ BTl,
    __bf16* __restrict__ Ch, int M, int K, int NcFull) {
  int lane = threadIdx.x & 63;
  int wave = threadIdx.x >> 6;
  int quad = lane >> 4;
  int l16 = lane & 15;
  int m0 = blockIdx.y * (64 * MT) + wave * (16 * MT);
  int col0 = blockIdx.x * (NT * 16);
  const __bf16* arh[MT];
  const __bf16* arl[MT];
#pragma unroll
  for (int mt = 0; mt < MT; mt++) {
    int am = min(m0 + mt * 16 + l16, M - 1);
    arh[mt] = Ah + (size_t)am * K + quad * 8;
    arl[mt] = Al + (size_t)am * K + quad * 8;
  }
  const __bf16* brh = BTh + (size_t)(col0 + l16) * K + quad * 8;
  const __bf16* brl = BTl + (size_t)(col0 + l16) * K + quad * 8;
  f32x4 acc[MT][NT];
#pragma unroll
  for (int mt = 0; mt < MT; mt++)
#pragma unroll
    for (int t = 0; t < NT; t++) acc[mt][t] = (f32x4){0.f, 0.f, 0.f, 0.f};
  for (int k0 = 0; k0 < K; k0 += 32) {
    bf16x8 a_h[MT], a_l[MT], b_h[NT], b_l[NT];
#pragma unroll
    for (int mt = 0; mt < MT; mt++) {
      a_h[mt] = *(const bf16x8*)(arh[mt] + k0);
      a_l[mt] = *(const bf16x8*)(arl[mt] + k0);
    }
#pragma unroll
    for (int t = 0; t < NT; t++) {
      b_h[t] = *(const bf16x8*)(brh + (size_t)t * 16 * K + k0);
      b_l[t] = *(const bf16x8*)(brl + (size_t)t * 16 * K + k0);
    }
#pragma unroll
    for (int t = 0; t < NT; t++) {
#pragma unroll
      for (int mt = 0; mt < MT; mt++) {
        acc[mt][t] = __builtin_amdgcn_mfma_f32_16x16x32_bf16(a_h[mt], b_h[t], acc[mt][t], 0, 0, 0);
        acc[mt][t] = __builtin_amdgcn_mfma_f32_16x16x32_bf16(a_h[mt], b_l[t], acc[mt][t], 0, 0, 0);
        acc[mt][t] = __builtin_amdgcn_mfma_f32_16x16x32_bf16(a_l[mt], b_h[t], acc[mt][t], 0, 0, 0);
      }
    }
  }
#pragma unroll
  for (int mt = 0; mt < MT; mt++) {
#pragma unroll
    for (int t = 0; t < NT; t++) {
#pragma unroll
      for (int r = 0; r < 4; r++) {
        int m = m0 + mt * 16 + quad * 4 + r;
        if (m < M)
          Ch[(size_t)m * NcFull + col0 + t * 16 + l16] = (__bf16)acc[mt][t][r];
      }
    }
  }
}

// ---------------- attention dots (bf16-hi) ----------------
__global__ __launch_bounds__(256) void k_att(const __bf16* __restrict__ Hh,
                                             const float* __restrict__ attS,
                                             const float* __restrict__ attD,
                                             float* __restrict__ aS,
                                             float* __restrict__ aD, int NH, int H) {
  int idx = blockIdx.x * 256 + threadIdx.x;
  if (idx >= NH) return;
  int h = idx % H;
  const bf16x8* hv = (const bf16x8*)(Hh + (size_t)idx * 32);
  const float* sv = attS + h * 32;
  const float* dv = attD + h * 32;
  float ss = 0.f, dd = 0.f;
#pragma unroll
  for (int k = 0; k < 4; k++) {
    bf16x8 a = hv[k];
#pragma unroll
    for (int j = 0; j < 8; j++) {
      float v = (float)a[j];
      ss += v * sv[k * 8 + j];
      dd += v * dv[k * 8 + j];
    }
  }
  aS[idx] = ss;
  aD[idx] = dd;
}

// ---------------- GAT aggregation, H=8 ----------------
// One wave per dst node. Pass 1: exp(leaky(e)) once per (edge,head) -> bf16
// ealpha + shuffle-reduced sums. Pass 2 (serial edges, unroll-2): lane = 4
// consecutive channels (head = lane>>3), one FP8x4 (4B) row load per edge;
// normalize in epilogue. ELU + split-bf16 out.
__global__ __launch_bounds__(256) void k_gat_agg8(
    const unsigned char* __restrict__ Hf8, const float* __restrict__ aS,
    const float* __restrict__ aD, const int* __restrict__ rowptr,
    const int* __restrict__ colsrc, const float* __restrict__ bias,
    __bf16* __restrict__ ealpha, __bf16* __restrict__ outh,
    __bf16* __restrict__ outl, int N) {
  int wid = (blockIdx.x * blockDim.x + threadIdx.x) >> 6;
  int lane = threadIdx.x & 63;
  if (wid >= N) return;
  int n = wid;
  int row0 = rowptr[n];
  int deg = rowptr[n + 1] - row0;

  float adn[8], s[8];
#pragma unroll
  for (int h = 0; h < 8; h++) {
    adn[h] = aD[(size_t)n * 8 + h];
    s[h] = 0.f;
  }
  for (int i = lane; i < deg; i += 64) {
    int slot = row0 + i;
    int src = colsrc[slot];
    const float* ap = aS + (size_t)src * 8;
    bf16x8 ev;
#pragma unroll
    for (int h = 0; h < 8; h++) {
      float e = ap[h] + adn[h];
      e = (e > 0.f) ? e : 0.2f * e;
      float x = __expf(e);
      s[h] += x;
      ev[h] = (__bf16)x;
    }
    *(bf16x8*)(ealpha + (size_t)slot * 8) = ev;
  }
#pragma unroll
  for (int h = 0; h < 8; h++) {
#pragma unroll
    for (int off = 32; off > 0; off >>= 1) s[h] += __shfl_xor(s[h], off, 64);
  }
  int head = lane >> 3;
  float r0 = (head & 4) ? s[4] : s[0];
  float r1 = (head & 4) ? s[5] : s[1];
  float r2 = (head & 4) ? s[6] : s[2];
  float r3 = (head & 4) ? s[7] : s[3];
  float u0 = (head & 2) ? r2 : r0;
  float u1 = (head & 2) ? r3 : r1;
  float rsv = 1.f / ((head & 1) ? u1 : u0);

  f32x4 acc = (f32x4){0.f, 0.f, 0.f, 0.f};
  const __bf16* ea = ealpha;
  int i = 0;
  for (; i + 1 < deg; i += 2) {
    int sl = row0 + i;
    int s0 = colsrc[sl];
    int s1 = colsrc[sl + 1];
    float w0 = (float)ea[(size_t)sl * 8 + head];
    float w1 = (float)ea[(size_t)(sl + 1) * 8 + head];
    uchar4 h0 = *(const uchar4*)(Hf8 + (size_t)s0 * 256 + lane * 4);
    uchar4 h1 = *(const uchar4*)(Hf8 + (size_t)s1 * 256 + lane * 4);
    acc[0] += w0 * fp8_to_f32(h0.x);
    acc[1] += w0 * fp8_to_f32(h0.y);
    acc[2] += w0 * fp8_to_f32(h0.z);
    acc[3] += w0 * fp8_to_f32(h0.w);
    acc[0] += w1 * fp8_to_f32(h1.x);
    acc[1] += w1 * fp8_to_f32(h1.y);
    acc[2] += w1 * fp8_to_f32(h1.z);
    acc[3] += w1 * fp8_to_f32(h1.w);
  }
  if (i < deg) {
    int sl = row0 + i;
    int s0 = colsrc[sl];
    float w0 = (float)ea[(size_t)sl * 8 + head];
    uchar4 h0 = *(const uchar4*)(Hf8 + (size_t)s0 * 256 + lane * 4);
    acc[0] += w0 * fp8_to_f32(h0.x);
    acc[1] += w0 * fp8_to_f32(h0.y);
    acc[2] += w0 * fp8_to_f32(h0.z);
    acc[3] += w0 * fp8_to_f32(h0.w);
  }
  float4 bv = *(const float4*)(bias + lane * 4);
  bf16x4 hb, lb;
#pragma unroll
  for (int j = 0; j < 4; j++) {
    float v = acc[j] * rsv + ((const float*)&bv)[j];
    v = (v > 0.f) ? v : (__expf(v) - 1.f);  // ELU
    hb[j] = (__bf16)v;
    lb[j] = (__bf16)(v - (float)hb[j]);
  }
  *(bf16x4*)(outh + (size_t)n * 256 + lane * 4) = hb;
  *(bf16x4*)(outl + (size_t)n * 256 + lane * 4) = lb;
}

// ---------------- GAT aggregation, H=1 (layer 3, fp32 out, no ELU) ------
__global__ __launch_bounds__(256) void k_gat_agg1(
    const __bf16* __restrict__ Hh, const float* __restrict__ aS,
    const float* __restrict__ aD, const int* __restrict__ rowptr,
    const int* __restrict__ colsrc, const float* __restrict__ bias,
    __bf16* __restrict__ ealpha, float* __restrict__ out, int N) {
  int wid = (blockIdx.x * blockDim.x + threadIdx.x) >> 6;
  int lane = threadIdx.x & 63;
  if (wid >= N) return;
  int n = wid;
  int row0 = rowptr[n];
  int deg = rowptr[n + 1] - row0;
  float adn = aD[n];
  float s = 0.f;
  for (int i = lane; i < deg; i += 64) {
    int slot = row0 + i;
    float e = aS[colsrc[slot]] + adn;
    e = (e > 0.f) ? e : 0.2f * e;
    float x = __expf(e);
    s += x;
    ealpha[slot] = (__bf16)x;
  }
#pragma unroll
  for (int off = 32; off > 0; off >>= 1) s += __shfl_xor(s, off, 64);
  float rsv = 1.f / s;

  int eo = lane >> 3;
  int cl = lane & 7;
  f32x4 acc = (f32x4){0.f, 0.f, 0.f, 0.f};
  for (int i = eo; i < deg; i += 8) {
    int slot = row0 + i;
    int src = colsrc[slot];
    float w = (float)ealpha[slot];
    bf16x4 hv = *(const bf16x4*)(Hh + (size_t)src * 32 + cl * 4);
#pragma unroll
    for (int j = 0; j < 4; j++) acc[j] += w * (float)hv[j];
  }
#pragma unroll
  for (int j = 0; j < 4; j++) {
#pragma unroll
    for (int off = 8; off < 64; off <<= 1) acc[j] += __shfl_xor(acc[j], off, 64);
  }
  if (eo == 0) {
#pragma unroll
    for (int j = 0; j < 4; j++)
      out[(size_t)n * 32 + cl * 4 + j] = acc[j] * rsv + bias[cl * 4 + j];
  }
}

// ---------------- fused mean-pool + linear ----------------
__global__ __launch_bounds__(256) void k_pool_final(
    const float* __restrict__ h, const int* __restrict__ batch,
    const float* __restrict__ linW, const float* __restrict__ linb,
    float* __restrict__ out, int N) {
  __shared__ float sh[256];
  int g = blockIdx.x;
  int tid = threadIdx.x;
  int grp = tid >> 5, c = tid & 31;
  int lo = 0, hi = N;
  while (lo < hi) { int mid = (lo + hi) >> 1; if (batch[mid] < g) lo = mid + 1; else hi = mid; }
  int start = lo;
  hi = N;
  while (lo < hi) { int mid = (lo + hi) >> 1; if (batch[mid] < g + 1) lo = mid + 1; else hi = mid; }
  int end = lo;
  float acc = 0.f;
  for (int n = start + grp; n < end; n += 8) acc += h[(size_t)n * 32 + c];
  sh[tid] = acc;
  __syncthreads();
  if (tid < 32) {
    float s = 0.f;
#pragma unroll
    for (int j = 0; j < 8; j++) s += sh[j * 32 + tid];
    float v = s * linW[tid];
#pragma unroll
    for (int off = 16; off > 0; off >>= 1) v += __shfl_xor(v, off, 64);
    if (tid == 0) {
      float cnt = (float)(end - start);
      out[g] = v / fmaxf(cnt, 1.f) + linb[0];
    }
  }
}

extern "C" void kernel_launch(void* const* d_in, const int* in_sizes, int n_in,
                              void* d_out, int out_size, void* d_ws, size_t ws_size,
                              hipStream_t stream) {
  const float* x = (const float*)d_in[0];
  const int* ei = (const int*)d_in[1];
  const int* batch = (const int*)d_in[2];
  const float* W1 = (const float*)d_in[3];
  const float* as1 = (const float*)d_in[4];
  const float* ad1 = (const float*)d_in[5];
  const float* b1 = (const float*)d_in[6];
  const float* W2 = (const float*)d_in[7];
  const float* as2 = (const float*)d_in[8];
  const float* ad2 = (const float*)d_in[9];
  const float* b2 = (const float*)d_in[10];
  const float* W3 = (const float*)d_in[11];
  const float* as3 = (const float*)d_in[12];
  const float* ad3 = (const float*)d_in[13];
  const float* b3 = (const float*)d_in[14];
  const float* linW = (const float*)d_in[15];
  const float* linb = (const float*)d_in[16];

  const int N = in_sizes[0] / 256;
  const int E = in_sizes[1] / 2;
  const int NUM_GRAPHS = 64;
  float* out = (float*)d_out;

  char* ws = (char*)d_ws;
  size_t off = 0;
  auto alloc = [&](size_t bytes) -> void* {
    void* p = ws + off;
    off += (bytes + 255) & ~(size_t)255;
    return p;
  };
  __bf16* Hh = (__bf16*)alloc((size_t)N * 256 * 2);  // GEMM h out (bf16-hi)
  unsigned char* Hf8 = (unsigned char*)alloc((size_t)N * 256);  // fp8 copy
  __bf16* Ah = (__bf16*)alloc((size_t)N * 256 * 2);  // GEMM A in (hi)
  __bf16* Al = (__bf16*)alloc((size_t)N * 256 * 2);  //           (lo)
  __bf16* ealpha = (__bf16*)alloc((size_t)(E + N) * 8 * 2);  // per-edge exps
  float* aS = (float*)alloc((size_t)N * 8 * 4);
  float* aD = (float*)alloc((size_t)N * 8 * 4);
  int* deg = (int*)alloc((size_t)N * 4);
  int* rowptr = (int*)alloc((size_t)(N + 1) * 4);
  int* cursor = (int*)alloc((size_t)(N + 1) * 4);
  int* colsrc = (int*)alloc((size_t)(E + N) * 4);
  int* blockSums = (int*)alloc(256 * 4);
  int* blockOffs = (int*)alloc(256 * 4);
  __bf16* WT1h = (__bf16*)alloc(256 * 256 * 2);
  __bf16* WT1l = (__bf16*)alloc(256 * 256 * 2);
  __bf16* WT2h = (__bf16*)alloc(256 * 256 * 2);
  __bf16* WT2l = (__bf16*)alloc(256 * 256 * 2);
  __bf16* WT3h = (__bf16*)alloc(32 * 256 * 2);
  __bf16* WT3l = (__bf16*)alloc(32 * 256 * 2);
  // h3agg reuses Ah (GEMM3 already consumed Ah/Al when agg3 writes)
  float* h3agg = (float*)Ah;

  // --- preps: x split + W transposes/splits + CSR build ---
  k_split<<<(N * 64 + 255) / 256, 256, 0, stream>>>(x, Ah, Al, N * 64);
  k_wprep<<<(256 * 256 + 255) / 256, 256, 0, stream>>>(W1, WT1h, WT1l, 256, 256);
  k_wprep<<<(256 * 256 + 255) / 256, 256, 0, stream>>>(W2, WT2h, WT2l, 256, 256);
  k_wprep<<<(256 * 32 + 255) / 256, 256, 0, stream>>>(W3, WT3h, WT3l, 256, 32);
  k_init_deg<<<(N + 255) / 256, 256, 0, stream>>>(deg, N);
  k_count_deg<<<(E + 255) / 256, 256, 0, stream>>>(ei, E, deg);
  const int nb = (N + 256 * SCAN_CH - 1) / (256 * SCAN_CH);  // 49 <= 256
  k_scan_partial<<<nb, 256, 0, stream>>>(deg, blockSums, N);
  k_scan_blocksums<<<1, 256, 0, stream>>>(blockSums, blockOffs, rowptr, nb, N);
  k_scan_final<<<nb, 256, 0, stream>>>(deg, blockOffs, rowptr, cursor, N);
  k_scatter<<<(E + N + 255) / 256, 256, 0, stream>>>(ei, E, N, cursor, colsrc);

  const int aggBlocks = (N + 3) / 4;
  const int gemmBlocks = (N + 63) / 64;  // 64 rows/block, full 256-col width
  dim3 g3(1, (N + 63) / 64);

  // --- layer 1 ---
  k_gemm_lds<<<gemmBlocks, 256, 0, stream>>>(Ah, Al, WT1h, WT1l, Hh, Hf8, N, 256);
  k_att<<<(N * 8 + 255) / 256, 256, 0, stream>>>(Hh, as1, ad1, aS, aD, N * 8, 8);
  k_gat_agg8<<<aggBlocks, 256, 0, stream>>>(Hf8, aS, aD, rowptr, colsrc, b1,
                                            ealpha, Ah, Al, N);
  // --- layer 2 ---
  k_gemm_lds<<<gemmBlocks, 256, 0, stream>>>(Ah, Al, WT2h, WT2l, Hh, Hf8, N, 256);
  k_att<<<(N * 8 + 255) / 256, 256, 0, stream>>>(Hh, as2, ad2, aS, aD, N * 8, 8);
  k_gat_agg8<<<aggBlocks, 256, 0, stream>>>(Hf8, aS, aD, rowptr, colsrc, b2,
                                            ealpha, Ah, Al, N);
  // --- layer 3 (H=1, bf16 gather, no-LDS GEMM: single col-group already) ---
  k_gemm_split<2, 1><<<g3, 256, 0, stream>>>(Ah, Al, WT3h, WT3l, Hh, N, 256, 32);
  k_att<<<(N + 255) / 256, 256, 0, stream>>>(Hh, as3, ad3, aS, aD, N, 1);
  k_gat_agg1<<<aggBlocks, 256, 0, stream>>>(Hh, aS, aD, rowptr, colsrc, b3,
                                            ealpha, h3agg, N);
  // --- pool + final ---
  k_pool_final<<<NUM_GRAPHS, 256, 0, stream>>>(h3agg, batch, linW, linb, out, N);
}

// Round 11
// 583.579 us; speedup vs baseline: 2.4300x; 1.0480x over previous
//
#include <hip/hip_runtime.h>
#include <hip/hip_fp8.h>
#include <math.h>

// ---------------------------------------------------------------------------
// GATClassifier on MI355X.
//   1. CSR build over dst (histogram -> 3-phase device-wide scan -> scatter)
//   2. Per layer: split-bf16 MFMA GEMM; layers 1/2 use an LDS-staged A-tile
//      shared by all 4 col-group waves (A read from HBM once); h stored
//      bf16-hi + fp8-e4m3 copy; att dots from bf16; agg pass1: exp(leaky(e))
//      once per (edge,head) -> bf16 ealpha + sums; pass2: fp8x4 row gather,
//      unroll-4 + packed v_cvt_pk_f32_fp8 decode (R11: R10 showed agg8
//      MLP/VALU-bound — 2.4TB/s, 55% VALU, 21 inst/edge); normalize in
//      epilogue; split-bf16 out.
//   3. Fused mean-pool + 32->1 linear (batch sorted -> binary search)
// History: R2 atomic pool 383us. R3 fp32 SGEMM 158x2. R4 agg fp32-gather
// 155x2. R5 gemm latency 140x2. R6 agg 131x2. R7 1-block scan 111us. R8
// agg8 87x2 -> fp8 gather. R9 gemm A-over-fetch 89x2 -> LDS-shared A.
// R10 agg8 80x2 -> R11 unroll-4 + pk-cvt.
// NOTE: edge_index / batch are int32.
// ---------------------------------------------------------------------------

typedef __attribute__((ext_vector_type(8))) __bf16 bf16x8;
typedef __attribute__((ext_vector_type(4))) __bf16 bf16x4;
typedef __attribute__((ext_vector_type(4))) float f32x4;
typedef __attribute__((ext_vector_type(2))) float f32x2;

#define SCAN_CH 4  // elements per thread in the device-wide scan

__device__ inline unsigned char f32_to_fp8(float f) {
  __hip_fp8_e4m3 v(f);
  return (unsigned char)v.__x;
}
__device__ inline float fp8_to_f32(unsigned char u) {
  __hip_fp8_e4m3 v;
  v.__x = (__hip_fp8_storage_t)u;
  return (float)v;
}

// Decode 4 packed fp8-e4m3 bytes -> 4 floats, accumulate w * val into acc.
__device__ inline void fma_fp8x4(f32x4& acc, float w, unsigned int packed) {
#if defined(__has_builtin) && __has_builtin(__builtin_amdgcn_cvt_pk_f32_fp8)
  f32x2 lo = __builtin_amdgcn_cvt_pk_f32_fp8((int)packed, false);  // bytes 0,1
  f32x2 hi = __builtin_amdgcn_cvt_pk_f32_fp8((int)packed, true);   // bytes 2,3
  acc[0] += w * lo[0];
  acc[1] += w * lo[1];
  acc[2] += w * hi[0];
  acc[3] += w * hi[1];
#else
  acc[0] += w * fp8_to_f32((unsigned char)(packed & 0xff));
  acc[1] += w * fp8_to_f32((unsigned char)((packed >> 8) & 0xff));
  acc[2] += w * fp8_to_f32((unsigned char)((packed >> 16) & 0xff));
  acc[3] += w * fp8_to_f32((unsigned char)(packed >> 24));
#endif
}

// ---------------- CSR build ----------------
__global__ __launch_bounds__(256) void k_init_deg(int* deg, int N) {
  int n = blockIdx.x * 256 + threadIdx.x;
  if (n < N) deg[n] = 1;  // self-loop
}

__global__ __launch_bounds__(256) void k_count_deg(const int* __restrict__ ei,
                                                   int E, int* deg) {
  int e = blockIdx.x * 256 + threadIdx.x;
  if (e < E) atomicAdd(&deg[ei[E + e]], 1);
}

// --- 3-phase exclusive scan (R8: old single-block scan was 111us on 1 CU) ---
__global__ __launch_bounds__(256) void k_scan_partial(const int* __restrict__ deg,
                                                      int* __restrict__ blockSums,
                                                      int N) {
  __shared__ int sh[256];
  int t = threadIdx.x, b = blockIdx.x;
  int base = (b * 256 + t) * SCAN_CH;
  int s = 0;
#pragma unroll
  for (int j = 0; j < SCAN_CH; j++) {
    int idx = base + j;
    if (idx < N) s += deg[idx];
  }
  sh[t] = s;
  __syncthreads();
  for (int off = 128; off > 0; off >>= 1) {
    if (t < off) sh[t] += sh[t + off];
    __syncthreads();
  }
  if (t == 0) blockSums[b] = sh[0];
}

__global__ __launch_bounds__(256) void k_scan_blocksums(
    const int* __restrict__ blockSums, int* __restrict__ blockOffs,
    int* __restrict__ rowptr, int nb, int N) {
  __shared__ int sh[256];
  int t = threadIdx.x;
  int v = (t < nb) ? blockSums[t] : 0;
  sh[t] = v;
  __syncthreads();
  for (int off = 1; off < 256; off <<= 1) {
    int u = (t >= off) ? sh[t - off] : 0;
    __syncthreads();
    sh[t] += u;
    __syncthreads();
  }
  if (t < nb) blockOffs[t] = sh[t] - v;  // exclusive
  if (t == nb - 1) rowptr[N] = sh[t];    // total
}

__global__ __launch_bounds__(256) void k_scan_final(const int* __restrict__ deg,
                                                    const int* __restrict__ blockOffs,
                                                    int* __restrict__ rowptr,
                                                    int* __restrict__ cursor, int N) {
  __shared__ int sh[256];
  int t = threadIdx.x, b = blockIdx.x;
  int base = (b * 256 + t) * SCAN_CH;
  int vals[SCAN_CH];
  int s = 0;
#pragma unroll
  for (int j = 0; j < SCAN_CH; j++) {
    int idx = base + j;
    vals[j] = (idx < N) ? deg[idx] : 0;
    s += vals[j];
  }
  sh[t] = s;
  __syncthreads();
  for (int off = 1; off < 256; off <<= 1) {
    int u = (t >= off) ? sh[t - off] : 0;
    __syncthreads();
    sh[t] += u;
    __syncthreads();
  }
  int run = blockOffs[b] + sh[t] - s;  // exclusive prefix for this thread
#pragma unroll
  for (int j = 0; j < SCAN_CH; j++) {
    int idx = base + j;
    if (idx < N) {
      rowptr[idx] = run;
      cursor[idx] = run;
      run += vals[j];
    }
  }
}

__global__ __launch_bounds__(256) void k_scatter(const int* __restrict__ ei,
                                                 int E, int N, int* cursor,
                                                 int* __restrict__ colsrc) {
  int i = blockIdx.x * 256 + threadIdx.x;
  if (i < E) {
    int s = ei[i];
    int d = ei[E + i];
    int pos = atomicAdd(&cursor[d], 1);
    colsrc[pos] = s;
  } else if (i < E + N) {
    int nn = i - E;
    int pos = atomicAdd(&cursor[nn], 1);
    colsrc[pos] = nn;  // self loop
  }
}

// ---------------- split-cast preps ----------------
__global__ __launch_bounds__(256) void k_split(const float* __restrict__ in,
                                               __bf16* __restrict__ oh,
                                               __bf16* __restrict__ ol, int n4) {
  int i = blockIdx.x * 256 + threadIdx.x;
  if (i >= n4) return;
  float4 v = ((const float4*)in)[i];
  bf16x4 h, l;
  h[0] = (__bf16)v.x; l[0] = (__bf16)(v.x - (float)h[0]);
  h[1] = (__bf16)v.y; l[1] = (__bf16)(v.y - (float)h[1]);
  h[2] = (__bf16)v.z; l[2] = (__bf16)(v.z - (float)h[2]);
  h[3] = (__bf16)v.w; l[3] = (__bf16)(v.w - (float)h[3]);
  ((bf16x4*)oh)[i] = h;
  ((bf16x4*)ol)[i] = l;
}

// W [K][Nc] fp32 -> WT hi/lo [Nc][K] bf16 (transposed so B-frags load b128).
__global__ __launch_bounds__(256) void k_wprep(const float* __restrict__ W,
                                               __bf16* __restrict__ WTh,
                                               __bf16* __restrict__ WTl,
                                               int K, int Nc) {
  int i = blockIdx.x * 256 + threadIdx.x;  // i = n*K + k
  if (i >= K * Nc) return;
  int n = i / K, k = i - n * K;
  float w = W[k * Nc + n];
  __bf16 h = (__bf16)w;
  WTh[i] = h;
  WTl[i] = (__bf16)(w - (float)h);
}

// ---------------- LDS-shared split-bf16 MFMA GEMM (layers 1/2) ----------
// Block = 64 rows x 256 cols; per 32-k step the A-tile (64x32 hi+lo, 8KB)
// is cooperatively staged into LDS in MFMA-fragment order; each of the 4
// waves computes its own 64-col group. A read from HBM exactly once.
// mfma_f32_16x16x32_bf16 (m89-verified): A: m=lane&15,k=quad*8+j;
// B: n=lane&15,k=quad*8+j (from WT); C/D: row=quad*4+reg, col=lane&15.
__global__ __launch_bounds__(256) void k_gemm_lds(
    const __bf16* __restrict__ Ah, const __bf16* __restrict__ Al,
    const __bf16* __restrict__ BTh, const __bf16* __restrict__ BTl,
    __bf16* __restrict__ Ch, unsigned char* __restrict__ Cf8, int M, int K) {
  constexpr int NcFull = 256;
  __shared__ __bf16 sAh[2048];  // [mt*4+kq][l16][8k] fragment-order, 4KB
  __shared__ __bf16 sAl[2048];
  int tid = threadIdx.x;
  int lane = tid & 63, wave = tid >> 6;
  int quad = lane >> 4, l16 = lane & 15;
  int m0 = blockIdx.x * 64;
  int col0 = wave * 64;
  int sr = tid >> 2, skq = tid & 3;
  int sidx = (((sr >> 4) * 4 + skq) * 16 + (sr & 15)) * 8;
  int arow = min(m0 + sr, M - 1);  // clamp: rows >= M never stored
  const __bf16* agh = Ah + (size_t)arow * K + skq * 8;
  const __bf16* agl = Al + (size_t)arow * K + skq * 8;
  const __bf16* brh = BTh + (size_t)(col0 + l16) * K + quad * 8;
  const __bf16* brl = BTl + (size_t)(col0 + l16) * K + quad * 8;
  f32x4 acc[4][4];  // [mt][nt]
#pragma unroll
  for (int mt = 0; mt < 4; mt++)
#pragma unroll
    for (int t = 0; t < 4; t++) acc[mt][t] = (f32x4){0.f, 0.f, 0.f, 0.f};
  for (int k0 = 0; k0 < K; k0 += 32) {
    bf16x8 gh = *(const bf16x8*)(agh + k0);
    bf16x8 gl = *(const bf16x8*)(agl + k0);
    __syncthreads();  // previous iter's LDS reads done
    *(bf16x8*)(sAh + sidx) = gh;
    *(bf16x8*)(sAl + sidx) = gl;
    __syncthreads();  // staging visible
    bf16x8 b_h[4], b_l[4];
#pragma unroll
    for (int t = 0; t < 4; t++) {
      b_h[t] = *(const bf16x8*)(brh + (size_t)t * 16 * K + k0);
      b_l[t] = *(const bf16x8*)(brl + (size_t)t * 16 * K + k0);
    }
    bf16x8 a_h[4], a_l[4];
#pragma unroll
    for (int mt = 0; mt < 4; mt++) {
      int fi = ((mt * 4 + quad) * 16 + l16) * 8;
      a_h[mt] = *(const bf16x8*)(sAh + fi);
      a_l[mt] = *(const bf16x8*)(sAl + fi);
    }
#pragma unroll
    for (int t = 0; t < 4; t++) {
#pragma unroll
      for (int mt = 0; mt < 4; mt++) {
        acc[mt][t] = __builtin_amdgcn_mfma_f32_16x16x32_bf16(a_h[mt], b_h[t], acc[mt][t], 0, 0, 0);
        acc[mt][t] = __builtin_amdgcn_mfma_f32_16x16x32_bf16(a_h[mt], b_l[t], acc[mt][t], 0, 0, 0);
        acc[mt][t] = __builtin_amdgcn_mfma_f32_16x16x32_bf16(a_l[mt], b_h[t], acc[mt][t], 0, 0, 0);
      }
    }
  }
#pragma unroll
  for (int mt = 0; mt < 4; mt++) {
#pragma unroll
    for (int t = 0; t < 4; t++) {
#pragma unroll
      for (int r = 0; r < 4; r++) {
        int m = m0 + mt * 16 + quad * 4 + r;
        if (m < M) {
          size_t o = (size_t)m * NcFull + col0 + t * 16 + l16;
          Ch[o] = (__bf16)acc[mt][t][r];
          Cf8[o] = f32_to_fp8(acc[mt][t][r]);
        }
      }
    }
  }
}

// ---------------- split-bf16 MFMA GEMM, no-LDS (layer 3) ----------------
template <int NT, int MT>
__global__ __launch_bounds__(256) void k_gemm_split(
    const __bf16* __restrict__ Ah, const __bf16* __restrict__ Al,
    const __bf16* __restrict__ BTh, const __bf16* __restrict__ BTl,
    __bf16* __restrict__ Ch, int M, int K, int NcFull) {
  int lane = threadIdx.x & 63;
  int wave = threadIdx.x >> 6;
  int quad = lane >> 4;
  int l16 = lane & 15;
  int m0 = blockIdx.y * (64 * MT) + wave * (16 * MT);
  int col0 = blockIdx.x * (NT * 16);
  const __bf16* arh[MT];
  const __bf16* arl[MT];
#pragma unroll
  for (int mt = 0; mt < MT; mt++) {
    int am = min(m0 + mt * 16 + l16, M - 1);
    arh[mt] = Ah + (size_t)am * K + quad * 8;
    arl[mt] = Al + (size_t)am * K + quad * 8;
  }
  const __bf16* brh = BTh + (size_t)(col0 + l16) * K + quad * 8;
  const __bf16* brl = BTl + (size_t)(col0 + l16) * K + quad * 8;
  f32x4 acc[MT][NT];
#pragma unroll
  for (int mt = 0; mt < MT; mt++)
#pragma unroll
    for (int t = 0; t < NT; t++) acc[mt][t] = (f32x4){0.f, 0.f, 0.f, 0.f};
  for (int k0 = 0; k0 < K; k0 += 32) {
    bf16x8 a_h[MT], a_l[MT], b_h[NT], b_l[NT];
#pragma unroll
    for (int mt = 0; mt < MT; mt++) {
      a_h[mt] = *(const bf16x8*)(arh[mt] + k0);
      a_l[mt] = *(const bf16x8*)(arl[mt] + k0);
    }
#pragma unroll
    for (int t = 0; t < NT; t++) {
      b_h[t] = *(const bf16x8*)(brh + (size_t)t * 16 * K + k0);
      b_l[t] = *(const bf16x8*)(brl + (size_t)t * 16 * K + k0);
    }
#pragma unroll
    for (int t = 0; t < NT; t++) {
#pragma unroll
      for (int mt = 0; mt < MT; mt++) {
        acc[mt][t] = __builtin_amdgcn_mfma_f32_16x16x32_bf16(a_h[mt], b_h[t], acc[mt][t], 0, 0, 0);
        acc[mt][t] = __builtin_amdgcn_mfma_f32_16x16x32_bf16(a_h[mt], b_l[t], acc[mt][t], 0, 0, 0);
        acc[mt][t] = __builtin_amdgcn_mfma_f32_16x16x32_bf16(a_l[mt], b_h[t], acc[mt][t], 0, 0, 0);
      }
    }
  }
#pragma unroll
  for (int mt = 0; mt < MT; mt++) {
#pragma unroll
    for (int t = 0; t < NT; t++) {
#pragma unroll
      for (int r = 0; r < 4; r++) {
        int m = m0 + mt * 16 + quad * 4 + r;
        if (m < M)
          Ch[(size_t)m * NcFull + col0 + t * 16 + l16] = (__bf16)acc[mt][t][r];
      }
    }
  }
}

// ---------------- attention dots (bf16-hi) ----------------
__global__ __launch_bounds__(256) void k_att(const __bf16* __restrict__ Hh,
                                             const float* __restrict__ attS,
                                             const float* __restrict__ attD,
                                             float* __restrict__ aS,
                                             float* __restrict__ aD, int NH, int H) {
  int idx = blockIdx.x * 256 + threadIdx.x;
  if (idx >= NH) return;
  int h = idx % H;
  const bf16x8* hv = (const bf16x8*)(Hh + (size_t)idx * 32);
  const float* sv = attS + h * 32;
  const float* dv = attD + h * 32;
  float ss = 0.f, dd = 0.f;
#pragma unroll
  for (int k = 0; k < 4; k++) {
    bf16x8 a = hv[k];
#pragma unroll
    for (int j = 0; j < 8; j++) {
      float v = (float)a[j];
      ss += v * sv[k * 8 + j];
      dd += v * dv[k * 8 + j];
    }
  }
  aS[idx] = ss;
  aD[idx] = dd;
}

// ---------------- GAT aggregation, H=8 ----------------
// One wave per dst node. Pass 1: exp(leaky(e)) once per (edge,head) -> bf16
// ealpha + shuffle-reduced sums. Pass 2: UNROLL-4 serial edge loop — 4
// wave-uniform colsrc scalar loads + 4 weight loads + 4 fp8x4 row loads
// batched ahead of the FMAs (4 rows in flight), packed v_cvt_pk_f32_fp8
// decode (R11). Normalize in epilogue. ELU + split-bf16 out.
__global__ __launch_bounds__(256) void k_gat_agg8(
    const unsigned char* __restrict__ Hf8, const float* __restrict__ aS,
    const float* __restrict__ aD, const int* __restrict__ rowptr,
    const int* __restrict__ colsrc, const float* __restrict__ bias,
    __bf16* __restrict__ ealpha, __bf16* __restrict__ outh,
    __bf16* __restrict__ outl, int N) {
  int wid = (blockIdx.x * blockDim.x + threadIdx.x) >> 6;
  int lane = threadIdx.x & 63;
  if (wid >= N) return;
  int n = wid;
  int row0 = rowptr[n];
  int deg = rowptr[n + 1] - row0;

  float adn[8], s[8];
#pragma unroll
  for (int h = 0; h < 8; h++) {
    adn[h] = aD[(size_t)n * 8 + h];
    s[h] = 0.f;
  }
  for (int i = lane; i < deg; i += 64) {
    int slot = row0 + i;
    int src = colsrc[slot];
    const float* ap = aS + (size_t)src * 8;
    bf16x8 ev;
#pragma unroll
    for (int h = 0; h < 8; h++) {
      float e = ap[h] + adn[h];
      e = (e > 0.f) ? e : 0.2f * e;
      float x = __expf(e);
      s[h] += x;
      ev[h] = (__bf16)x;
    }
    *(bf16x8*)(ealpha + (size_t)slot * 8) = ev;
  }
#pragma unroll
  for (int h = 0; h < 8; h++) {
#pragma unroll
    for (int off = 32; off > 0; off >>= 1) s[h] += __shfl_xor(s[h], off, 64);
  }
  int head = lane >> 3;
  float r0 = (head & 4) ? s[4] : s[0];
  float r1 = (head & 4) ? s[5] : s[1];
  float r2 = (head & 4) ? s[6] : s[2];
  float r3 = (head & 4) ? s[7] : s[3];
  float u0 = (head & 2) ? r2 : r0;
  float u1 = (head & 2) ? r3 : r1;
  float rsv = 1.f / ((head & 1) ? u1 : u0);

  // pass 2: unroll-4, loads batched before FMAs (4 rows in flight)
  f32x4 acc = (f32x4){0.f, 0.f, 0.f, 0.f};
  const __bf16* ea = ealpha;
  int i = 0;
  for (; i + 3 < deg; i += 4) {
    int sl = row0 + i;
    int s0 = colsrc[sl + 0];
    int s1 = colsrc[sl + 1];
    int s2 = colsrc[sl + 2];
    int s3 = colsrc[sl + 3];
    float w0 = (float)ea[(size_t)(sl + 0) * 8 + head];
    float w1 = (float)ea[(size_t)(sl + 1) * 8 + head];
    float w2 = (float)ea[(size_t)(sl + 2) * 8 + head];
    float w3 = (float)ea[(size_t)(sl + 3) * 8 + head];
    unsigned int p0 = *(const unsigned int*)(Hf8 + (size_t)s0 * 256 + lane * 4);
    unsigned int p1 = *(const unsigned int*)(Hf8 + (size_t)s1 * 256 + lane * 4);
    unsigned int p2 = *(const unsigned int*)(Hf8 + (size_t)s2 * 256 + lane * 4);
    unsigned int p3 = *(const unsigned int*)(Hf8 + (size_t)s3 * 256 + lane * 4);
    fma_fp8x4(acc, w0, p0);
    fma_fp8x4(acc, w1, p1);
    fma_fp8x4(acc, w2, p2);
    fma_fp8x4(acc, w3, p3);
  }
  for (; i < deg; i++) {
    int sl = row0 + i;
    int s0 = colsrc[sl];
    float w0 = (float)ea[(size_t)sl * 8 + head];
    unsigned int p0 = *(const unsigned int*)(Hf8 + (size_t)s0 * 256 + lane * 4);
    fma_fp8x4(acc, w0, p0);
  }
  float4 bv = *(const float4*)(bias + lane * 4);
  bf16x4 hb, lb;
#pragma unroll
  for (int j = 0; j < 4; j++) {
    float v = acc[j] * rsv + ((const float*)&bv)[j];
    v = (v > 0.f) ? v : (__expf(v) - 1.f);  // ELU
    hb[j] = (__bf16)v;
    lb[j] = (__bf16)(v - (float)hb[j]);
  }
  *(bf16x4*)(outh + (size_t)n * 256 + lane * 4) = hb;
  *(bf16x4*)(outl + (size_t)n * 256 + lane * 4) = lb;
}

// ---------------- GAT aggregation, H=1 (layer 3, fp32 out, no ELU) ------
__global__ __launch_bounds__(256) void k_gat_agg1(
    const __bf16* __restrict__ Hh, const float* __restrict__ aS,
    const float* __restrict__ aD, const int* __restrict__ rowptr,
    const int* __restrict__ colsrc, const float* __restrict__ bias,
    __bf16* __restrict__ ealpha, float* __restrict__ out, int N) {
  int wid = (blockIdx.x * blockDim.x + threadIdx.x) >> 6;
  int lane = threadIdx.x & 63;
  if (wid >= N) return;
  int n = wid;
  int row0 = rowptr[n];
  int deg = rowptr[n + 1] - row0;
  float adn = aD[n];
  float s = 0.f;
  for (int i = lane; i < deg; i += 64) {
    int slot = row0 + i;
    float e = aS[colsrc[slot]] + adn;
    e = (e > 0.f) ? e : 0.2f * e;
    float x = __expf(e);
    s += x;
    ealpha[slot] = (__bf16)x;
  }
#pragma unroll
  for (int off = 32; off > 0; off >>= 1) s += __shfl_xor(s, off, 64);
  float rsv = 1.f / s;

  int eo = lane >> 3;
  int cl = lane & 7;
  f32x4 acc = (f32x4){0.f, 0.f, 0.f, 0.f};
  for (int i = eo; i < deg; i += 8) {
    int slot = row0 + i;
    int src = colsrc[slot];
    float w = (float)ealpha[slot];
    bf16x4 hv = *(const bf16x4*)(Hh + (size_t)src * 32 + cl * 4);
#pragma unroll
    for (int j = 0; j < 4; j++) acc[j] += w * (float)hv[j];
  }
#pragma unroll
  for (int j = 0; j < 4; j++) {
#pragma unroll
    for (int off = 8; off < 64; off <<= 1) acc[j] += __shfl_xor(acc[j], off, 64);
  }
  if (eo == 0) {
#pragma unroll
    for (int j = 0; j < 4; j++)
      out[(size_t)n * 32 + cl * 4 + j] = acc[j] * rsv + bias[cl * 4 + j];
  }
}

// ---------------- fused mean-pool + linear ----------------
__global__ __launch_bounds__(256) void k_pool_final(
    const float* __restrict__ h, const int* __restrict__ batch,
    const float* __restrict__ linW, const float* __restrict__ linb,
    float* __restrict__ out, int N) {
  __shared__ float sh[256];
  int g = blockIdx.x;
  int tid = threadIdx.x;
  int grp = tid >> 5, c = tid & 31;
  int lo = 0, hi = N;
  while (lo < hi) { int mid = (lo + hi) >> 1; if (batch[mid] < g) lo = mid + 1; else hi = mid; }
  int start = lo;
  hi = N;
  while (lo < hi) { int mid = (lo + hi) >> 1; if (batch[mid] < g + 1) lo = mid + 1; else hi = mid; }
  int end = lo;
  float acc = 0.f;
  for (int n = start + grp; n < end; n += 8) acc += h[(size_t)n * 32 + c];
  sh[tid] = acc;
  __syncthreads();
  if (tid < 32) {
    float s = 0.f;
#pragma unroll
    for (int j = 0; j < 8; j++) s += sh[j * 32 + tid];
    float v = s * linW[tid];
#pragma unroll
    for (int off = 16; off > 0; off >>= 1) v += __shfl_xor(v, off, 64);
    if (tid == 0) {
      float cnt = (float)(end - start);
      out[g] = v / fmaxf(cnt, 1.f) + linb[0];
    }
  }
}

extern "C" void kernel_launch(void* const* d_in, const int* in_sizes, int n_in,
                              void* d_out, int out_size, void* d_ws, size_t ws_size,
                              hipStream_t stream) {
  const float* x = (const float*)d_in[0];
  const int* ei = (const int*)d_in[1];
  const int* batch = (const int*)d_in[2];
  const float* W1 = (const float*)d_in[3];
  const float* as1 = (const float*)d_in[4];
  const float* ad1 = (const float*)d_in[5];
  const float* b1 = (const float*)d_in[6];
  const float* W2 = (const float*)d_in[7];
  const float* as2 = (const float*)d_in[8];
  const float* ad2 = (const float*)d_in[9];
  const float* b2 = (const float*)d_in[10];
  const float* W3 = (const float*)d_in[11];
  const float* as3 = (const float*)d_in[12];
  const float* ad3 = (const float*)d_in[13];
  const float* b3 = (const float*)d_in[14];
  const float* linW = (const float*)d_in[15];
  const float* linb = (const float*)d_in[16];

  const int N = in_sizes[0] / 256;
  const int E = in_sizes[1] / 2;
  const int NUM_GRAPHS = 64;
  float* out = (float*)d_out;

  char* ws = (char*)d_ws;
  size_t off = 0;
  auto alloc = [&](size_t bytes) -> void* {
    void* p = ws + off;
    off += (bytes + 255) & ~(size_t)255;
    return p;
  };
  __bf16* Hh = (__bf16*)alloc((size_t)N * 256 * 2);  // GEMM h out (bf16-hi)
  unsigned char* Hf8 = (unsigned char*)alloc((size_t)N * 256);  // fp8 copy
  __bf16* Ah = (__bf16*)alloc((size_t)N * 256 * 2);  // GEMM A in (hi)
  __bf16* Al = (__bf16*)alloc((size_t)N * 256 * 2);  //           (lo)
  __bf16* ealpha = (__bf16*)alloc((size_t)(E + N) * 8 * 2);  // per-edge exps
  float* aS = (float*)alloc((size_t)N * 8 * 4);
  float* aD = (float*)alloc((size_t)N * 8 * 4);
  int* deg = (int*)alloc((size_t)N * 4);
  int* rowptr = (int*)alloc((size_t)(N + 1) * 4);
  int* cursor = (int*)alloc((size_t)(N + 1) * 4);
  int* colsrc = (int*)alloc((size_t)(E + N) * 4);
  int* blockSums = (int*)alloc(256 * 4);
  int* blockOffs = (int*)alloc(256 * 4);
  __bf16* WT1h = (__bf16*)alloc(256 * 256 * 2);
  __bf16* WT1l = (__bf16*)alloc(256 * 256 * 2);
  __bf16* WT2h = (__bf16*)alloc(256 * 256 * 2);
  __bf16* WT2l = (__bf16*)alloc(256 * 256 * 2);
  __bf16* WT3h = (__bf16*)alloc(32 * 256 * 2);
  __bf16* WT3l = (__bf16*)alloc(32 * 256 * 2);
  // h3agg reuses Ah (GEMM3 already consumed Ah/Al when agg3 writes)
  float* h3agg = (float*)Ah;

  // --- preps: x split + W transposes/splits + CSR build ---
  k_split<<<(N * 64 + 255) / 256, 256, 0, stream>>>(x, Ah, Al, N * 64);
  k_wprep<<<(256 * 256 + 255) / 256, 256, 0, stream>>>(W1, WT1h, WT1l, 256, 256);
  k_wprep<<<(256 * 256 + 255) / 256, 256, 0, stream>>>(W2, WT2h, WT2l, 256, 256);
  k_wprep<<<(256 * 32 + 255) / 256, 256, 0, stream>>>(W3, WT3h, WT3l, 256, 32);
  k_init_deg<<<(N + 255) / 256, 256, 0, stream>>>(deg, N);
  k_count_deg<<<(E + 255) / 256, 256, 0, stream>>>(ei, E, deg);
  const int nb = (N + 256 * SCAN_CH - 1) / (256 * SCAN_CH);  // 49 <= 256
  k_scan_partial<<<nb, 256, 0, stream>>>(deg, blockSums, N);
  k_scan_blocksums<<<1, 256, 0, stream>>>(blockSums, blockOffs, rowptr, nb, N);
  k_scan_final<<<nb, 256, 0, stream>>>(deg, blockOffs, rowptr, cursor, N);
  k_scatter<<<(E + N + 255) / 256, 256, 0, stream>>>(ei, E, N, cursor, colsrc);

  const int aggBlocks = (N + 3) / 4;
  const int gemmBlocks = (N + 63) / 64;  // 64 rows/block, full 256-col width
  dim3 g3(1, (N + 63) / 64);

  // --- layer 1 ---
  k_gemm_lds<<<gemmBlocks, 256, 0, stream>>>(Ah, Al, WT1h, WT1l, Hh, Hf8, N, 256);
  k_att<<<(N * 8 + 255) / 256, 256, 0, stream>>>(Hh, as1, ad1, aS, aD, N * 8, 8);
  k_gat_agg8<<<aggBlocks, 256, 0, stream>>>(Hf8, aS, aD, rowptr, colsrc, b1,
                                            ealpha, Ah, Al, N);
  // --- layer 2 ---
  k_gemm_lds<<<gemmBlocks, 256, 0, stream>>>(Ah, Al, WT2h, WT2l, Hh, Hf8, N, 256);
  k_att<<<(N * 8 + 255) / 256, 256, 0, stream>>>(Hh, as2, ad2, aS, aD, N * 8, 8);
  k_gat_agg8<<<aggBlocks, 256, 0, stream>>>(Hf8, aS, aD, rowptr, colsrc, b2,
                                            ealpha, Ah, Al, N);
  // --- layer 3 (H=1, bf16 gather, no-LDS GEMM: single col-group already) ---
  k_gemm_split<2, 1><<<g3, 256, 0, stream>>>(Ah, Al, WT3h, WT3l, Hh, N, 256, 32);
  k_att<<<(N + 255) / 256, 256, 0, stream>>>(Hh, as3, ad3, aS, aD, N, 1);
  k_gat_agg1<<<aggBlocks, 256, 0, stream>>>(Hh, aS, aD, rowptr, colsrc, b3,
                                            ealpha, h3agg, N);
  // --- pool + final ---
  k_pool_final<<<NUM_GRAPHS, 256, 0, stream>>>(h3agg, batch, linW, linb, out, N);
}

// Round 12
// 560.801 us; speedup vs baseline: 2.5287x; 1.0406x over previous
//
#include <hip/hip_runtime.h>
#include <hip/hip_fp8.h>
#include <math.h>

// ---------------------------------------------------------------------------
// GATClassifier on MI355X.
//   1. CSR build over dst (histogram -> 3-phase scan -> scatter, storing
//      colsrc AND coldst per slot)
//   2. Per layer: split-bf16 MFMA GEMM (LDS-shared A-tile, read-once);
//      h stored bf16-hi + fp8-e4m3 copy; att dots from bf16;
//      k_edge_alpha: DENSE edge-parallel exp(leaky(aS[src]+aD[dst])) -> bf16
//      ealpha (R12: node-wave pass1 had 17/64 lanes active + 48-shuffle
//      reduce tree — VALUBusy 52% at 71us); agg = single serial-edge gather
//      accumulating acc += w*row AND den += w per lane (every lane sees all
//      edges -> full sum in-register, no shuffles), normalize by 1/den.
//   3. Fused mean-pool + 32->1 linear (batch sorted -> binary search)
// History: R2 pool 383. R3 SGEMM 158x2. R4 agg 155x2. R5 gemm 140x2. R6 agg
// 131x2. R7 scan 111. R8 agg 87x2->fp8. R9 gemm 89x2->LDS-A. R10 agg 80x2
// ->unroll4+pkcvt. R11 agg 71x2 (VALU: idle-lane pass1 + shuffle tree) ->
// R12 dense edge-alpha + shuffle-free den.
// NOTE: edge_index / batch are int32.
// ---------------------------------------------------------------------------

typedef __attribute__((ext_vector_type(8))) __bf16 bf16x8;
typedef __attribute__((ext_vector_type(4))) __bf16 bf16x4;
typedef __attribute__((ext_vector_type(4))) float f32x4;
typedef __attribute__((ext_vector_type(2))) float f32x2;

#define SCAN_CH 4  // elements per thread in the device-wide scan

__device__ inline unsigned char f32_to_fp8(float f) {
  __hip_fp8_e4m3 v(f);
  return (unsigned char)v.__x;
}
__device__ inline float fp8_to_f32(unsigned char u) {
  __hip_fp8_e4m3 v;
  v.__x = (__hip_fp8_storage_t)u;
  return (float)v;
}

// Decode 4 packed fp8-e4m3 bytes -> 4 floats, accumulate w * val into acc.
__device__ inline void fma_fp8x4(f32x4& acc, float w, unsigned int packed) {
#if defined(__has_builtin) && __has_builtin(__builtin_amdgcn_cvt_pk_f32_fp8)
  f32x2 lo = __builtin_amdgcn_cvt_pk_f32_fp8((int)packed, false);  // bytes 0,1
  f32x2 hi = __builtin_amdgcn_cvt_pk_f32_fp8((int)packed, true);   // bytes 2,3
  acc[0] += w * lo[0];
  acc[1] += w * lo[1];
  acc[2] += w * hi[0];
  acc[3] += w * hi[1];
#else
  acc[0] += w * fp8_to_f32((unsigned char)(packed & 0xff));
  acc[1] += w * fp8_to_f32((unsigned char)((packed >> 8) & 0xff));
  acc[2] += w * fp8_to_f32((unsigned char)((packed >> 16) & 0xff));
  acc[3] += w * fp8_to_f32((unsigned char)(packed >> 24));
#endif
}

// ---------------- CSR build ----------------
__global__ __launch_bounds__(256) void k_init_deg(int* deg, int N) {
  int n = blockIdx.x * 256 + threadIdx.x;
  if (n < N) deg[n] = 1;  // self-loop
}

__global__ __launch_bounds__(256) void k_count_deg(const int* __restrict__ ei,
                                                   int E, int* deg) {
  int e = blockIdx.x * 256 + threadIdx.x;
  if (e < E) atomicAdd(&deg[ei[E + e]], 1);
}

// --- 3-phase exclusive scan (R8: old single-block scan was 111us on 1 CU) ---
__global__ __launch_bounds__(256) void k_scan_partial(const int* __restrict__ deg,
                                                      int* __restrict__ blockSums,
                                                      int N) {
  __shared__ int sh[256];
  int t = threadIdx.x, b = blockIdx.x;
  int base = (b * 256 + t) * SCAN_CH;
  int s = 0;
#pragma unroll
  for (int j = 0; j < SCAN_CH; j++) {
    int idx = base + j;
    if (idx < N) s += deg[idx];
  }
  sh[t] = s;
  __syncthreads();
  for (int off = 128; off > 0; off >>= 1) {
    if (t < off) sh[t] += sh[t + off];
    __syncthreads();
  }
  if (t == 0) blockSums[b] = sh[0];
}

__global__ __launch_bounds__(256) void k_scan_blocksums(
    const int* __restrict__ blockSums, int* __restrict__ blockOffs,
    int* __restrict__ rowptr, int nb, int N) {
  __shared__ int sh[256];
  int t = threadIdx.x;
  int v = (t < nb) ? blockSums[t] : 0;
  sh[t] = v;
  __syncthreads();
  for (int off = 1; off < 256; off <<= 1) {
    int u = (t >= off) ? sh[t - off] : 0;
    __syncthreads();
    sh[t] += u;
    __syncthreads();
  }
  if (t < nb) blockOffs[t] = sh[t] - v;  // exclusive
  if (t == nb - 1) rowptr[N] = sh[t];    // total
}

__global__ __launch_bounds__(256) void k_scan_final(const int* __restrict__ deg,
                                                    const int* __restrict__ blockOffs,
                                                    int* __restrict__ rowptr,
                                                    int* __restrict__ cursor, int N) {
  __shared__ int sh[256];
  int t = threadIdx.x, b = blockIdx.x;
  int base = (b * 256 + t) * SCAN_CH;
  int vals[SCAN_CH];
  int s = 0;
#pragma unroll
  for (int j = 0; j < SCAN_CH; j++) {
    int idx = base + j;
    vals[j] = (idx < N) ? deg[idx] : 0;
    s += vals[j];
  }
  sh[t] = s;
  __syncthreads();
  for (int off = 1; off < 256; off <<= 1) {
    int u = (t >= off) ? sh[t - off] : 0;
    __syncthreads();
    sh[t] += u;
    __syncthreads();
  }
  int run = blockOffs[b] + sh[t] - s;  // exclusive prefix for this thread
#pragma unroll
  for (int j = 0; j < SCAN_CH; j++) {
    int idx = base + j;
    if (idx < N) {
      rowptr[idx] = run;
      cursor[idx] = run;
      run += vals[j];
    }
  }
}

__global__ __launch_bounds__(256) void k_scatter(const int* __restrict__ ei,
                                                 int E, int N, int* cursor,
                                                 int* __restrict__ colsrc,
                                                 int* __restrict__ coldst) {
  int i = blockIdx.x * 256 + threadIdx.x;
  if (i < E) {
    int s = ei[i];
    int d = ei[E + i];
    int pos = atomicAdd(&cursor[d], 1);
    colsrc[pos] = s;
    coldst[pos] = d;
  } else if (i < E + N) {
    int nn = i - E;
    int pos = atomicAdd(&cursor[nn], 1);
    colsrc[pos] = nn;  // self loop
    coldst[pos] = nn;
  }
}

// ---------------- split-cast preps ----------------
__global__ __launch_bounds__(256) void k_split(const float* __restrict__ in,
                                               __bf16* __restrict__ oh,
                                               __bf16* __restrict__ ol, int n4) {
  int i = blockIdx.x * 256 + threadIdx.x;
  if (i >= n4) return;
  float4 v = ((const float4*)in)[i];
  bf16x4 h, l;
  h[0] = (__bf16)v.x; l[0] = (__bf16)(v.x - (float)h[0]);
  h[1] = (__bf16)v.y; l[1] = (__bf16)(v.y - (float)h[1]);
  h[2] = (__bf16)v.z; l[2] = (__bf16)(v.z - (float)h[2]);
  h[3] = (__bf16)v.w; l[3] = (__bf16)(v.w - (float)h[3]);
  ((bf16x4*)oh)[i] = h;
  ((bf16x4*)ol)[i] = l;
}

// W [K][Nc] fp32 -> WT hi/lo [Nc][K] bf16 (transposed so B-frags load b128).
__global__ __launch_bounds__(256) void k_wprep(const float* __restrict__ W,
                                               __bf16* __restrict__ WTh,
                                               __bf16* __restrict__ WTl,
                                               int K, int Nc) {
  int i = blockIdx.x * 256 + threadIdx.x;  // i = n*K + k
  if (i >= K * Nc) return;
  int n = i / K, k = i - n * K;
  float w = W[k * Nc + n];
  __bf16 h = (__bf16)w;
  WTh[i] = h;
  WTl[i] = (__bf16)(w - (float)h);
}

// ---------------- LDS-shared split-bf16 MFMA GEMM (layers 1/2) ----------
// Block = 64 rows x 256 cols; per 32-k step the A-tile (64x32 hi+lo, 8KB)
// is cooperatively staged into LDS in MFMA-fragment order; each of the 4
// waves computes its own 64-col group. A read from HBM exactly once.
// mfma_f32_16x16x32_bf16 (m89-verified): A: m=lane&15,k=quad*8+j;
// B: n=lane&15,k=quad*8+j (from WT); C/D: row=quad*4+reg, col=lane&15.
__global__ __launch_bounds__(256) void k_gemm_lds(
    const __bf16* __restrict__ Ah, const __bf16* __restrict__ Al,
    const __bf16* __restrict__ BTh, const __bf16* __restrict__ BTl,
    __bf16* __restrict__ Ch, unsigned char* __restrict__ Cf8, int M, int K) {
  constexpr int NcFull = 256;
  __shared__ __bf16 sAh[2048];  // [mt*4+kq][l16][8k] fragment-order, 4KB
  __shared__ __bf16 sAl[2048];
  int tid = threadIdx.x;
  int lane = tid & 63, wave = tid >> 6;
  int quad = lane >> 4, l16 = lane & 15;
  int m0 = blockIdx.x * 64;
  int col0 = wave * 64;
  int sr = tid >> 2, skq = tid & 3;
  int sidx = (((sr >> 4) * 4 + skq) * 16 + (sr & 15)) * 8;
  int arow = min(m0 + sr, M - 1);  // clamp: rows >= M never stored
  const __bf16* agh = Ah + (size_t)arow * K + skq * 8;
  const __bf16* agl = Al + (size_t)arow * K + skq * 8;
  const __bf16* brh = BTh + (size_t)(col0 + l16) * K + quad * 8;
  const __bf16* brl = BTl + (size_t)(col0 + l16) * K + quad * 8;
  f32x4 acc[4][4];  // [mt][nt]
#pragma unroll
  for (int mt = 0; mt < 4; mt++)
#pragma unroll
    for (int t = 0; t < 4; t++) acc[mt][t] = (f32x4){0.f, 0.f, 0.f, 0.f};
  for (int k0 = 0; k0 < K; k0 += 32) {
    bf16x8 gh = *(const bf16x8*)(agh + k0);
    bf16x8 gl = *(const bf16x8*)(agl + k0);
    __syncthreads();  // previous iter's LDS reads done
    *(bf16x8*)(sAh + sidx) = gh;
    *(bf16x8*)(sAl + sidx) = gl;
    __syncthreads();  // staging visible
    bf16x8 b_h[4], b_l[4];
#pragma unroll
    for (int t = 0; t < 4; t++) {
      b_h[t] = *(const bf16x8*)(brh + (size_t)t * 16 * K + k0);
      b_l[t] = *(const bf16x8*)(brl + (size_t)t * 16 * K + k0);
    }
    bf16x8 a_h[4], a_l[4];
#pragma unroll
    for (int mt = 0; mt < 4; mt++) {
      int fi = ((mt * 4 + quad) * 16 + l16) * 8;
      a_h[mt] = *(const bf16x8*)(sAh + fi);
      a_l[mt] = *(const bf16x8*)(sAl + fi);
    }
#pragma unroll
    for (int t = 0; t < 4; t++) {
#pragma unroll
      for (int mt = 0; mt < 4; mt++) {
        acc[mt][t] = __builtin_amdgcn_mfma_f32_16x16x32_bf16(a_h[mt], b_h[t], acc[mt][t], 0, 0, 0);
        acc[mt][t] = __builtin_amdgcn_mfma_f32_16x16x32_bf16(a_h[mt], b_l[t], acc[mt][t], 0, 0, 0);
        acc[mt][t] = __builtin_amdgcn_mfma_f32_16x16x32_bf16(a_l[mt], b_h[t], acc[mt][t], 0, 0, 0);
      }
    }
  }
#pragma unroll
  for (int mt = 0; mt < 4; mt++) {
#pragma unroll
    for (int t = 0; t < 4; t++) {
#pragma unroll
      for (int r = 0; r < 4; r++) {
        int m = m0 + mt * 16 + quad * 4 + r;
        if (m < M) {
          size_t o = (size_t)m * NcFull + col0 + t * 16 + l16;
          Ch[o] = (__bf16)acc[mt][t][r];
          Cf8[o] = f32_to_fp8(acc[mt][t][r]);
        }
      }
    }
  }
}

// ---------------- split-bf16 MFMA GEMM, no-LDS (layer 3) ----------------
template <int NT, int MT>
__global__ __launch_bounds__(256) void k_gemm_split(
    const __bf16* __restrict__ Ah, const __bf16* __restrict__ Al,
    const __bf16* __restrict__ BTh, const __bf16* __restrict__ BTl,
    __bf16* __restrict__ Ch, int M, int K, int NcFull) {
  int lane = threadIdx.x & 63;
  int wave = threadIdx.x >> 6;
  int quad = lane >> 4;
  int l16 = lane & 15;
  int m0 = blockIdx.y * (64 * MT) + wave * (16 * MT);
  int col0 = blockIdx.x * (NT * 16);
  const __bf16* arh[MT];
  const __bf16* arl[MT];
#pragma unroll
  for (int mt = 0; mt < MT; mt++) {
    int am = min(m0 + mt * 16 + l16, M - 1);
    arh[mt] = Ah + (size_t)am * K + quad * 8;
    arl[mt] = Al + (size_t)am * K + quad * 8;
  }
  const __bf16* brh = BTh + (size_t)(col0 + l16) * K + quad * 8;
  const __bf16* brl = BTl + (size_t)(col0 + l16) * K + quad * 8;
  f32x4 acc[MT][NT];
#pragma unroll
  for (int mt = 0; mt < MT; mt++)
#pragma unroll
    for (int t = 0; t < NT; t++) acc[mt][t] = (f32x4){0.f, 0.f, 0.f, 0.f};
  for (int k0 = 0; k0 < K; k0 += 32) {
    bf16x8 a_h[MT], a_l[MT], b_h[NT], b_l[NT];
#pragma unroll
    for (int mt = 0; mt < MT; mt++) {
      a_h[mt] = *(const bf16x8*)(arh[mt] + k0);
      a_l[mt] = *(const bf16x8*)(arl[mt] + k0);
    }
#pragma unroll
    for (int t = 0; t < NT; t++) {
      b_h[t] = *(const bf16x8*)(brh + (size_t)t * 16 * K + k0);
      b_l[t] = *(const bf16x8*)(brl + (size_t)t * 16 * K + k0);
    }
#pragma unroll
    for (int t = 0; t < NT; t++) {
#pragma unroll
      for (int mt = 0; mt < MT; mt++) {
        acc[mt][t] = __builtin_amdgcn_mfma_f32_16x16x32_bf16(a_h[mt], b_h[t], acc[mt][t], 0, 0, 0);
        acc[mt][t] = __builtin_amdgcn_mfma_f32_16x16x32_bf16(a_h[mt], b_l[t], acc[mt][t], 0, 0, 0);
        acc[mt][t] = __builtin_amdgcn_mfma_f32_16x16x32_bf16(a_l[mt], b_h[t], acc[mt][t], 0, 0, 0);
      }
    }
  }
#pragma unroll
  for (int mt = 0; mt < MT; mt++) {
#pragma unroll
    for (int t = 0; t < NT; t++) {
#pragma unroll
      for (int r = 0; r < 4; r++) {
        int m = m0 + mt * 16 + quad * 4 + r;
        if (m < M)
          Ch[(size_t)m * NcFull + col0 + t * 16 + l16] = (__bf16)acc[mt][t][r];
      }
    }
  }
}

// ---------------- attention dots (bf16-hi) ----------------
__global__ __launch_bounds__(256) void k_att(const __bf16* __restrict__ Hh,
                                             const float* __restrict__ attS,
                                             const float* __restrict__ attD,
                                             float* __restrict__ aS,
                                             float* __restrict__ aD, int NH, int H) {
  int idx = blockIdx.x * 256 + threadIdx.x;
  if (idx >= NH) return;
  int h = idx % H;
  const bf16x8* hv = (const bf16x8*)(Hh + (size_t)idx * 32);
  const float* sv = attS + h * 32;
  const float* dv = attD + h * 32;
  float ss = 0.f, dd = 0.f;
#pragma unroll
  for (int k = 0; k < 4; k++) {
    bf16x8 a = hv[k];
#pragma unroll
    for (int j = 0; j < 8; j++) {
      float v = (float)a[j];
      ss += v * sv[k * 8 + j];
      dd += v * dv[k * 8 + j];
    }
  }
  aS[idx] = ss;
  aD[idx] = dd;
}

// ---------------- dense edge-parallel alpha (R12) ----------------
// One thread per CSR slot: w = exp(leaky(aS[src,h] + aD[dst,h])) -> bf16.
// aS is a 1.6MB L2-hot table; coldst is sorted -> aD reads are L1-hot.
__global__ __launch_bounds__(256) void k_edge_alpha8(
    const float* __restrict__ aS, const float* __restrict__ aD,
    const int* __restrict__ colsrc, const int* __restrict__ coldst,
    __bf16* __restrict__ ealpha, int M) {
  int e = blockIdx.x * 256 + threadIdx.x;
  if (e >= M) return;
  int src = colsrc[e];
  int dst = coldst[e];
  const float* ap = aS + (size_t)src * 8;
  const float* dp = aD + (size_t)dst * 8;
  bf16x8 ev;
#pragma unroll
  for (int h = 0; h < 8; h++) {
    float x = ap[h] + dp[h];
    x = (x > 0.f) ? x : 0.2f * x;
    ev[h] = (__bf16)__expf(x);
  }
  *(bf16x8*)(ealpha + (size_t)e * 8) = ev;
}

__global__ __launch_bounds__(256) void k_edge_alpha1(
    const float* __restrict__ aS, const float* __restrict__ aD,
    const int* __restrict__ colsrc, const int* __restrict__ coldst,
    __bf16* __restrict__ ealpha, int M) {
  int e = blockIdx.x * 256 + threadIdx.x;
  if (e >= M) return;
  float x = aS[colsrc[e]] + aD[coldst[e]];
  x = (x > 0.f) ? x : 0.2f * x;
  ealpha[e] = (__bf16)__expf(x);
}

// ---------------- GAT aggregation, H=8 (gather-only, R12) ----------------
// One wave per dst node. Single serial-edge loop (unroll-4, 4 rows in
// flight): every lane walks all edges, accumulating acc += w*row AND
// den += w — the full normalizer lands in every lane's registers, so no
// shuffle reduction and no separate softmax pass. lane = 4 consecutive
// channels (head = lane>>3). Normalize by 1/den; ELU; split-bf16 out.
__global__ __launch_bounds__(256) void k_gat_agg8(
    const unsigned char* __restrict__ Hf8, const int* __restrict__ rowptr,
    const int* __restrict__ colsrc, const __bf16* __restrict__ ealpha,
    const float* __restrict__ bias, __bf16* __restrict__ outh,
    __bf16* __restrict__ outl, int N) {
  int wid = (blockIdx.x * blockDim.x + threadIdx.x) >> 6;
  int lane = threadIdx.x & 63;
  if (wid >= N) return;
  int n = wid;
  int row0 = rowptr[n];
  int deg = rowptr[n + 1] - row0;
  int head = lane >> 3;

  f32x4 acc = (f32x4){0.f, 0.f, 0.f, 0.f};
  float den = 0.f;
  const __bf16* ea = ealpha;
  int i = 0;
  for (; i + 3 < deg; i += 4) {
    int sl = row0 + i;
    int s0 = colsrc[sl + 0];
    int s1 = colsrc[sl + 1];
    int s2 = colsrc[sl + 2];
    int s3 = colsrc[sl + 3];
    float w0 = (float)ea[(size_t)(sl + 0) * 8 + head];
    float w1 = (float)ea[(size_t)(sl + 1) * 8 + head];
    float w2 = (float)ea[(size_t)(sl + 2) * 8 + head];
    float w3 = (float)ea[(size_t)(sl + 3) * 8 + head];
    unsigned int p0 = *(const unsigned int*)(Hf8 + (size_t)s0 * 256 + lane * 4);
    unsigned int p1 = *(const unsigned int*)(Hf8 + (size_t)s1 * 256 + lane * 4);
    unsigned int p2 = *(const unsigned int*)(Hf8 + (size_t)s2 * 256 + lane * 4);
    unsigned int p3 = *(const unsigned int*)(Hf8 + (size_t)s3 * 256 + lane * 4);
    den += w0 + w1 + w2 + w3;
    fma_fp8x4(acc, w0, p0);
    fma_fp8x4(acc, w1, p1);
    fma_fp8x4(acc, w2, p2);
    fma_fp8x4(acc, w3, p3);
  }
  for (; i < deg; i++) {
    int sl = row0 + i;
    int s0 = colsrc[sl];
    float w0 = (float)ea[(size_t)sl * 8 + head];
    unsigned int p0 = *(const unsigned int*)(Hf8 + (size_t)s0 * 256 + lane * 4);
    den += w0;
    fma_fp8x4(acc, w0, p0);
  }
  float rsv = 1.f / den;  // deg >= 1 (self-loop), den > 0
  float4 bv = *(const float4*)(bias + lane * 4);
  bf16x4 hb, lb;
#pragma unroll
  for (int j = 0; j < 4; j++) {
    float v = acc[j] * rsv + ((const float*)&bv)[j];
    v = (v > 0.f) ? v : (__expf(v) - 1.f);  // ELU
    hb[j] = (__bf16)v;
    lb[j] = (__bf16)(v - (float)hb[j]);
  }
  *(bf16x4*)(outh + (size_t)n * 256 + lane * 4) = hb;
  *(bf16x4*)(outl + (size_t)n * 256 + lane * 4) = lb;
}

// ---------------- GAT aggregation, H=1 (layer 3, fp32 out, no ELU) ------
// 8 edge-groups x 8 channel-pairs; den accumulated per group, then both acc
// and den cross-group shuffle-reduced (small: 3 levels).
__global__ __launch_bounds__(256) void k_gat_agg1(
    const __bf16* __restrict__ Hh, const int* __restrict__ rowptr,
    const int* __restrict__ colsrc, const __bf16* __restrict__ ealpha,
    const float* __restrict__ bias, float* __restrict__ out, int N) {
  int wid = (blockIdx.x * blockDim.x + threadIdx.x) >> 6;
  int lane = threadIdx.x & 63;
  if (wid >= N) return;
  int n = wid;
  int row0 = rowptr[n];
  int deg = rowptr[n + 1] - row0;
  int eo = lane >> 3;
  int cl = lane & 7;
  f32x4 acc = (f32x4){0.f, 0.f, 0.f, 0.f};
  float den = 0.f;
  for (int i = eo; i < deg; i += 8) {
    int slot = row0 + i;
    int src = colsrc[slot];
    float w = (float)ealpha[slot];
    den += w;
    bf16x4 hv = *(const bf16x4*)(Hh + (size_t)src * 32 + cl * 4);
#pragma unroll
    for (int j = 0; j < 4; j++) acc[j] += w * (float)hv[j];
  }
#pragma unroll
  for (int off = 8; off < 64; off <<= 1) {
#pragma unroll
    for (int j = 0; j < 4; j++) acc[j] += __shfl_xor(acc[j], off, 64);
    den += __shfl_xor(den, off, 64);
  }
  if (eo == 0) {
    float rsv = 1.f / den;
#pragma unroll
    for (int j = 0; j < 4; j++)
      out[(size_t)n * 32 + cl * 4 + j] = acc[j] * rsv + bias[cl * 4 + j];
  }
}

// ---------------- fused mean-pool + linear ----------------
__global__ __launch_bounds__(256) void k_pool_final(
    const float* __restrict__ h, const int* __restrict__ batch,
    const float* __restrict__ linW, const float* __restrict__ linb,
    float* __restrict__ out, int N) {
  __shared__ float sh[256];
  int g = blockIdx.x;
  int tid = threadIdx.x;
  int grp = tid >> 5, c = tid & 31;
  int lo = 0, hi = N;
  while (lo < hi) { int mid = (lo + hi) >> 1; if (batch[mid] < g) lo = mid + 1; else hi = mid; }
  int start = lo;
  hi = N;
  while (lo < hi) { int mid = (lo + hi) >> 1; if (batch[mid] < g + 1) lo = mid + 1; else hi = mid; }
  int end = lo;
  float acc = 0.f;
  for (int n = start + grp; n < end; n += 8) acc += h[(size_t)n * 32 + c];
  sh[tid] = acc;
  __syncthreads();
  if (tid < 32) {
    float s = 0.f;
#pragma unroll
    for (int j = 0; j < 8; j++) s += sh[j * 32 + tid];
    float v = s * linW[tid];
#pragma unroll
    for (int off = 16; off > 0; off >>= 1) v += __shfl_xor(v, off, 64);
    if (tid == 0) {
      float cnt = (float)(end - start);
      out[g] = v / fmaxf(cnt, 1.f) + linb[0];
    }
  }
}

extern "C" void kernel_launch(void* const* d_in, const int* in_sizes, int n_in,
                              void* d_out, int out_size, void* d_ws, size_t ws_size,
                              hipStream_t stream) {
  const float* x = (const float*)d_in[0];
  const int* ei = (const int*)d_in[1];
  const int* batch = (const int*)d_in[2];
  const float* W1 = (const float*)d_in[3];
  const float* as1 = (const float*)d_in[4];
  const float* ad1 = (const float*)d_in[5];
  const float* b1 = (const float*)d_in[6];
  const float* W2 = (const float*)d_in[7];
  const float* as2 = (const float*)d_in[8];
  const float* ad2 = (const float*)d_in[9];
  const float* b2 = (const float*)d_in[10];
  const float* W3 = (const float*)d_in[11];
  const float* as3 = (const float*)d_in[12];
  const float* ad3 = (const float*)d_in[13];
  const float* b3 = (const float*)d_in[14];
  const float* linW = (const float*)d_in[15];
  const float* linb = (const float*)d_in[16];

  const int N = in_sizes[0] / 256;
  const int E = in_sizes[1] / 2;
  const int NUM_GRAPHS = 64;
  float* out = (float*)d_out;

  char* ws = (char*)d_ws;
  size_t off = 0;
  auto alloc = [&](size_t bytes) -> void* {
    void* p = ws + off;
    off += (bytes + 255) & ~(size_t)255;
    return p;
  };
  __bf16* Hh = (__bf16*)alloc((size_t)N * 256 * 2);  // GEMM h out (bf16-hi)
  unsigned char* Hf8 = (unsigned char*)alloc((size_t)N * 256);  // fp8 copy
  __bf16* Ah = (__bf16*)alloc((size_t)N * 256 * 2);  // GEMM A in (hi)
  __bf16* Al = (__bf16*)alloc((size_t)N * 256 * 2);  //           (lo)
  __bf16* ealpha = (__bf16*)alloc((size_t)(E + N) * 8 * 2);  // per-edge exps
  float* aS = (float*)alloc((size_t)N * 8 * 4);
  float* aD = (float*)alloc((size_t)N * 8 * 4);
  int* deg = (int*)alloc((size_t)N * 4);
  int* rowptr = (int*)alloc((size_t)(N + 1) * 4);
  int* cursor = (int*)alloc((size_t)(N + 1) * 4);
  int* colsrc = (int*)alloc((size_t)(E + N) * 4);
  int* coldst = (int*)alloc((size_t)(E + N) * 4);
  int* blockSums = (int*)alloc(256 * 4);
  int* blockOffs = (int*)alloc(256 * 4);
  __bf16* WT1h = (__bf16*)alloc(256 * 256 * 2);
  __bf16* WT1l = (__bf16*)alloc(256 * 256 * 2);
  __bf16* WT2h = (__bf16*)alloc(256 * 256 * 2);
  __bf16* WT2l = (__bf16*)alloc(256 * 256 * 2);
  __bf16* WT3h = (__bf16*)alloc(32 * 256 * 2);
  __bf16* WT3l = (__bf16*)alloc(32 * 256 * 2);
  // h3agg reuses Ah (GEMM3 already consumed Ah/Al when agg3 writes)
  float* h3agg = (float*)Ah;

  // --- preps: x split + W transposes/splits + CSR build ---
  k_split<<<(N * 64 + 255) / 256, 256, 0, stream>>>(x, Ah, Al, N * 64);
  k_wprep<<<(256 * 256 + 255) / 256, 256, 0, stream>>>(W1, WT1h, WT1l, 256, 256);
  k_wprep<<<(256 * 256 + 255) / 256, 256, 0, stream>>>(W2, WT2h, WT2l, 256, 256);
  k_wprep<<<(256 * 32 + 255) / 256, 256, 0, stream>>>(W3, WT3h, WT3l, 256, 32);
  k_init_deg<<<(N + 255) / 256, 256, 0, stream>>>(deg, N);
  k_count_deg<<<(E + 255) / 256, 256, 0, stream>>>(ei, E, deg);
  const int nb = (N + 256 * SCAN_CH - 1) / (256 * SCAN_CH);  // 49 <= 256
  k_scan_partial<<<nb, 256, 0, stream>>>(deg, blockSums, N);
  k_scan_blocksums<<<1, 256, 0, stream>>>(blockSums, blockOffs, rowptr, nb, N);
  k_scan_final<<<nb, 256, 0, stream>>>(deg, blockOffs, rowptr, cursor, N);
  k_scatter<<<(E + N + 255) / 256, 256, 0, stream>>>(ei, E, N, cursor, colsrc, coldst);

  const int aggBlocks = (N + 3) / 4;
  const int gemmBlocks = (N + 63) / 64;  // 64 rows/block, full 256-col width
  const int M = E + N;
  const int edgeBlocks = (M + 255) / 256;
  dim3 g3(1, (N + 63) / 64);

  // --- layer 1 ---
  k_gemm_lds<<<gemmBlocks, 256, 0, stream>>>(Ah, Al, WT1h, WT1l, Hh, Hf8, N, 256);
  k_att<<<(N * 8 + 255) / 256, 256, 0, stream>>>(Hh, as1, ad1, aS, aD, N * 8, 8);
  k_edge_alpha8<<<edgeBlocks, 256, 0, stream>>>(aS, aD, colsrc, coldst, ealpha, M);
  k_gat_agg8<<<aggBlocks, 256, 0, stream>>>(Hf8, rowptr, colsrc, ealpha, b1,
                                            Ah, Al, N);
  // --- layer 2 ---
  k_gemm_lds<<<gemmBlocks, 256, 0, stream>>>(Ah, Al, WT2h, WT2l, Hh, Hf8, N, 256);
  k_att<<<(N * 8 + 255) / 256, 256, 0, stream>>>(Hh, as2, ad2, aS, aD, N * 8, 8);
  k_edge_alpha8<<<edgeBlocks, 256, 0, stream>>>(aS, aD, colsrc, coldst, ealpha, M);
  k_gat_agg8<<<aggBlocks, 256, 0, stream>>>(Hf8, rowptr, colsrc, ealpha, b2,
                                            Ah, Al, N);
  // --- layer 3 (H=1, bf16 gather) ---
  k_gemm_split<2, 1><<<g3, 256, 0, stream>>>(Ah, Al, WT3h, WT3l, Hh, N, 256, 32);
  k_att<<<(N + 255) / 256, 256, 0, stream>>>(Hh, as3, ad3, aS, aD, N, 1);
  k_edge_alpha1<<<edgeBlocks, 256, 0, stream>>>(aS, aD, colsrc, coldst, ealpha, M);
  k_gat_agg1<<<aggBlocks, 256, 0, stream>>>(Hh, rowptr, colsrc, ealpha, b3,
                                            h3agg, N);
  // --- pool + final ---
  k_pool_final<<<NUM_GRAPHS, 256, 0, stream>>>(h3agg, batch, linW, linb, out, N);
}